// Round 1
// 886.554 us; speedup vs baseline: 1.1261x; 1.1261x over previous
//
#include <hip/hip_runtime.h>

typedef unsigned short u16;
typedef __attribute__((ext_vector_type(8))) short short8;
typedef __attribute__((ext_vector_type(8))) unsigned short ushort8;
typedef __attribute__((ext_vector_type(4))) float f32x4;
typedef __attribute__((ext_vector_type(2))) float f32x2;

#define DEV __device__ __forceinline__

DEV float bf2f(u16 u){ union{unsigned int i; float f;} v; v.i = ((unsigned int)u)<<16u; return v.f; }
DEV u16 f2bf(float f){ union{float f; unsigned int i;} v; v.f=f; unsigned int r = v.i + 0x7FFFu + ((v.i>>16)&1u); return (u16)(r>>16); }

DEV void gload16(const u16* g, u16* l){
  __builtin_amdgcn_global_load_lds((const __attribute__((address_space(1))) void*)g,
                                   (__attribute__((address_space(3))) void*)l, 16, 0, 0);
}

DEV float wsum(float v){
  v += __shfl_xor(v, 32, 64);
  v += __shfl_xor(v, 16, 64);
  v += __shfl_xor(v, 8, 64);
  v += __shfl_xor(v, 4, 64);
  v += __shfl_xor(v, 2, 64);
  v += __shfl_xor(v, 1, 64);
  return v;
}
// sum over the 4 lanes sharing (lane&15)
DEV float qsum(float v){
  v += __shfl_xor(v, 16, 64);
  v += __shfl_xor(v, 32, 64);
  return v;
}
// sum over the 16 lanes sharing (lane>>4)
DEV float jsum(float v){
  v += __shfl_xor(v, 1, 64);
  v += __shfl_xor(v, 2, 64);
  v += __shfl_xor(v, 4, 64);
  v += __shfl_xor(v, 8, 64);
  return v;
}

DEV float block_sum(float v, float* red){
  v = wsum(v);
  __syncthreads();
  if((threadIdx.x & 63u)==0) red[threadIdx.x>>6] = v;
  __syncthreads();
  return red[0]+red[1]+red[2]+red[3];
}

// raw workgroup barrier: drain own LDS ops only (Y-stores / prefetch global
// loads stay in flight across it; __syncthreads would vmcnt(0)-drain them)
#define BARS() do{ asm volatile("s_waitcnt lgkmcnt(0)" ::: "memory"); \
  __builtin_amdgcn_s_barrier(); __builtin_amdgcn_sched_barrier(0); }while(0)

// ---------------- LN over rows of 2048, bf16 out ----------------
__global__ __launch_bounds__(256) void ln_row(
    const float* __restrict__ in, const float* __restrict__ w, const float* __restrict__ bb,
    float eps, u16* __restrict__ outb)
{
  __shared__ float red[4];
  const int row = blockIdx.x, t = threadIdx.x;
  const float* p = in + (size_t)row*2048 + t*8;
  f32x4 a = *(const f32x4*)p;
  f32x4 c = *(const f32x4*)(p+4);
  float s = a[0]+a[1]+a[2]+a[3]+c[0]+c[1]+c[2]+c[3];
  s = block_sum(s, red);
  float mu = s*(1.f/2048.f);
  float vs = 0.f;
  #pragma unroll
  for(int j=0;j<4;j++){ float d=a[j]-mu; vs += d*d; }
  #pragma unroll
  for(int j=0;j<4;j++){ float d=c[j]-mu; vs += d*d; }
  vs = block_sum(vs, red);
  float rstd = rsqrtf(vs*(1.f/2048.f) + eps);
  f32x4 w0 = *(const f32x4*)(w + t*8);
  f32x4 w1 = *(const f32x4*)(w + t*8 + 4);
  f32x4 b0 = *(const f32x4*)(bb + t*8);
  f32x4 b1 = *(const f32x4*)(bb + t*8 + 4);
  ushort8 o;
  #pragma unroll
  for(int j=0;j<4;j++) o[j]   = f2bf((a[j]-mu)*rstd*w0[j] + b0[j]);
  #pragma unroll
  for(int j=0;j<4;j++) o[j+4] = f2bf((c[j]-mu)*rstd*w1[j] + b1[j]);
  *(ushort8*)(outb + (size_t)row*2048 + t*8) = o;
}

// ---------------- transpose + cast fp32 (K x N) -> bf16 (N x K) ----------------
__global__ __launch_bounds__(256) void transpose_cast(
    const float* __restrict__ src, u16* __restrict__ dst, int K, int N)
{
  __shared__ float tile[32][33];
  const int kb = blockIdx.x*32, nb = blockIdx.y*32;
  const int tx = threadIdx.x & 31, ty = threadIdx.x >> 5; // 32 x 8
  #pragma unroll
  for(int i=0;i<4;i++){
    int k = ty + i*8;
    tile[k][tx] = src[(size_t)(kb+k)*N + nb + tx];
  }
  __syncthreads();
  #pragma unroll
  for(int i=0;i<4;i++){
    int nn = ty + i*8;
    dst[(size_t)(nb+nn)*K + kb + tx] = f2bf(tile[tx][nn]);
  }
}

// cast lr_w (32 x 2048) into rows [0..31] of a 256x2048 block, zero the rest
// (rows 6144..6399 of the padded-to-6400 B^T weight buffer)
__global__ __launch_bounds__(256) void cast_lrw(const float* __restrict__ lrw, u16* __restrict__ dst)
{
  int i = blockIdx.x*256 + threadIdx.x;       // 256*2048 total
  if (i < 32*2048) dst[i] = f2bf(lrw[i]);
  else dst[i] = 0;
}

// rope tables (pos 0..15, d 0..63) + tok vector
__global__ void rope_init(const float* __restrict__ tio, float* __restrict__ cosb,
                          float* __restrict__ sinb, float* __restrict__ tokb)
{
  int t = blockIdx.x*256 + threadIdx.x;
  if (t < 1024){
    int p = t>>6, d = t&63;
    float inv = powf(10000.f, -(float)(2*(d&31))/64.f);
    float fr = (float)p * inv;
    cosb[t] = cosf(fr);
    sinb[t] = sinf(fr);
  }
  if (blockIdx.x==0 && threadIdx.x<16)
    tokb[threadIdx.x] = fmaxf(1.f/(float)(threadIdx.x+1) + tio[threadIdx.x], 0.f);
}

// ================== 256x256 8-phase bf16 GEMM (BK=64, 8 waves) ==================
// LDS 128 KiB = 2 dbuf x 2 khalf x (A 256x32 + B 256x32) bf16, pair-row XOR swizzle.
// Per phase: {4|8 ds_read_b128, 1 half-tile stage (2 global_load_lds dwordx4),
// barrier, lgkmcnt(0), setprio(1), 16 MFMA, setprio(0), [vmcnt(8)], barrier}.
// Stage->consume distance = 6 phases; vmcnt never drained to 0 in the loop.
//
// Swizzle (within a 256x32 half-buffer): logical (row r, k-octet s in [0,4))
// lives at byte (r>>1)*128 + (((r&1)*4+s) ^ ((r>>1)&7))*16. Reads: all 64 lanes
// of a frag cover a contiguous 1024B block with 2 lanes per 4-bank group (free).
// Writes: global_load_lds dest is linear lane*16; the XOR is folded into the
// per-lane GLOBAL source address (both-sides-or-neither rule).
#define MM(MI,NI,AA,BB) acc[MI][NI] = __builtin_amdgcn_mfma_f32_16x16x32_bf16(AA, BB, acc[MI][NI], 0, 0, 0)

#define RD_A(D,KH,MF) (*(const short8*)(ldsb + ((D)<<16) + ((KH)<<14) + (wm<<13) + ((MF)<<10) + loff))
#define RD_B(D,KH,NF) (*(const short8*)(ldsb + ((D)<<16) + 32768 + ((KH)<<14) + (wn<<12) + ((NF)<<10) + loff))

#define PHASE(D,KH,MH,RB,STG,VM) { \
  __builtin_amdgcn_sched_barrier(0); \
  if (RB){ b0 = RD_B(D,KH,0); b1 = RD_B(D,KH,1); b2 = RD_B(D,KH,2); b3 = RD_B(D,KH,3); } \
  short8 a0 = RD_A(D,KH,4*(MH)+0); \
  short8 a1 = RD_A(D,KH,4*(MH)+1); \
  short8 a2 = RD_A(D,KH,4*(MH)+2); \
  short8 a3 = RD_A(D,KH,4*(MH)+3); \
  STG; \
  __builtin_amdgcn_sched_barrier(0); \
  __builtin_amdgcn_s_barrier(); \
  asm volatile("s_waitcnt lgkmcnt(0)" ::: "memory"); \
  __builtin_amdgcn_sched_barrier(0); \
  __builtin_amdgcn_s_setprio(1); \
  MM(4*(MH)+0,0,a0,b0); MM(4*(MH)+1,0,a1,b0); MM(4*(MH)+2,0,a2,b0); MM(4*(MH)+3,0,a3,b0); \
  MM(4*(MH)+0,1,a0,b1); MM(4*(MH)+1,1,a1,b1); MM(4*(MH)+2,1,a2,b1); MM(4*(MH)+3,1,a3,b1); \
  MM(4*(MH)+0,2,a0,b2); MM(4*(MH)+1,2,a1,b2); MM(4*(MH)+2,2,a2,b2); MM(4*(MH)+3,2,a3,b2); \
  MM(4*(MH)+0,3,a0,b3); MM(4*(MH)+1,3,a1,b3); MM(4*(MH)+2,3,a2,b3); MM(4*(MH)+3,3,a3,b3); \
  __builtin_amdgcn_s_setprio(0); \
  if (VM){ asm volatile("s_waitcnt vmcnt(8)" ::: "memory"); } \
  __builtin_amdgcn_sched_barrier(0); \
  __builtin_amdgcn_s_barrier(); \
}

template<int EPI>
__global__ __launch_bounds__(512, 2) void gemm256(
    const u16* __restrict__ A, const u16* __restrict__ Bt,
    float* __restrict__ C, u16* __restrict__ Cb,
    const float* __restrict__ bias, const float* __restrict__ resid,
    int Nld, int Nreal, int K, int ntN)
{
  extern __shared__ u16 lds[];
  const int t = threadIdx.x, lane = t&63, wv = t>>6;
  const int wm = wv>>2, wn = wv&3;          // 2 (M) x 4 (N) waves
  const int fr = lane&15, kq = lane>>4;

  int bid = blockIdx.x;
  {
    int nwg = gridDim.x;                    // bijective XCD swizzle
    int q = nwg>>3, r = nwg&7;
    int x = bid&7, l = bid>>3;
    bid = (x<r) ? (x*(q+1)+l) : (r*(q+1)+(x-r)*q+l);
  }
  const int bm = bid/ntN, bn = bid%ntN;

  f32x4 acc[8][4];
  #pragma unroll
  for(int i=0;i<8;i++)
    #pragma unroll
    for(int j=0;j<4;j++) acc[i][j]=(f32x4){0.f,0.f,0.f,0.f};

  const u16* gA = A  + (size_t)(bm*256)*K;
  const u16* gB = Bt + (size_t)(bn*256)*K;

  // staging constants: thread t writes LDS linear 16B slot; inverse-swizzled
  // global source (row rstg(+128*pass), k-octet cstg)
  const int Ls   = (t&7) ^ ((t>>3)&7);
  const int rstg = ((t>>3)<<1) | (Ls>>2);
  const int cstg = (Ls&3)<<3;
  u16* const ldsw = lds + (wv<<9);

  // read constants: per-lane invariant byte offset within a frag
  const int Plane = (((fr&1)<<2) | kq) ^ (fr>>1);
  const int loff  = ((fr>>1)<<7) | (Plane<<4);
  const char* const ldsb = (const char*)lds;

  auto stA = [&](int d, int kh, int kts){
    u16* lb = ldsw + (d<<15) + (kh<<13);
    const u16* g = gA + (size_t)rstg*K + kts + (kh<<5) + cstg;
    gload16(g, lb);
    gload16(g + ((size_t)K<<7), lb + 4096);
  };
  auto stB = [&](int d, int kh, int kts){
    u16* lb = ldsw + (d<<15) + 16384 + (kh<<13);
    const u16* g = gB + (size_t)rstg*K + kts + (kh<<5) + cstg;
    gload16(g, lb);
    gload16(g + ((size_t)K<<7), lb + 4096);
  };

  // prologue: T0 fully + T1.khalf0  (12 loads/wave) -> wait oldest 4 (T0.k0)
  stA(0,0,0); stB(0,0,0); stA(0,1,0); stB(0,1,0); stA(1,0,64); stB(1,0,64);
  asm volatile("s_waitcnt vmcnt(8)" ::: "memory");
  __builtin_amdgcn_sched_barrier(0);
  __builtin_amdgcn_s_barrier();

  for (int kt = 0; kt < K; kt += 128){
    const int ktp = (kt+128 < K) ? kt+128 : 0;            // wrapped (harmless reload)
    const int ktq = (kt+192 < K) ? kt+192 : kt+192-K;
    short8 b0={0},b1={0},b2={0},b3={0};
    PHASE(0,0,0,1, stA(1,1,kt+64), 0)
    PHASE(0,0,1,0, stB(1,1,kt+64), 1)
    PHASE(0,1,0,1, stA(0,0,ktp),   0)
    PHASE(0,1,1,0, stB(0,0,ktp),   1)
    PHASE(1,0,0,1, stA(0,1,ktp),   0)
    PHASE(1,0,1,0, stB(0,1,ktp),   1)
    PHASE(1,1,0,1, stA(1,0,ktq),   0)
    PHASE(1,1,1,0, stB(1,0,ktq),   1)
  }

  const int cr = (lane>>4)<<2, cc = lane&15;
  #pragma unroll
  for(int mi=0;mi<8;mi++){
    #pragma unroll
    for(int ni=0;ni<4;ni++){
      const int row0 = bm*256 + wm*128 + mi*16 + cr;
      const int col  = bn*256 + wn*64  + ni*16 + cc;
      if (col < Nreal){
        #pragma unroll
        for(int rr=0;rr<4;rr++){
          size_t idx = (size_t)(row0+rr)*Nld + col;
          float v = acc[mi][ni][rr];
          if (EPI==1 || EPI==3) v += resid[idx];
          if (EPI==2 || EPI==3) v += bias[col];
          if (EPI==2){ v = fmaxf(v, 0.f); Cb[idx] = f2bf(v); }
          else if (EPI==4){ Cb[idx] = f2bf(v); }
          else C[idx] = v;
        }
      }
    }
  }
}

// ================== MFMA TTT scan ==================
// One block (512 thr, 8 waves) per (b,h). All per-step matmuls via
// mfma_f32_16x16x32_bf16 in TRANSPOSED space: Z^T[d][i] = sum_k W1t[d][k] xk[i][k],
// so row reductions (over d) are 15 reg-adds + shfl_xor(16)+shfl_xor(32).
// W1 state lives in per-wave C-fragments (8 VGPR/thread); bf16 mirror in LDS
// refreshed each step for A-operand reads.
#define W1LD 72   // bf16 elems per row of W1bf (pad 64->72)
#define XLD  72   // xqbf/xkbf row stride
#define GTLD 40   // gradTbf row stride (16 cols used, [16,32) zero for K=32 frags)
#define EKLD 40   // exkT row stride
#define EALD 40   // etaA row stride
#define TLD  17   // f32 transposed tiles [64][17]

__global__ __launch_bounds__(512, 1) void ttt_scan(
    const u16* __restrict__ XQKV,   // 8192 x 6272 bf16: [q|k|v|lr_pre(32)+pad]
    const float* __restrict__ ropec, const float* __restrict__ ropes,
    const float* __restrict__ tokp,
    const float* __restrict__ nw, const float* __restrict__ nb,
    const float* __restrict__ lrb,
    const float* __restrict__ W1i,  // NH x 64 x 64  (W1i[h][k][d])
    const float* __restrict__ b1i,  // NH x 64
    float* __restrict__ Y)          // 8192 x 2048
{
  const int blk = blockIdx.x, b = blk>>5, h = blk&31;
  const int t = threadIdx.x, lane = t&63, wv = t>>6;
  const int fr = lane&15, quad = lane>>4;
  const int i0 = wv*2, i1 = i0+1;      // rows this wave stages

  __shared__ u16 W1bf[64*W1LD];        // W1t[d][k] in bf16
  __shared__ u16 xqbf[2][16*XLD];      // [i][k]
  __shared__ u16 xkbf[2][16*XLD];
  __shared__ u16 exkT[2][64*EKLD];     // [k][j] = -e_j * xk[j][k]
  __shared__ u16 gradTbf[64*GTLD];     // [d][j]
  __shared__ u16 etaA[16*EALD];        // [i][j] = -tok_i*lr_j/64*(1+At[i][j])*(j<=i)
  __shared__ float tgT[2][64*TLD];     // [d][i] = (v - xk)[i][d]
  __shared__ float xqT[2][64*TLD];     // [d][i]
  __shared__ float b1s[64];
  __shared__ f32x2 lwlb[64];
  __shared__ float lrs[2][16];
  __shared__ float tokl[16];

  const float lrbh = lrb[h];
  const float cc0 = ropec[i0*64 + lane], ss0 = ropes[i0*64 + lane];
  const float cc1 = ropec[i1*64 + lane], ss1 = ropes[i1*64 + lane];
  const float tok15 = tokp[15];
  const float ct = tok15*(1.f/64.f);
  const float sg = (lane<32)? -1.f : 1.f;

  // ---- W1 fragments: tiles T0=2wv, T1=2wv+1; tile T: mtile=T>>2 (d), ntile=T&3 (k)
  const int m0 = (wv*2)>>2,   n0 = (wv*2)&3;
  const int m1 = (wv*2+1)>>2, n1 = (wv*2+1)&3;
  f32x4 wfa, wfb;
  {
    const float* wsrc = W1i + (size_t)h*4096;
    #pragma unroll
    for(int r=0;r<4;r++){
      wfa[r] = wsrc[(n0*16+fr)*64 + (m0*16+quad*4+r)];
      wfb[r] = wsrc[(n1*16+fr)*64 + (m1*16+quad*4+r)];
    }
    #pragma unroll
    for(int r=0;r<4;r++){
      W1bf[(m0*16+quad*4+r)*W1LD + n0*16 + fr] = f2bf(wfa[r]);
      W1bf[(m1*16+quad*4+r)*W1LD + n1*16 + fr] = f2bf(wfb[r]);
    }
  }
  // zero pads (cols [16,40) of gradTbf/exkT/etaA so K=32 fragments see zeros)
  for(int i=t;i<64*24;i+=512){
    int rr=i/24, cp=16+i%24;
    gradTbf[rr*GTLD+cp]=0; exkT[0][rr*EKLD+cp]=0; exkT[1][rr*EKLD+cp]=0;
  }
  for(int i=t;i<16*24;i+=512){ int rr=i/24, cp=16+i%24; etaA[rr*EALD+cp]=0; }
  if (t<64){ b1s[t]=b1i[h*64+t]; lwlb[t]=(f32x2){nw[h*64+t], nb[h*64+t]}; }
  if (t<16) tokl[t]=tokp[t];

  // stage minibatch data (RoPE + transposed copies) into buffer bf
  auto stage = [&](int bf, u16 Pq0,u16 Pk0,u16 Pv0,u16 Pl0,
                           u16 Pq1,u16 Pk1,u16 Pv1,u16 Pl1){
    float q0=bf2f(Pq0), k0=bf2f(Pk0), v0=bf2f(Pv0);
    float q1=bf2f(Pq1), k1=bf2f(Pk1), v1=bf2f(Pv1);
    float qr0 = q0*cc0 + sg*__shfl_xor(q0,32,64)*ss0;
    float kr0 = k0*cc0 + sg*__shfl_xor(k0,32,64)*ss0;
    float qr1 = q1*cc1 + sg*__shfl_xor(q1,32,64)*ss1;
    float kr1 = k1*cc1 + sg*__shfl_xor(k1,32,64)*ss1;
    float lr0 = 1.f/(1.f + expf(-(bf2f(Pl0) + lrbh)));
    float lr1 = 1.f/(1.f + expf(-(bf2f(Pl1) + lrbh)));
    xqbf[bf][i0*XLD+lane] = f2bf(qr0);
    xqbf[bf][i1*XLD+lane] = f2bf(qr1);
    xkbf[bf][i0*XLD+lane] = f2bf(kr0);
    xkbf[bf][i1*XLD+lane] = f2bf(kr1);
    exkT[bf][lane*EKLD+i0] = f2bf(-ct*lr0*kr0);
    exkT[bf][lane*EKLD+i1] = f2bf(-ct*lr1*kr1);
    tgT[bf][lane*TLD+i0] = v0 - kr0;
    tgT[bf][lane*TLD+i1] = v1 - kr1;
    xqT[bf][lane*TLD+i0] = qr0;
    xqT[bf][lane*TLD+i1] = qr1;
    if (lane==0){ lrs[bf][i0]=lr0; lrs[bf][i1]=lr1; }
  };

  // prologue: stage minibatch 0
  {
    const size_t rb = (size_t)b*2048;
    const u16* p0 = XQKV + (rb+i0)*6272 + h*64 + lane;
    const u16* p1 = XQKV + (rb+i1)*6272 + h*64 + lane;
    u16 l0 = XQKV[(rb+i0)*6272 + 6144 + h];
    u16 l1 = XQKV[(rb+i1)*6272 + 6144 + h];
    stage(0, p0[0],p0[2048],p0[4096],l0, p1[0],p1[2048],p1[4096],l1);
  }
  __syncthreads();

  const f32x4 fzero = (f32x4){0.f,0.f,0.f,0.f};

  for(int n=0;n<128;n++){
    const int cur = n&1, nxt = cur^1;
    const size_t rbase = (size_t)b*2048 + n*16;

    // prefetch next minibatch into regs
    u16 Pq0=0,Pk0=0,Pv0=0,Pl0=0,Pq1=0,Pk1=0,Pv1=0,Pl1=0;
    if (n<127){
      const size_t rb2 = rbase + 16;
      const u16* p0 = XQKV + (rb2+i0)*6272 + h*64 + lane;
      const u16* p1 = XQKV + (rb2+i1)*6272 + h*64 + lane;
      Pq0=p0[0]; Pk0=p0[2048]; Pv0=p0[4096];
      Pq1=p1[0]; Pk1=p1[2048]; Pv1=p1[4096];
      Pl0=XQKV[(rb2+i0)*6272 + 6144 + h];
      Pl1=XQKV[(rb2+i1)*6272 + 6144 + h];
    }

    // ---------------- region A ----------------
    f32x4 del = fzero;                       // waves 0-3: b1 delta (per r)
    f32x4 zq0, zq1, zq2, zq3;                // wave 4: Zq^T tiles
    f32x4 b1q0, b1q1, b1q2, b1q3;            // wave 4: old b1 per (m,r)
    zq0=zq1=zq2=zq3=fzero; b1q0=b1q1=b1q2=b1q3=fzero;

    if (wv < 4){
      // Zk^T = W1t (x) xk : C[d][i], full 64x16 per wave (dup x4)
      short8 bk0 = *(const short8*)&xkbf[cur][fr*XLD + quad*8];
      short8 bk1 = *(const short8*)&xkbf[cur][fr*XLD + 32 + quad*8];
      f32x4 z0,z1,z2,z3;
      z0 = __builtin_amdgcn_mfma_f32_16x16x32_bf16(*(const short8*)&W1bf[( 0+fr)*W1LD + quad*8],      bk0, fzero, 0,0,0);
      z0 = __builtin_amdgcn_mfma_f32_16x16x32_bf16(*(const short8*)&W1bf[( 0+fr)*W1LD + 32 + quad*8], bk1, z0,    0,0,0);
      z1 = __builtin_amdgcn_mfma_f32_16x16x32_bf16(*(const short8*)&W1bf[(16+fr)*W1LD + quad*8],      bk0, fzero, 0,0,0);
      z1 = __builtin_amdgcn_mfma_f32_16x16x32_bf16(*(const short8*)&W1bf[(16+fr)*W1LD + 32 + quad*8], bk1, z1,    0,0,0);
      z2 = __builtin_amdgcn_mfma_f32_16x16x32_bf16(*(const short8*)&W1bf[(32+fr)*W1LD + quad*8],      bk0, fzero, 0,0,0);
      z2 = __builtin_amdgcn_mfma_f32_16x16x32_bf16(*(const short8*)&W1bf[(32+fr)*W1LD + 32 + quad*8], bk1, z2,    0,0,0);
      z3 = __builtin_amdgcn_mfma_f32_16x16x32_bf16(*(const short8*)&W1bf[(48+fr)*W1LD + quad*8],      bk0, fzero, 0,0,0);
      z3 = __builtin_amdgcn_mfma_f32_16x16x32_bf16(*(const short8*)&W1bf[(48+fr)*W1LD + 32 + quad*8], bk1, z3,    0,0,0);
      // add b1 (Z1 = xk@W1 + b1): z[m][r] += b1[d]
      f32x4 xh0,xh1,xh2,xh3;
      {
        float s1=0.f, s2=0.f;
        #pragma unroll
        for(int r=0;r<4;r++){
          z0[r] += b1s[ 0+quad*4+r];
          z1[r] += b1s[16+quad*4+r];
          z2[r] += b1s[32+quad*4+r];
          z3[r] += b1s[48+quad*4+r];
          s1 += z0[r]+z1[r]+z2[r]+z3[r];
          s2 += z0[r]*z0[r]+z1[r]*z1[r]+z2[r]*z2[r]+z3[r]*z3[r];
        }
        s1 = qsum(s1); s2 = qsum(s2);
        float mu = s1*(1.f/64.f);
        float var = s2*(1.f/64.f) - mu*mu;
        float rstd = rsqrtf(var + 1e-6f);
        // xh, gxh
        float u1=0.f, u2=0.f;
        #pragma unroll
        for(int m=0;m<4;m++){
          f32x4* zp = (m==0)?&z0:(m==1)?&z1:(m==2)?&z2:&z3;
          f32x4* xp = (m==0)?&xh0:(m==1)?&xh1:(m==2)?&xh2:&xh3;
          #pragma unroll
          for(int r=0;r<4;r++){
            int d = m*16 + quad*4 + r;
            f32x2 wb = lwlb[d];
            float xh = ((*zp)[r] - mu)*rstd;
            float gx = (wb[0]*xh + wb[1] - tgT[cur][d*TLD + fr])*wb[0];
            (*xp)[r] = xh;
            (*zp)[r] = gx;
            u1 += gx; u2 += gx*xh;
          }
        }
        u1 = qsum(u1); u2 = qsum(u2);
        const float c64 = rstd*(1.f/64.f);
        #pragma unroll
        for(int m=0;m<4;m++){
          f32x4* zp = (m==0)?&z0:(m==1)?&z1:(m==2)?&z2:&z3;
          f32x4* xp = (m==0)?&xh0:(m==1)?&xh1:(m==2)?&xh2:&xh3;
          #pragma unroll
          for(int r=0;r<4;r++)
            (*zp)[r] = (64.f*(*zp)[r] - u1 - (*xp)[r]*u2)*c64;   // gradT
        }
      }
      // wave wv writes mtile wv of gradTbf; computes b1 delta for its mtile
      f32x4 zsel = (wv==0)?z0:(wv==1)?z1:(wv==2)?z2:z3;
      #pragma unroll
      for(int r=0;r<4;r++)
        gradTbf[(wv*16+quad*4+r)*GTLD + fr] = f2bf(zsel[r]);
      float ej = ct * lrs[cur][fr];
      #pragma unroll
      for(int r=0;r<4;r++)
        del[r] = jsum(ej * zsel[r]);
    }
    else if (wv == 4){
      // Zq^T = W1t (x) xq
      short8 bq0 = *(const short8*)&xqbf[cur][fr*XLD + quad*8];
      short8 bq1 = *(const short8*)&xqbf[cur][fr*XLD + 32 + quad*8];
      zq0 = __builtin_amdgcn_mfma_f32_16x16x32_bf16(*(const short8*)&W1bf[( 0+fr)*W1LD + quad*8],      bq0, fzero, 0,0,0);
      zq0 = __builtin_amdgcn_mfma_f32_16x16x32_bf16(*(const short8*)&W1bf[( 0+fr)*W1LD + 32 + quad*8], bq1, zq0,   0,0,0);
      zq1 = __builtin_amdgcn_mfma_f32_16x16x32_bf16(*(const short8*)&W1bf[(16+fr)*W1LD + quad*8],      bq0, fzero, 0,0,0);
      zq1 = __builtin_amdgcn_mfma_f32_16x16x32_bf16(*(const short8*)&W1bf[(16+fr)*W1LD + 32 + quad*8], bq1, zq1,   0,0,0);
      zq2 = __builtin_amdgcn_mfma_f32_16x16x32_bf16(*(const short8*)&W1bf[(32+fr)*W1LD + quad*8],      bq0, fzero, 0,0,0);
      zq2 = __builtin_amdgcn_mfma_f32_16x16x32_bf16(*(const short8*)&W1bf[(32+fr)*W1LD + 32 + quad*8], bq1, zq2,   0,0,0);
      zq3 = __builtin_amdgcn_mfma_f32_16x16x32_bf16(*(const short8*)&W1bf[(48+fr)*W1LD + quad*8],      bq0, fzero, 0,0,0);
      zq3 = __builtin_amdgcn_mfma_f32_16x16x32_bf16(*(const short8*)&W1bf[(48+fr)*W1LD + 32 + quad*8], bq1, zq3,   0,0,0);
      // old b1 (pre-update) for b1_bar base
      b1q0 = *(const f32x4*)&b1s[ 0+quad*4];
      b1q1 = *(const f32x4*)&b1s[16+quad*4];
      b1q2 = *(const f32x4*)&b1s[32+quad*4];
      b1q3 = *(const f32x4*)&b1s[48+quad*4];
    }
    else if (wv == 7){
      // At = xq (x) xk : C[i][j]
      short8 aq0 = *(const short8*)&xqbf[cur][fr*XLD + quad*8];
      short8 aq1 = *(const short8*)&xqbf[cur][fr*XLD + 32 + quad*8];
      short8 bk0 = *(const short8*)&xkbf[cur][fr*XLD + quad*8];
      short8 bk1 = *(const short8*)&xkbf[cur][fr*XLD + 32 + quad*8];
      f32x4 at;
      at = __builtin_amdgcn_mfma_f32_16x16x32_bf16(aq0, bk0, fzero, 0,0,0);
      at = __builtin_amdgcn_mfma_f32_16x16x32_bf16(aq1, bk1, at,    0,0,0);
      float lrj = lrs[cur][fr]*(1.f/64.f);
      #pragma unroll
      for(int r=0;r<4;r++){
        int i = quad*4 + r;
        float val = (fr <= i) ? -tokl[i]*lrj*(1.f + at[r]) : 0.f;
        etaA[i*EALD + fr] = f2bf(val);
      }
    }
    BARS();

    // ---------------- region B ----------------
    // W1 update: wfrag += gradT (x) (-e*xk^T)   [16 tiles, 2 per wave]
    {
      short8 ga = *(const short8*)&gradTbf[(m0*16+fr)*GTLD + quad*8];
      short8 eb = *(const short8*)&exkT[cur][(n0*16+fr)*EKLD + quad*8];
      wfa = __builtin_amdgcn_mfma_f32_16x16x32_bf16(ga, eb, wfa, 0,0,0);
      short8 gb = *(const short8*)&gradTbf[(m1*16+fr)*GTLD + quad*8];
      short8 eb2 = *(const short8*)&exkT[cur][(n1*16+fr)*EKLD + quad*8];
      wfb = __builtin_amdgcn_mfma_f32_16x16x32_bf16(gb, eb2, wfb, 0,0,0);
      #pragma unroll
      for(int r=0;r<4;r++){
        W1bf[(m0*16+quad*4+r)*W1LD + n0*16 + fr] = f2bf(wfa[r]);
        W1bf[(m1*16+quad*4+r)*W1LD + n1*16 + fr] = f2bf(wfb[r]);
      }
    }
    if (wv == 4){
      // C2[d][i] = gradT (x) etaA ; Z1_bar^T = Zq^T + b1 + C2; LN; Y write
      short8 be = *(const short8*)&etaA[fr*EALD + quad*8];
      f32x4 c20,c21,c22,c23;
      c20 = __builtin_amdgcn_mfma_f32_16x16x32_bf16(*(const short8*)&gradTbf[( 0+fr)*GTLD + quad*8], be, fzero, 0,0,0);
      c21 = __builtin_amdgcn_mfma_f32_16x16x32_bf16(*(const short8*)&gradTbf[(16+fr)*GTLD + quad*8], be, fzero, 0,0,0);
      c22 = __builtin_amdgcn_mfma_f32_16x16x32_bf16(*(const short8*)&gradTbf[(32+fr)*GTLD + quad*8], be, fzero, 0,0,0);
      c23 = __builtin_amdgcn_mfma_f32_16x16x32_bf16(*(const short8*)&gradTbf[(48+fr)*GTLD + quad*8], be, fzero, 0,0,0);
      f32x4 zb0,zb1,zb2,zb3;
      float s1=0.f, s2=0.f;
      #pragma unroll
      for(int r=0;r<4;r++){
        zb0[r] = zq0[r] + b1q0[r] + c20[r];
        zb1[r] = zq1[r] + b1q1[r] + c21[r];
        zb2[r] = zq2[r] + b1q2[r] + c22[r];
        zb3[r] = zq3[r] + b1q3[r] + c23[r];
        s1 += zb0[r]+zb1[r]+zb2[r]+zb3[r];
        s2 += zb0[r]*zb0[r]+zb1[r]*zb1[r]+zb2[r]*zb2[r]+zb3[r]*zb3[r];
      }
      s1 = qsum(s1); s2 = qsum(s2);
      float mu = s1*(1.f/64.f);
      float var = s2*(1.f/64.f) - mu*mu;
      float rstd = rsqrtf(var + 1e-6f);
      #pragma unroll
      for(int m=0;m<4;m++){
        f32x4* zp = (m==0)?&zb0:(m==1)?&zb1:(m==2)?&zb2:&zb3;
        #pragma unroll
        for(int r=0;r<4;r++){
          int d = m*16 + quad*4 + r;
          f32x2 wb = lwlb[d];
          float xh = ((*zp)[r] - mu)*rstd;
          Y[(rbase+fr)*2048 + h*64 + d] = xqT[cur][d*TLD + fr] + xh*wb[0] + wb[1];
        }
      }
    }
    if (wv < 4 && fr == 0){
      #pragma unroll
      for(int r=0;r<4;r++) b1s[wv*16+quad*4+r] -= del[r];
    }
    if (n<127) stage(nxt, Pq0,Pk0,Pv0,Pl0, Pq1,Pk1,Pv1,Pl1);
    BARS();
  }
}

// ---------------- host launch ----------------
extern "C" void kernel_launch(void* const* d_in, const int* in_sizes, int n_in,
                              void* d_out, int out_size, void* d_ws, size_t ws_size,
                              hipStream_t stream)
{
  const float* enc   = (const float*)d_in[0];
  const float* ln1w  = (const float*)d_in[1];
  const float* ln1b  = (const float*)d_in[2];
  const float* qw    = (const float*)d_in[3];
  const float* kw    = (const float*)d_in[4];
  const float* vw    = (const float*)d_in[5];
  const float* ow    = (const float*)d_in[6];
  const float* lrw   = (const float*)d_in[7];
  const float* lrb   = (const float*)d_in[8];
  const float* tio   = (const float*)d_in[9];
  const float* tnw   = (const float*)d_in[10];
  const float* tnb   = (const float*)d_in[11];
  const float* W1i   = (const float*)d_in[12];
  const float* b1i   = (const float*)d_in[13];
  const float* postw = (const float*)d_in[14];
  const float* postb = (const float*)d_in[15];
  const float* flnw  = (const float*)d_in[16];
  const float* flnb  = (const float*)d_in[17];
  const float* w1f   = (const float*)d_in[18];
  const float* b1f   = (const float*)d_in[19];
  const float* w2f   = (const float*)d_in[20];
  const float* b2f   = (const float*)d_in[21];
  float* out = (float*)d_out;

  char* ws = (char*)d_ws;
  size_t off = 0;
  auto alloc = [&](size_t bytes)->void*{ void* p = ws + off; off += (bytes + 255) & ~(size_t)255; return p; };
  u16*   regA  = (u16*)  alloc(8192ull*2048*2);   // x_bf -> ypost_bf -> z_bf
  u16*   wqkvT = (u16*)  alloc(6400ull*2048*2);   // [qT|kT|vT|lr(32)+zeros..6400); later oT/w1fT/w2fT
  u16*   XQKV  = (u16*)  alloc(8192ull*6272*2);   // later: h_bf
  float* yb    = (float*)alloc(8192ull*2048*4);   // y -> y2
  float* ropec = (float*)alloc(1024*4);
  float* ropes = (float*)alloc(1024*4);
  float* tokb  = (float*)alloc(64*4);

  u16* oT   = wqkvT;
  u16* w1fT = wqkvT + 2048ull*2048;
  u16* w2fT = w1fT + 1024ull*2048;
  u16* hbf  = XQKV;
  float* y2 = yb;

  static bool s_attr = false;
  if (!s_attr){
    s_attr = true;
    (void)hipFuncSetAttribute(reinterpret_cast<const void*>(gemm256<4>), hipFuncAttributeMaxDynamicSharedMemorySize, 131072);
    (void)hipFuncSetAttribute(reinterpret_cast<const void*>(gemm256<1>), hipFuncAttributeMaxDynamicSharedMemorySize, 131072);
    (void)hipFuncSetAttribute(reinterpret_cast<const void*>(gemm256<2>), hipFuncAttributeMaxDynamicSharedMemorySize, 131072);
    (void)hipFuncSetAttribute(reinterpret_cast<const void*>(gemm256<3>), hipFuncAttributeMaxDynamicSharedMemorySize, 131072);
  }

  rope_init<<<4, 256, 0, stream>>>(tio, ropec, ropes, tokb);

  dim3 tg1(64, 64);
  transpose_cast<<<tg1, 256, 0, stream>>>(qw, wqkvT,               2048, 2048);
  transpose_cast<<<tg1, 256, 0, stream>>>(kw, wqkvT + 2048ull*2048, 2048, 2048);
  transpose_cast<<<tg1, 256, 0, stream>>>(vw, wqkvT + 4096ull*2048, 2048, 2048);
  cast_lrw<<<2048, 256, 0, stream>>>(lrw, wqkvT + 6144ull*2048);

  ln_row<<<8192, 256, 0, stream>>>(enc, ln1w, ln1b, 1e-5f, regA);

  // QKV + lr projection: logical N=6400 (25 tiles), real cols 6272, ldc 6272
  gemm256<4><<<32*25, 512, 131072, stream>>>(regA, wqkvT, nullptr, XQKV,
                                             nullptr, nullptr, 6272, 6272, 2048, 25);

  // transpose remaining weights (reuses wqkvT region; QKV GEMM already consumed it)
  transpose_cast<<<tg1, 256, 0, stream>>>(ow, oT, 2048, 2048);
  dim3 tg2(64, 32);
  transpose_cast<<<tg2, 256, 0, stream>>>(w1f, w1fT, 2048, 1024);
  dim3 tg3(32, 64);
  transpose_cast<<<tg3, 256, 0, stream>>>(w2f, w2fT, 1024, 2048);

  // sequential TTT scan (MFMA formulation)
  ttt_scan<<<128, 512, 0, stream>>>(XQKV, ropec, ropes, tokb, tnw, tnb, lrb, W1i, b1i, yb);

  // post-LN + O-projection + residual(enc)
  ln_row<<<8192, 256, 0, stream>>>(yb, postw, postb, 1e-6f, regA);
  gemm256<1><<<32*8, 512, 131072, stream>>>(regA, oT, y2, nullptr,
                                            nullptr, enc, 2048, 2048, 2048, 8);

  // FFN
  ln_row<<<8192, 256, 0, stream>>>(y2, flnw, flnb, 1e-6f, regA);
  gemm256<2><<<32*4, 512, 131072, stream>>>(regA, w1fT, nullptr, hbf,
                                            b1f, nullptr, 1024, 1024, 2048, 4);
  gemm256<3><<<32*8, 512, 131072, stream>>>(hbf, w2fT, out, nullptr,
                                            b2f, y2, 2048, 2048, 1024, 8);
}

// Round 2
// 857.081 us; speedup vs baseline: 1.1648x; 1.0344x over previous
//
#include <hip/hip_runtime.h>

typedef unsigned short u16;
typedef __attribute__((ext_vector_type(8))) short short8;
typedef __attribute__((ext_vector_type(8))) unsigned short ushort8;
typedef __attribute__((ext_vector_type(4))) float f32x4;
typedef __attribute__((ext_vector_type(2))) float f32x2;
typedef __attribute__((ext_vector_type(2))) unsigned int uint2v;

#define DEV __device__ __forceinline__

DEV float bf2f(u16 u){ union{unsigned int i; float f;} v; v.i = ((unsigned int)u)<<16u; return v.f; }
DEV u16 f2bf(float f){ union{float f; unsigned int i;} v; v.f=f; unsigned int r = v.i + 0x7FFFu + ((v.i>>16)&1u); return (u16)(r>>16); }

DEV void gload16(const u16* g, u16* l){
  __builtin_amdgcn_global_load_lds((const __attribute__((address_space(1))) void*)g,
                                   (__attribute__((address_space(3))) void*)l, 16, 0, 0);
}

DEV float wsum(float v){
  v += __shfl_xor(v, 32, 64);
  v += __shfl_xor(v, 16, 64);
  v += __shfl_xor(v, 8, 64);
  v += __shfl_xor(v, 4, 64);
  v += __shfl_xor(v, 2, 64);
  v += __shfl_xor(v, 1, 64);
  return v;
}

// sum over the 4 lanes sharing (lane&15): xor16 then xor32.
// permlane*_swap is a VALU exchange between two copies of v; whichever
// orientation, x+y == v + v[lane^k] in every lane -> exact same arithmetic
// as the shfl version but without the DS round-trip latency.
#if __has_builtin(__builtin_amdgcn_permlane16_swap) && __has_builtin(__builtin_amdgcn_permlane32_swap)
DEV float qsum(float v){
  unsigned u = __float_as_uint(v);
  uint2v a = __builtin_amdgcn_permlane16_swap(u, u, false, false);
  float s = __uint_as_float(a[0]) + __uint_as_float(a[1]);
  unsigned u2 = __float_as_uint(s);
  uint2v bsw = __builtin_amdgcn_permlane32_swap(u2, u2, false, false);
  return __uint_as_float(bsw[0]) + __uint_as_float(bsw[1]);
}
#else
DEV float qsum(float v){
  v += __shfl_xor(v, 16, 64);
  v += __shfl_xor(v, 32, 64);
  return v;
}
#endif

DEV float block_sum(float v, float* red){
  v = wsum(v);
  __syncthreads();
  if((threadIdx.x & 63u)==0) red[threadIdx.x>>6] = v;
  __syncthreads();
  return red[0]+red[1]+red[2]+red[3];
}

// raw workgroup barrier: drain own LDS ops only (Y-stores / prefetch global
// loads stay in flight across it; __syncthreads would vmcnt(0)-drain them)
#define BARS() do{ asm volatile("s_waitcnt lgkmcnt(0)" ::: "memory"); \
  __builtin_amdgcn_s_barrier(); __builtin_amdgcn_sched_barrier(0); }while(0)

// ---------------- LN over rows of 2048, bf16 out ----------------
__global__ __launch_bounds__(256) void ln_row(
    const float* __restrict__ in, const float* __restrict__ w, const float* __restrict__ bb,
    float eps, u16* __restrict__ outb)
{
  __shared__ float red[4];
  const int row = blockIdx.x, t = threadIdx.x;
  const float* p = in + (size_t)row*2048 + t*8;
  f32x4 a = *(const f32x4*)p;
  f32x4 c = *(const f32x4*)(p+4);
  float s = a[0]+a[1]+a[2]+a[3]+c[0]+c[1]+c[2]+c[3];
  s = block_sum(s, red);
  float mu = s*(1.f/2048.f);
  float vs = 0.f;
  #pragma unroll
  for(int j=0;j<4;j++){ float d=a[j]-mu; vs += d*d; }
  #pragma unroll
  for(int j=0;j<4;j++){ float d=c[j]-mu; vs += d*d; }
  vs = block_sum(vs, red);
  float rstd = rsqrtf(vs*(1.f/2048.f) + eps);
  f32x4 w0 = *(const f32x4*)(w + t*8);
  f32x4 w1 = *(const f32x4*)(w + t*8 + 4);
  f32x4 b0 = *(const f32x4*)(bb + t*8);
  f32x4 b1 = *(const f32x4*)(bb + t*8 + 4);
  ushort8 o;
  #pragma unroll
  for(int j=0;j<4;j++) o[j]   = f2bf((a[j]-mu)*rstd*w0[j] + b0[j]);
  #pragma unroll
  for(int j=0;j<4;j++) o[j+4] = f2bf((c[j]-mu)*rstd*w1[j] + b1[j]);
  *(ushort8*)(outb + (size_t)row*2048 + t*8) = o;
}

// ---------------- transpose + cast fp32 (K x N) -> bf16 (N x K) ----------------
__global__ __launch_bounds__(256) void transpose_cast(
    const float* __restrict__ src, u16* __restrict__ dst, int K, int N)
{
  __shared__ float tile[32][33];
  const int kb = blockIdx.x*32, nb = blockIdx.y*32;
  const int tx = threadIdx.x & 31, ty = threadIdx.x >> 5; // 32 x 8
  #pragma unroll
  for(int i=0;i<4;i++){
    int k = ty + i*8;
    tile[k][tx] = src[(size_t)(kb+k)*N + nb + tx];
  }
  __syncthreads();
  #pragma unroll
  for(int i=0;i<4;i++){
    int nn = ty + i*8;
    dst[(size_t)(nb+nn)*K + kb + tx] = f2bf(tile[tx][nn]);
  }
}

// cast lr_w (32 x 2048) into rows [0..31] of a 256x2048 block, zero the rest
// (rows 6144..6399 of the padded-to-6400 B^T weight buffer)
__global__ __launch_bounds__(256) void cast_lrw(const float* __restrict__ lrw, u16* __restrict__ dst)
{
  int i = blockIdx.x*256 + threadIdx.x;       // 256*2048 total
  if (i < 32*2048) dst[i] = f2bf(lrw[i]);
  else dst[i] = 0;
}

// rope tables (pos 0..15, d 0..63) + tok vector
__global__ void rope_init(const float* __restrict__ tio, float* __restrict__ cosb,
                          float* __restrict__ sinb, float* __restrict__ tokb)
{
  int t = blockIdx.x*256 + threadIdx.x;
  if (t < 1024){
    int p = t>>6, d = t&63;
    float inv = powf(10000.f, -(float)(2*(d&31))/64.f);
    float fr = (float)p * inv;
    cosb[t] = cosf(fr);
    sinb[t] = sinf(fr);
  }
  if (blockIdx.x==0 && threadIdx.x<16)
    tokb[threadIdx.x] = fmaxf(1.f/(float)(threadIdx.x+1) + tio[threadIdx.x], 0.f);
}

// ================== 256x256 8-phase bf16 GEMM (BK=64, 8 waves) ==================
#define MM(MI,NI,AA,BB) acc[MI][NI] = __builtin_amdgcn_mfma_f32_16x16x32_bf16(AA, BB, acc[MI][NI], 0, 0, 0)

#define RD_A(D,KH,MF) (*(const short8*)(ldsb + ((D)<<16) + ((KH)<<14) + (wm<<13) + ((MF)<<10) + loff))
#define RD_B(D,KH,NF) (*(const short8*)(ldsb + ((D)<<16) + 32768 + ((KH)<<14) + (wn<<12) + ((NF)<<10) + loff))

#define PHASE(D,KH,MH,RB,STG,VM) { \
  __builtin_amdgcn_sched_barrier(0); \
  if (RB){ b0 = RD_B(D,KH,0); b1 = RD_B(D,KH,1); b2 = RD_B(D,KH,2); b3 = RD_B(D,KH,3); } \
  short8 a0 = RD_A(D,KH,4*(MH)+0); \
  short8 a1 = RD_A(D,KH,4*(MH)+1); \
  short8 a2 = RD_A(D,KH,4*(MH)+2); \
  short8 a3 = RD_A(D,KH,4*(MH)+3); \
  STG; \
  __builtin_amdgcn_sched_barrier(0); \
  __builtin_amdgcn_s_barrier(); \
  asm volatile("s_waitcnt lgkmcnt(0)" ::: "memory"); \
  __builtin_amdgcn_sched_barrier(0); \
  __builtin_amdgcn_s_setprio(1); \
  MM(4*(MH)+0,0,a0,b0); MM(4*(MH)+1,0,a1,b0); MM(4*(MH)+2,0,a2,b0); MM(4*(MH)+3,0,a3,b0); \
  MM(4*(MH)+0,1,a0,b1); MM(4*(MH)+1,1,a1,b1); MM(4*(MH)+2,1,a2,b1); MM(4*(MH)+3,1,a3,b1); \
  MM(4*(MH)+0,2,a0,b2); MM(4*(MH)+1,2,a1,b2); MM(4*(MH)+2,2,a2,b2); MM(4*(MH)+3,2,a3,b2); \
  MM(4*(MH)+0,3,a0,b3); MM(4*(MH)+1,3,a1,b3); MM(4*(MH)+2,3,a2,b3); MM(4*(MH)+3,3,a3,b3); \
  __builtin_amdgcn_s_setprio(0); \
  if (VM){ asm volatile("s_waitcnt vmcnt(8)" ::: "memory"); } \
  __builtin_amdgcn_sched_barrier(0); \
  __builtin_amdgcn_s_barrier(); \
}

template<int EPI>
__global__ __launch_bounds__(512, 2) void gemm256(
    const u16* __restrict__ A, const u16* __restrict__ Bt,
    float* __restrict__ C, u16* __restrict__ Cb,
    const float* __restrict__ bias, const float* __restrict__ resid,
    int Nld, int Nreal, int K, int ntN)
{
  extern __shared__ u16 lds[];
  const int t = threadIdx.x, lane = t&63, wv = t>>6;
  const int wm = wv>>2, wn = wv&3;          // 2 (M) x 4 (N) waves
  const int fr = lane&15, kq = lane>>4;

  int bid = blockIdx.x;
  {
    int nwg = gridDim.x;                    // bijective XCD swizzle
    int q = nwg>>3, r = nwg&7;
    int x = bid&7, l = bid>>3;
    bid = (x<r) ? (x*(q+1)+l) : (r*(q+1)+(x-r)*q+l);
  }
  const int bm = bid/ntN, bn = bid%ntN;

  f32x4 acc[8][4];
  #pragma unroll
  for(int i=0;i<8;i++)
    #pragma unroll
    for(int j=0;j<4;j++) acc[i][j]=(f32x4){0.f,0.f,0.f,0.f};

  const u16* gA = A  + (size_t)(bm*256)*K;
  const u16* gB = Bt + (size_t)(bn*256)*K;

  const int Ls   = (t&7) ^ ((t>>3)&7);
  const int rstg = ((t>>3)<<1) | (Ls>>2);
  const int cstg = (Ls&3)<<3;
  u16* const ldsw = lds + (wv<<9);

  const int Plane = (((fr&1)<<2) | kq) ^ (fr>>1);
  const int loff  = ((fr>>1)<<7) | (Plane<<4);
  const char* const ldsb = (const char*)lds;

  auto stA = [&](int d, int kh, int kts){
    u16* lb = ldsw + (d<<15) + (kh<<13);
    const u16* g = gA + (size_t)rstg*K + kts + (kh<<5) + cstg;
    gload16(g, lb);
    gload16(g + ((size_t)K<<7), lb + 4096);
  };
  auto stB = [&](int d, int kh, int kts){
    u16* lb = ldsw + (d<<15) + 16384 + (kh<<13);
    const u16* g = gB + (size_t)rstg*K + kts + (kh<<5) + cstg;
    gload16(g, lb);
    gload16(g + ((size_t)K<<7), lb + 4096);
  };

  // prologue: T0 fully + T1.khalf0  (12 loads/wave) -> wait oldest 4 (T0.k0)
  stA(0,0,0); stB(0,0,0); stA(0,1,0); stB(0,1,0); stA(1,0,64); stB(1,0,64);
  asm volatile("s_waitcnt vmcnt(8)" ::: "memory");
  __builtin_amdgcn_sched_barrier(0);
  __builtin_amdgcn_s_barrier();

  for (int kt = 0; kt < K; kt += 128){
    const int ktp = (kt+128 < K) ? kt+128 : 0;            // wrapped (harmless reload)
    const int ktq = (kt+192 < K) ? kt+192 : kt+192-K;
    short8 b0={0},b1={0},b2={0},b3={0};
    PHASE(0,0,0,1, stA(1,1,kt+64), 0)
    PHASE(0,0,1,0, stB(1,1,kt+64), 1)
    PHASE(0,1,0,1, stA(0,0,ktp),   0)
    PHASE(0,1,1,0, stB(0,0,ktp),   1)
    PHASE(1,0,0,1, stA(0,1,ktp),   0)
    PHASE(1,0,1,0, stB(0,1,ktp),   1)
    PHASE(1,1,0,1, stA(1,0,ktq),   0)
    PHASE(1,1,1,0, stB(1,0,ktq),   1)
  }

  const int cr = (lane>>4)<<2, cc = lane&15;
  #pragma unroll
  for(int mi=0;mi<8;mi++){
    #pragma unroll
    for(int ni=0;ni<4;ni++){
      const int row0 = bm*256 + wm*128 + mi*16 + cr;
      const int col  = bn*256 + wn*64  + ni*16 + cc;
      if (col < Nreal){
        #pragma unroll
        for(int rr=0;rr<4;rr++){
          size_t idx = (size_t)(row0+rr)*Nld + col;
          float v = acc[mi][ni][rr];
          if (EPI==1 || EPI==3) v += resid[idx];
          if (EPI==2 || EPI==3) v += bias[col];
          if (EPI==2){ v = fmaxf(v, 0.f); Cb[idx] = f2bf(v); }
          else if (EPI==4){ Cb[idx] = f2bf(v); }
          else C[idx] = v;
        }
      }
    }
  }
}

// ================== MFMA TTT scan ==================
// One block (512 thr, 8 waves) per (b,h). Transposed-space MFMA formulation.
// NEW structure this round:
//  - W1 tiles owned by mtile: wave m (0..3) holds tiles (m, n=0..3). After
//    computing gradT, each wave writes its own mtile to LDS, lgkmcnt(0),
//    reads its A-frag back (same-wave, no barrier) and updates its 4 W1
//    tiles IN REGION A. W1bf is double-buffered so wave 4's Zq reads of the
//    old state never race the new-state writes.
//  - region B shrinks to: wave 4 (C2 + out-LN + Y), wave 5 (b1 update via
//    16-term dot on gradTbf; replaces the 16-shuffle jsum chain), stage.
//  - qsum uses v_permlane16/32_swap (VALU) instead of DS-path shuffles.
#define W1LD 72   // bf16 elems per row of W1bf (pad 64->72)
#define XLD  72   // xqbf/xkbf row stride
#define GTLD 40   // gradTbf row stride (16 cols used, [16,32) zero for K=32 frags)
#define EKLD 40   // exkT row stride
#define EALD 40   // etaA row stride
#define TLD  17   // f32 transposed tiles [64][17]

__global__ __launch_bounds__(512, 1) void ttt_scan(
    const u16* __restrict__ XQKV,   // 8192 x 6272 bf16: [q|k|v|lr_pre(32)+pad]
    const float* __restrict__ ropec, const float* __restrict__ ropes,
    const float* __restrict__ tokp,
    const float* __restrict__ nw, const float* __restrict__ nb,
    const float* __restrict__ lrb,
    const float* __restrict__ W1i,  // NH x 64 x 64  (W1i[h][k][d])
    const float* __restrict__ b1i,  // NH x 64
    float* __restrict__ Y)          // 8192 x 2048
{
  const int blk = blockIdx.x, b = blk>>5, h = blk&31;
  const int t = threadIdx.x, lane = t&63, wv = t>>6;
  const int fr = lane&15, quad = lane>>4;
  const int i0 = wv*2, i1 = i0+1;      // rows this wave stages

  __shared__ u16 W1bf[2][64*W1LD];     // double-buffered W1t[d][k] in bf16
  __shared__ u16 xqbf[2][16*XLD];      // [i][k]
  __shared__ u16 xkbf[2][16*XLD];
  __shared__ u16 exkT[2][64*EKLD];     // [k][j] = -e_j * xk[j][k]
  __shared__ u16 gradTbf[64*GTLD];     // [d][j]
  __shared__ u16 etaA[16*EALD];        // [i][j]
  __shared__ float tgT[2][64*TLD];     // [d][i] = (v - xk)[i][d]
  __shared__ float xqT[2][64*TLD];     // [d][i]
  __shared__ float b1s[64];
  __shared__ f32x2 lwlb[64];
  __shared__ float lrs[2][16];
  __shared__ float tokl[16];

  const float lrbh = lrb[h];
  const float cc0 = ropec[i0*64 + lane], ss0 = ropes[i0*64 + lane];
  const float cc1 = ropec[i1*64 + lane], ss1 = ropes[i1*64 + lane];
  const float tok15 = tokp[15];
  const float ct = tok15*(1.f/64.f);
  const float sg = (lane<32)? -1.f : 1.f;

  // ---- W1 state: wave wv (0..3) owns tiles (m=wv, n=0..3)
  f32x4 wf0, wf1, wf2, wf3;
  if (wv < 4){
    const float* wsrc = W1i + (size_t)h*4096;
    #pragma unroll
    for(int r=0;r<4;r++){
      int d = wv*16+quad*4+r;
      wf0[r] = wsrc[( 0+fr)*64 + d];
      wf1[r] = wsrc[(16+fr)*64 + d];
      wf2[r] = wsrc[(32+fr)*64 + d];
      wf3[r] = wsrc[(48+fr)*64 + d];
    }
    #pragma unroll
    for(int r=0;r<4;r++){
      int d = wv*16+quad*4+r;
      W1bf[0][d*W1LD +  0 + fr] = f2bf(wf0[r]);
      W1bf[0][d*W1LD + 16 + fr] = f2bf(wf1[r]);
      W1bf[0][d*W1LD + 32 + fr] = f2bf(wf2[r]);
      W1bf[0][d*W1LD + 48 + fr] = f2bf(wf3[r]);
    }
  }
  // zero pads (cols [16,40) of gradTbf/exkT/etaA so K=32 fragments see zeros)
  for(int i=t;i<64*24;i+=512){
    int rr=i/24, cp=16+i%24;
    gradTbf[rr*GTLD+cp]=0; exkT[0][rr*EKLD+cp]=0; exkT[1][rr*EKLD+cp]=0;
  }
  for(int i=t;i<16*24;i+=512){ int rr=i/24, cp=16+i%24; etaA[rr*EALD+cp]=0; }
  if (t<64){ b1s[t]=b1i[h*64+t]; lwlb[t]=(f32x2){nw[h*64+t], nb[h*64+t]}; }
  if (t<16) tokl[t]=tokp[t];

  // stage minibatch data (RoPE + transposed copies) into buffer bf
  auto stage = [&](int bf, u16 Pq0,u16 Pk0,u16 Pv0,u16 Pl0,
                           u16 Pq1,u16 Pk1,u16 Pv1,u16 Pl1){
    float q0=bf2f(Pq0), k0=bf2f(Pk0), v0=bf2f(Pv0);
    float q1=bf2f(Pq1), k1=bf2f(Pk1), v1=bf2f(Pv1);
    float qr0 = q0*cc0 + sg*__shfl_xor(q0,32,64)*ss0;
    float kr0 = k0*cc0 + sg*__shfl_xor(k0,32,64)*ss0;
    float qr1 = q1*cc1 + sg*__shfl_xor(q1,32,64)*ss1;
    float kr1 = k1*cc1 + sg*__shfl_xor(k1,32,64)*ss1;
    float lr0 = 1.f/(1.f + expf(-(bf2f(Pl0) + lrbh)));
    float lr1 = 1.f/(1.f + expf(-(bf2f(Pl1) + lrbh)));
    xqbf[bf][i0*XLD+lane] = f2bf(qr0);
    xqbf[bf][i1*XLD+lane] = f2bf(qr1);
    xkbf[bf][i0*XLD+lane] = f2bf(kr0);
    xkbf[bf][i1*XLD+lane] = f2bf(kr1);
    exkT[bf][lane*EKLD+i0] = f2bf(-ct*lr0*kr0);
    exkT[bf][lane*EKLD+i1] = f2bf(-ct*lr1*kr1);
    tgT[bf][lane*TLD+i0] = v0 - kr0;
    tgT[bf][lane*TLD+i1] = v1 - kr1;
    xqT[bf][lane*TLD+i0] = qr0;
    xqT[bf][lane*TLD+i1] = qr1;
    if (lane==0){ lrs[bf][i0]=lr0; lrs[bf][i1]=lr1; }
  };

  // prologue: stage minibatch 0
  {
    const size_t rb = (size_t)b*2048;
    const u16* p0 = XQKV + (rb+i0)*6272 + h*64 + lane;
    const u16* p1 = XQKV + (rb+i1)*6272 + h*64 + lane;
    u16 l0 = XQKV[(rb+i0)*6272 + 6144 + h];
    u16 l1 = XQKV[(rb+i1)*6272 + 6144 + h];
    stage(0, p0[0],p0[2048],p0[4096],l0, p1[0],p1[2048],p1[4096],l1);
  }
  __syncthreads();

  const f32x4 fzero = (f32x4){0.f,0.f,0.f,0.f};

  for(int n=0;n<128;n++){
    const int cur = n&1, nxt = cur^1;
    const int cb = n&1, nbuf = cb^1;            // W1 state read/write buffers
    const size_t rbase = (size_t)b*2048 + n*16;

    // prefetch next minibatch into regs
    u16 Pq0=0,Pk0=0,Pv0=0,Pl0=0,Pq1=0,Pk1=0,Pv1=0,Pl1=0;
    if (n<127){
      const size_t rb2 = rbase + 16;
      const u16* p0 = XQKV + (rb2+i0)*6272 + h*64 + lane;
      const u16* p1 = XQKV + (rb2+i1)*6272 + h*64 + lane;
      Pq0=p0[0]; Pk0=p0[2048]; Pv0=p0[4096];
      Pq1=p1[0]; Pk1=p1[2048]; Pv1=p1[4096];
      Pl0=XQKV[(rb2+i0)*6272 + 6144 + h];
      Pl1=XQKV[(rb2+i1)*6272 + 6144 + h];
    }

    // wave-4 state carried A->B
    f32x4 zq0, zq1, zq2, zq3;
    f32x4 b1q0, b1q1, b1q2, b1q3;
    float xq_r[16];
    f32x2 lw4[16];
    zq0=zq1=zq2=zq3=fzero; b1q0=b1q1=b1q2=b1q3=fzero;

    // ---------------- region A ----------------
    if (wv < 4){
      // hoisted operand loads (independent of MFMA results)
      f32x4 b1v0 = *(const f32x4*)&b1s[ 0+quad*4];
      f32x4 b1v1 = *(const f32x4*)&b1s[16+quad*4];
      f32x4 b1v2 = *(const f32x4*)&b1s[32+quad*4];
      f32x4 b1v3 = *(const f32x4*)&b1s[48+quad*4];
      float tg[16]; f32x2 lwv[16];
      #pragma unroll
      for(int m=0;m<4;m++)
        #pragma unroll
        for(int r=0;r<4;r++){
          int d = m*16+quad*4+r;
          tg[m*4+r]  = tgT[cur][d*TLD + fr];
          lwv[m*4+r] = lwlb[d];
        }
      // Zk^T = W1t (x) xk : C[d][i]
      short8 bk0 = *(const short8*)&xkbf[cur][fr*XLD + quad*8];
      short8 bk1 = *(const short8*)&xkbf[cur][fr*XLD + 32 + quad*8];
      f32x4 z0,z1,z2,z3;
      z0 = __builtin_amdgcn_mfma_f32_16x16x32_bf16(*(const short8*)&W1bf[cb][( 0+fr)*W1LD + quad*8],      bk0, fzero, 0,0,0);
      z0 = __builtin_amdgcn_mfma_f32_16x16x32_bf16(*(const short8*)&W1bf[cb][( 0+fr)*W1LD + 32 + quad*8], bk1, z0,    0,0,0);
      z1 = __builtin_amdgcn_mfma_f32_16x16x32_bf16(*(const short8*)&W1bf[cb][(16+fr)*W1LD + quad*8],      bk0, fzero, 0,0,0);
      z1 = __builtin_amdgcn_mfma_f32_16x16x32_bf16(*(const short8*)&W1bf[cb][(16+fr)*W1LD + 32 + quad*8], bk1, z1,    0,0,0);
      z2 = __builtin_amdgcn_mfma_f32_16x16x32_bf16(*(const short8*)&W1bf[cb][(32+fr)*W1LD + quad*8],      bk0, fzero, 0,0,0);
      z2 = __builtin_amdgcn_mfma_f32_16x16x32_bf16(*(const short8*)&W1bf[cb][(32+fr)*W1LD + 32 + quad*8], bk1, z2,    0,0,0);
      z3 = __builtin_amdgcn_mfma_f32_16x16x32_bf16(*(const short8*)&W1bf[cb][(48+fr)*W1LD + quad*8],      bk0, fzero, 0,0,0);
      z3 = __builtin_amdgcn_mfma_f32_16x16x32_bf16(*(const short8*)&W1bf[cb][(48+fr)*W1LD + 32 + quad*8], bk1, z3,    0,0,0);
      // LN-l2 backward
      f32x4 xh0,xh1,xh2,xh3;
      {
        float s1=0.f, s2=0.f;
        #pragma unroll
        for(int r=0;r<4;r++){
          z0[r] += b1v0[r];
          z1[r] += b1v1[r];
          z2[r] += b1v2[r];
          z3[r] += b1v3[r];
          s1 += z0[r]+z1[r]+z2[r]+z3[r];
          s2 += z0[r]*z0[r]+z1[r]*z1[r]+z2[r]*z2[r]+z3[r]*z3[r];
        }
        s1 = qsum(s1); s2 = qsum(s2);
        float mu = s1*(1.f/64.f);
        float var = s2*(1.f/64.f) - mu*mu;
        float rstd = rsqrtf(var + 1e-6f);
        float u1=0.f, u2=0.f;
        #pragma unroll
        for(int m=0;m<4;m++){
          f32x4* zp = (m==0)?&z0:(m==1)?&z1:(m==2)?&z2:&z3;
          f32x4* xp = (m==0)?&xh0:(m==1)?&xh1:(m==2)?&xh2:&xh3;
          #pragma unroll
          for(int r=0;r<4;r++){
            f32x2 wb = lwv[m*4+r];
            float xh = ((*zp)[r] - mu)*rstd;
            float gx = (wb[0]*xh + wb[1] - tg[m*4+r])*wb[0];
            (*xp)[r] = xh;
            (*zp)[r] = gx;
            u1 += gx; u2 += gx*xh;
          }
        }
        u1 = qsum(u1); u2 = qsum(u2);
        const float c64 = rstd*(1.f/64.f);
        #pragma unroll
        for(int m=0;m<4;m++){
          f32x4* zp = (m==0)?&z0:(m==1)?&z1:(m==2)?&z2:&z3;
          f32x4* xp = (m==0)?&xh0:(m==1)?&xh1:(m==2)?&xh2:&xh3;
          #pragma unroll
          for(int r=0;r<4;r++)
            (*zp)[r] = (64.f*(*zp)[r] - u1 - (*xp)[r]*u2)*c64;   // gradT
        }
      }
      // write own mtile of gradT; same-wave read-back (no barrier needed)
      f32x4 zsel = (wv==0)?z0:(wv==1)?z1:(wv==2)?z2:z3;
      #pragma unroll
      for(int r=0;r<4;r++)
        gradTbf[(wv*16+quad*4+r)*GTLD + fr] = f2bf(zsel[r]);
      asm volatile("s_waitcnt lgkmcnt(0)" ::: "memory");
      short8 ga = *(const short8*)&gradTbf[(wv*16+fr)*GTLD + quad*8];
      short8 e0 = *(const short8*)&exkT[cur][( 0+fr)*EKLD + quad*8];
      short8 e1 = *(const short8*)&exkT[cur][(16+fr)*EKLD + quad*8];
      short8 e2 = *(const short8*)&exkT[cur][(32+fr)*EKLD + quad*8];
      short8 e3 = *(const short8*)&exkT[cur][(48+fr)*EKLD + quad*8];
      wf0 = __builtin_amdgcn_mfma_f32_16x16x32_bf16(ga, e0, wf0, 0,0,0);
      wf1 = __builtin_amdgcn_mfma_f32_16x16x32_bf16(ga, e1, wf1, 0,0,0);
      wf2 = __builtin_amdgcn_mfma_f32_16x16x32_bf16(ga, e2, wf2, 0,0,0);
      wf3 = __builtin_amdgcn_mfma_f32_16x16x32_bf16(ga, e3, wf3, 0,0,0);
      #pragma unroll
      for(int r=0;r<4;r++){
        int d = wv*16+quad*4+r;
        W1bf[nbuf][d*W1LD +  0 + fr] = f2bf(wf0[r]);
        W1bf[nbuf][d*W1LD + 16 + fr] = f2bf(wf1[r]);
        W1bf[nbuf][d*W1LD + 32 + fr] = f2bf(wf2[r]);
        W1bf[nbuf][d*W1LD + 48 + fr] = f2bf(wf3[r]);
      }
    }
    else if (wv == 4){
      // prefetch out-path operands (old b1, xq^T, LN params)
      b1q0 = *(const f32x4*)&b1s[ 0+quad*4];
      b1q1 = *(const f32x4*)&b1s[16+quad*4];
      b1q2 = *(const f32x4*)&b1s[32+quad*4];
      b1q3 = *(const f32x4*)&b1s[48+quad*4];
      #pragma unroll
      for(int m=0;m<4;m++)
        #pragma unroll
        for(int r=0;r<4;r++){
          int d = m*16+quad*4+r;
          xq_r[m*4+r] = xqT[cur][d*TLD + fr];
          lw4[m*4+r]  = lwlb[d];
        }
      // Zq^T = W1t (x) xq
      short8 bq0 = *(const short8*)&xqbf[cur][fr*XLD + quad*8];
      short8 bq1 = *(const short8*)&xqbf[cur][fr*XLD + 32 + quad*8];
      zq0 = __builtin_amdgcn_mfma_f32_16x16x32_bf16(*(const short8*)&W1bf[cb][( 0+fr)*W1LD + quad*8],      bq0, fzero, 0,0,0);
      zq0 = __builtin_amdgcn_mfma_f32_16x16x32_bf16(*(const short8*)&W1bf[cb][( 0+fr)*W1LD + 32 + quad*8], bq1, zq0,   0,0,0);
      zq1 = __builtin_amdgcn_mfma_f32_16x16x32_bf16(*(const short8*)&W1bf[cb][(16+fr)*W1LD + quad*8],      bq0, fzero, 0,0,0);
      zq1 = __builtin_amdgcn_mfma_f32_16x16x32_bf16(*(const short8*)&W1bf[cb][(16+fr)*W1LD + 32 + quad*8], bq1, zq1,   0,0,0);
      zq2 = __builtin_amdgcn_mfma_f32_16x16x32_bf16(*(const short8*)&W1bf[cb][(32+fr)*W1LD + quad*8],      bq0, fzero, 0,0,0);
      zq2 = __builtin_amdgcn_mfma_f32_16x16x32_bf16(*(const short8*)&W1bf[cb][(32+fr)*W1LD + 32 + quad*8], bq1, zq2,   0,0,0);
      zq3 = __builtin_amdgcn_mfma_f32_16x16x32_bf16(*(const short8*)&W1bf[cb][(48+fr)*W1LD + quad*8],      bq0, fzero, 0,0,0);
      zq3 = __builtin_amdgcn_mfma_f32_16x16x32_bf16(*(const short8*)&W1bf[cb][(48+fr)*W1LD + 32 + quad*8], bq1, zq3,   0,0,0);
    }
    else if (wv == 7){
      // At = xq (x) xk : C[i][j]
      short8 aq0 = *(const short8*)&xqbf[cur][fr*XLD + quad*8];
      short8 aq1 = *(const short8*)&xqbf[cur][fr*XLD + 32 + quad*8];
      short8 bk0 = *(const short8*)&xkbf[cur][fr*XLD + quad*8];
      short8 bk1 = *(const short8*)&xkbf[cur][fr*XLD + 32 + quad*8];
      f32x4 at;
      at = __builtin_amdgcn_mfma_f32_16x16x32_bf16(aq0, bk0, fzero, 0,0,0);
      at = __builtin_amdgcn_mfma_f32_16x16x32_bf16(aq1, bk1, at,    0,0,0);
      float lrj = lrs[cur][fr]*(1.f/64.f);
      #pragma unroll
      for(int r=0;r<4;r++){
        int i = quad*4 + r;
        float val = (fr <= i) ? -tokl[i]*lrj*(1.f + at[r]) : 0.f;
        etaA[i*EALD + fr] = f2bf(val);
      }
    }
    BARS();

    // ---------------- region B ----------------
    if (wv == 4){
      // C2[d][i] = gradT (x) etaA ; Z1_bar^T = Zq^T + b1 + C2; LN; Y write
      short8 be = *(const short8*)&etaA[fr*EALD + quad*8];
      f32x4 c20,c21,c22,c23;
      c20 = __builtin_amdgcn_mfma_f32_16x16x32_bf16(*(const short8*)&gradTbf[( 0+fr)*GTLD + quad*8], be, fzero, 0,0,0);
      c21 = __builtin_amdgcn_mfma_f32_16x16x32_bf16(*(const short8*)&gradTbf[(16+fr)*GTLD + quad*8], be, fzero, 0,0,0);
      c22 = __builtin_amdgcn_mfma_f32_16x16x32_bf16(*(const short8*)&gradTbf[(32+fr)*GTLD + quad*8], be, fzero, 0,0,0);
      c23 = __builtin_amdgcn_mfma_f32_16x16x32_bf16(*(const short8*)&gradTbf[(48+fr)*GTLD + quad*8], be, fzero, 0,0,0);
      f32x4 zb0,zb1,zb2,zb3;
      float s1=0.f, s2=0.f;
      #pragma unroll
      for(int r=0;r<4;r++){
        zb0[r] = zq0[r] + b1q0[r] + c20[r];
        zb1[r] = zq1[r] + b1q1[r] + c21[r];
        zb2[r] = zq2[r] + b1q2[r] + c22[r];
        zb3[r] = zq3[r] + b1q3[r] + c23[r];
        s1 += zb0[r]+zb1[r]+zb2[r]+zb3[r];
        s2 += zb0[r]*zb0[r]+zb1[r]*zb1[r]+zb2[r]*zb2[r]+zb3[r]*zb3[r];
      }
      s1 = qsum(s1); s2 = qsum(s2);
      float mu = s1*(1.f/64.f);
      float var = s2*(1.f/64.f) - mu*mu;
      float rstd = rsqrtf(var + 1e-6f);
      #pragma unroll
      for(int m=0;m<4;m++){
        f32x4* zp = (m==0)?&zb0:(m==1)?&zb1:(m==2)?&zb2:&zb3;
        f32x4 o;
        #pragma unroll
        for(int r=0;r<4;r++){
          f32x2 wb = lw4[m*4+r];
          float xh = ((*zp)[r] - mu)*rstd;
          o[r] = xq_r[m*4+r] + xh*wb[0] + wb[1];
        }
        *(f32x4*)&Y[(rbase+fr)*2048 + h*64 + m*16 + quad*4] = o;
      }
    }
    else if (wv == 5){
      // b1 update: b1s[d] -= ct * sum_j lrs[j] * gradT[d][j]
      const int d = lane;
      short8 g0 = *(const short8*)&gradTbf[d*GTLD + 0];
      short8 g1 = *(const short8*)&gradTbf[d*GTLD + 8];
      float s = 0.f;
      #pragma unroll
      for(int j=0;j<8;j++) s += lrs[cur][j]   * bf2f((u16)g0[j]);
      #pragma unroll
      for(int j=0;j<8;j++) s += lrs[cur][8+j] * bf2f((u16)g1[j]);
      b1s[d] -= ct * s;
    }
    if (n<127) stage(nxt, Pq0,Pk0,Pv0,Pl0, Pq1,Pk1,Pv1,Pl1);
    BARS();
  }
}

// ---------------- host launch ----------------
extern "C" void kernel_launch(void* const* d_in, const int* in_sizes, int n_in,
                              void* d_out, int out_size, void* d_ws, size_t ws_size,
                              hipStream_t stream)
{
  const float* enc   = (const float*)d_in[0];
  const float* ln1w  = (const float*)d_in[1];
  const float* ln1b  = (const float*)d_in[2];
  const float* qw    = (const float*)d_in[3];
  const float* kw    = (const float*)d_in[4];
  const float* vw    = (const float*)d_in[5];
  const float* ow    = (const float*)d_in[6];
  const float* lrw   = (const float*)d_in[7];
  const float* lrb   = (const float*)d_in[8];
  const float* tio   = (const float*)d_in[9];
  const float* tnw   = (const float*)d_in[10];
  const float* tnb   = (const float*)d_in[11];
  const float* W1i   = (const float*)d_in[12];
  const float* b1i   = (const float*)d_in[13];
  const float* postw = (const float*)d_in[14];
  const float* postb = (const float*)d_in[15];
  const float* flnw  = (const float*)d_in[16];
  const float* flnb  = (const float*)d_in[17];
  const float* w1f   = (const float*)d_in[18];
  const float* b1f   = (const float*)d_in[19];
  const float* w2f   = (const float*)d_in[20];
  const float* b2f   = (const float*)d_in[21];
  float* out = (float*)d_out;

  char* ws = (char*)d_ws;
  size_t off = 0;
  auto alloc = [&](size_t bytes)->void*{ void* p = ws + off; off += (bytes + 255) & ~(size_t)255; return p; };
  u16*   regA  = (u16*)  alloc(8192ull*2048*2);   // x_bf -> ypost_bf -> z_bf
  u16*   wqkvT = (u16*)  alloc(6400ull*2048*2);   // [qT|kT|vT|lr(32)+zeros..6400); later oT/w1fT/w2fT
  u16*   XQKV  = (u16*)  alloc(8192ull*6272*2);   // later: h_bf
  float* yb    = (float*)alloc(8192ull*2048*4);   // y -> y2
  float* ropec = (float*)alloc(1024*4);
  float* ropes = (float*)alloc(1024*4);
  float* tokb  = (float*)alloc(64*4);

  u16* oT   = wqkvT;
  u16* w1fT = wqkvT + 2048ull*2048;
  u16* w2fT = w1fT + 1024ull*2048;
  u16* hbf  = XQKV;
  float* y2 = yb;

  static bool s_attr = false;
  if (!s_attr){
    s_attr = true;
    (void)hipFuncSetAttribute(reinterpret_cast<const void*>(gemm256<4>), hipFuncAttributeMaxDynamicSharedMemorySize, 131072);
    (void)hipFuncSetAttribute(reinterpret_cast<const void*>(gemm256<1>), hipFuncAttributeMaxDynamicSharedMemorySize, 131072);
    (void)hipFuncSetAttribute(reinterpret_cast<const void*>(gemm256<2>), hipFuncAttributeMaxDynamicSharedMemorySize, 131072);
    (void)hipFuncSetAttribute(reinterpret_cast<const void*>(gemm256<3>), hipFuncAttributeMaxDynamicSharedMemorySize, 131072);
  }

  rope_init<<<4, 256, 0, stream>>>(tio, ropec, ropes, tokb);

  dim3 tg1(64, 64);
  transpose_cast<<<tg1, 256, 0, stream>>>(qw, wqkvT,               2048, 2048);
  transpose_cast<<<tg1, 256, 0, stream>>>(kw, wqkvT + 2048ull*2048, 2048, 2048);
  transpose_cast<<<tg1, 256, 0, stream>>>(vw, wqkvT + 4096ull*2048, 2048, 2048);
  cast_lrw<<<2048, 256, 0, stream>>>(lrw, wqkvT + 6144ull*2048);

  ln_row<<<8192, 256, 0, stream>>>(enc, ln1w, ln1b, 1e-5f, regA);

  // QKV + lr projection: logical N=6400 (25 tiles), real cols 6272, ldc 6272
  gemm256<4><<<32*25, 512, 131072, stream>>>(regA, wqkvT, nullptr, XQKV,
                                             nullptr, nullptr, 6272, 6272, 2048, 25);

  // transpose remaining weights (reuses wqkvT region; QKV GEMM already consumed it)
  transpose_cast<<<tg1, 256, 0, stream>>>(ow, oT, 2048, 2048);
  dim3 tg2(64, 32);
  transpose_cast<<<tg2, 256, 0, stream>>>(w1f, w1fT, 2048, 1024);
  dim3 tg3(32, 64);
  transpose_cast<<<tg3, 256, 0, stream>>>(w2f, w2fT, 1024, 2048);

  // sequential TTT scan (MFMA formulation)
  ttt_scan<<<128, 512, 0, stream>>>(XQKV, ropec, ropes, tokb, tnw, tnb, lrb, W1i, b1i, yb);

  // post-LN + O-projection + residual(enc)
  ln_row<<<8192, 256, 0, stream>>>(yb, postw, postb, 1e-6f, regA);
  gemm256<1><<<32*8, 512, 131072, stream>>>(regA, oT, y2, nullptr,
                                            nullptr, enc, 2048, 2048, 2048, 8);

  // FFN
  ln_row<<<8192, 256, 0, stream>>>(y2, flnw, flnb, 1e-6f, regA);
  gemm256<2><<<32*4, 512, 131072, stream>>>(regA, w1fT, nullptr, hbf,
                                            b1f, nullptr, 1024, 1024, 2048, 4);
  gemm256<3><<<32*8, 512, 131072, stream>>>(hbf, w2fT, out, nullptr,
                                            b2f, y2, 2048, 2048, 1024, 8);
}

// Round 4
// 800.735 us; speedup vs baseline: 1.2468x; 1.0704x over previous
//
#include <hip/hip_runtime.h>

typedef unsigned short u16;
typedef __attribute__((ext_vector_type(8))) short short8;
typedef __attribute__((ext_vector_type(8))) unsigned short ushort8;
typedef __attribute__((ext_vector_type(4))) float f32x4;
typedef __attribute__((ext_vector_type(2))) float f32x2;
typedef __attribute__((ext_vector_type(2))) unsigned int uint2v;

#define DEV __device__ __forceinline__

DEV float bf2f(u16 u){ union{unsigned int i; float f;} v; v.i = ((unsigned int)u)<<16u; return v.f; }
DEV u16 f2bf(float f){ union{float f; unsigned int i;} v; v.f=f; unsigned int r = v.i + 0x7FFFu + ((v.i>>16)&1u); return (u16)(r>>16); }

DEV void gload16(const u16* g, u16* l){
  __builtin_amdgcn_global_load_lds((const __attribute__((address_space(1))) void*)g,
                                   (__attribute__((address_space(3))) void*)l, 16, 0, 0);
}

DEV float wsum(float v){
  v += __shfl_xor(v, 32, 64);
  v += __shfl_xor(v, 16, 64);
  v += __shfl_xor(v, 8, 64);
  v += __shfl_xor(v, 4, 64);
  v += __shfl_xor(v, 2, 64);
  v += __shfl_xor(v, 1, 64);
  return v;
}

// sum over the 4 lanes sharing (lane&15). permlane pair-sum is
// orientation-agnostic (a[0]+a[1] == v + v[lane^k]) -> safe. (R2-verified.)
#if __has_builtin(__builtin_amdgcn_permlane16_swap) && __has_builtin(__builtin_amdgcn_permlane32_swap)
DEV float qsum(float v){
  unsigned u = __float_as_uint(v);
  uint2v a = __builtin_amdgcn_permlane16_swap(u, u, false, false);
  float s = __uint_as_float(a[0]) + __uint_as_float(a[1]);
  unsigned u2 = __float_as_uint(s);
  uint2v bsw = __builtin_amdgcn_permlane32_swap(u2, u2, false, false);
  return __uint_as_float(bsw[0]) + __uint_as_float(bsw[1]);
}
#else
DEV float qsum(float v){
  v += __shfl_xor(v, 16, 64);
  v += __shfl_xor(v, 32, 64);
  return v;
}
#endif

// exact element v[lane^32]: MUST be orientation-correct -> use proven shfl.
// (R3 post-mortem: permlane32_swap pair-select orientation was wrong -> absmax 3.46)
DEV float swap32(float v){ return __shfl_xor(v, 32, 64); }

DEV float block_sum(float v, float* red){
  v = wsum(v);
  __syncthreads();
  if((threadIdx.x & 63u)==0) red[threadIdx.x>>6] = v;
  __syncthreads();
  return red[0]+red[1]+red[2]+red[3];
}

// raw workgroup barrier: drain own LDS ops only
#define BARS() do{ asm volatile("s_waitcnt lgkmcnt(0)" ::: "memory"); \
  __builtin_amdgcn_s_barrier(); __builtin_amdgcn_sched_barrier(0); }while(0)

// ---------------- LN over rows of 2048, bf16 out ----------------
__global__ __launch_bounds__(256) void ln_row(
    const float* __restrict__ in, const float* __restrict__ w, const float* __restrict__ bb,
    float eps, u16* __restrict__ outb)
{
  __shared__ float red[4];
  const int row = blockIdx.x, t = threadIdx.x;
  const float* p = in + (size_t)row*2048 + t*8;
  f32x4 a = *(const f32x4*)p;
  f32x4 c = *(const f32x4*)(p+4);
  float s = a[0]+a[1]+a[2]+a[3]+c[0]+c[1]+c[2]+c[3];
  s = block_sum(s, red);
  float mu = s*(1.f/2048.f);
  float vs = 0.f;
  #pragma unroll
  for(int j=0;j<4;j++){ float d=a[j]-mu; vs += d*d; }
  #pragma unroll
  for(int j=0;j<4;j++){ float d=c[j]-mu; vs += d*d; }
  vs = block_sum(vs, red);
  float rstd = rsqrtf(vs*(1.f/2048.f) + eps);
  f32x4 w0 = *(const f32x4*)(w + t*8);
  f32x4 w1 = *(const f32x4*)(w + t*8 + 4);
  f32x4 b0 = *(const f32x4*)(bb + t*8);
  f32x4 b1 = *(const f32x4*)(bb + t*8 + 4);
  ushort8 o;
  #pragma unroll
  for(int j=0;j<4;j++) o[j]   = f2bf((a[j]-mu)*rstd*w0[j] + b0[j]);
  #pragma unroll
  for(int j=0;j<4;j++) o[j+4] = f2bf((c[j]-mu)*rstd*w1[j] + b1[j]);
  *(ushort8*)(outb + (size_t)row*2048 + t*8) = o;
}

// ---------------- transpose + cast fp32 (K x N) -> bf16 (N x K) ----------------
__global__ __launch_bounds__(256) void transpose_cast(
    const float* __restrict__ src, u16* __restrict__ dst, int K, int N)
{
  __shared__ float tile[32][33];
  const int kb = blockIdx.x*32, nb = blockIdx.y*32;
  const int tx = threadIdx.x & 31, ty = threadIdx.x >> 5; // 32 x 8
  #pragma unroll
  for(int i=0;i<4;i++){
    int k = ty + i*8;
    tile[k][tx] = src[(size_t)(kb+k)*N + nb + tx];
  }
  __syncthreads();
  #pragma unroll
  for(int i=0;i<4;i++){
    int nn = ty + i*8;
    dst[(size_t)(nb+nn)*K + kb + tx] = f2bf(tile[tx][nn]);
  }
}

// cast lr_w (32 x 2048) into rows [0..31] of a 256x2048 block, zero the rest
__global__ __launch_bounds__(256) void cast_lrw(const float* __restrict__ lrw, u16* __restrict__ dst)
{
  int i = blockIdx.x*256 + threadIdx.x;       // 256*2048 total
  if (i < 32*2048) dst[i] = f2bf(lrw[i]);
  else dst[i] = 0;
}

// rope tables (pos 0..15, d 0..63) + tok vector
__global__ void rope_init(const float* __restrict__ tio, float* __restrict__ cosb,
                          float* __restrict__ sinb, float* __restrict__ tokb)
{
  int t = blockIdx.x*256 + threadIdx.x;
  if (t < 1024){
    int p = t>>6, d = t&63;
    float inv = powf(10000.f, -(float)(2*(d&31))/64.f);
    float fr = (float)p * inv;
    cosb[t] = cosf(fr);
    sinb[t] = sinf(fr);
  }
  if (blockIdx.x==0 && threadIdx.x<16)
    tokb[threadIdx.x] = fmaxf(1.f/(float)(threadIdx.x+1) + tio[threadIdx.x], 0.f);
}

// ================== 256x256 8-phase bf16 GEMM (BK=64, 8 waves) ==================
#define MM(MI,NI,AA,BB) acc[MI][NI] = __builtin_amdgcn_mfma_f32_16x16x32_bf16(AA, BB, acc[MI][NI], 0, 0, 0)

#define RD_A(D,KH,MF) (*(const short8*)(ldsb + ((D)<<16) + ((KH)<<14) + (wm<<13) + ((MF)<<10) + loff))
#define RD_B(D,KH,NF) (*(const short8*)(ldsb + ((D)<<16) + 32768 + ((KH)<<14) + (wn<<12) + ((NF)<<10) + loff))

#define PHASE(D,KH,MH,RB,STG,VM) { \
  __builtin_amdgcn_sched_barrier(0); \
  if (RB){ b0 = RD_B(D,KH,0); b1 = RD_B(D,KH,1); b2 = RD_B(D,KH,2); b3 = RD_B(D,KH,3); } \
  short8 a0 = RD_A(D,KH,4*(MH)+0); \
  short8 a1 = RD_A(D,KH,4*(MH)+1); \
  short8 a2 = RD_A(D,KH,4*(MH)+2); \
  short8 a3 = RD_A(D,KH,4*(MH)+3); \
  STG; \
  __builtin_amdgcn_sched_barrier(0); \
  __builtin_amdgcn_s_barrier(); \
  asm volatile("s_waitcnt lgkmcnt(0)" ::: "memory"); \
  __builtin_amdgcn_sched_barrier(0); \
  __builtin_amdgcn_s_setprio(1); \
  MM(4*(MH)+0,0,a0,b0); MM(4*(MH)+1,0,a1,b0); MM(4*(MH)+2,0,a2,b0); MM(4*(MH)+3,0,a3,b0); \
  MM(4*(MH)+0,1,a0,b1); MM(4*(MH)+1,1,a1,b1); MM(4*(MH)+2,1,a2,b1); MM(4*(MH)+3,1,a3,b1); \
  MM(4*(MH)+0,2,a0,b2); MM(4*(MH)+1,2,a1,b2); MM(4*(MH)+2,2,a2,b2); MM(4*(MH)+3,2,a3,b2); \
  MM(4*(MH)+0,3,a0,b3); MM(4*(MH)+1,3,a1,b3); MM(4*(MH)+2,3,a2,b3); MM(4*(MH)+3,3,a3,b3); \
  __builtin_amdgcn_s_setprio(0); \
  if (VM){ asm volatile("s_waitcnt vmcnt(8)" ::: "memory"); } \
  __builtin_amdgcn_sched_barrier(0); \
  __builtin_amdgcn_s_barrier(); \
}

template<int EPI>
__global__ __launch_bounds__(512, 2) void gemm256(
    const u16* __restrict__ A, const u16* __restrict__ Bt,
    float* __restrict__ C, u16* __restrict__ Cb,
    const float* __restrict__ bias, const float* __restrict__ resid,
    int Nld, int Nreal, int K, int ntN)
{
  extern __shared__ u16 lds[];
  const int t = threadIdx.x, lane = t&63, wv = t>>6;
  const int wm = wv>>2, wn = wv&3;          // 2 (M) x 4 (N) waves
  const int fr = lane&15, kq = lane>>4;

  int bid = blockIdx.x;
  {
    int nwg = gridDim.x;                    // bijective XCD swizzle
    int q = nwg>>3, r = nwg&7;
    int x = bid&7, l = bid>>3;
    bid = (x<r) ? (x*(q+1)+l) : (r*(q+1)+(x-r)*q+l);
  }
  const int bm = bid/ntN, bn = bid%ntN;

  f32x4 acc[8][4];
  #pragma unroll
  for(int i=0;i<8;i++)
    #pragma unroll
    for(int j=0;j<4;j++) acc[i][j]=(f32x4){0.f,0.f,0.f,0.f};

  const u16* gA = A  + (size_t)(bm*256)*K;
  const u16* gB = Bt + (size_t)(bn*256)*K;

  const int Ls   = (t&7) ^ ((t>>3)&7);
  const int rstg = ((t>>3)<<1) | (Ls>>2);
  const int cstg = (Ls&3)<<3;
  u16* const ldsw = lds + (wv<<9);

  const int Plane = (((fr&1)<<2) | kq) ^ (fr>>1);
  const int loff  = ((fr>>1)<<7) | (Plane<<4);
  const char* const ldsb = (const char*)lds;

  auto stA = [&](int d, int kh, int kts){
    u16* lb = ldsw + (d<<15) + (kh<<13);
    const u16* g = gA + (size_t)rstg*K + kts + (kh<<5) + cstg;
    gload16(g, lb);
    gload16(g + ((size_t)K<<7), lb + 4096);
  };
  auto stB = [&](int d, int kh, int kts){
    u16* lb = ldsw + (d<<15) + 16384 + (kh<<13);
    const u16* g = gB + (size_t)rstg*K + kts + (kh<<5) + cstg;
    gload16(g, lb);
    gload16(g + ((size_t)K<<7), lb + 4096);
  };

  stA(0,0,0); stB(0,0,0); stA(0,1,0); stB(0,1,0); stA(1,0,64); stB(1,0,64);
  asm volatile("s_waitcnt vmcnt(8)" ::: "memory");
  __builtin_amdgcn_sched_barrier(0);
  __builtin_amdgcn_s_barrier();

  for (int kt = 0; kt < K; kt += 128){
    const int ktp = (kt+128 < K) ? kt+128 : 0;
    const int ktq = (kt+192 < K) ? kt+192 : kt+192-K;
    short8 b0={0},b1={0},b2={0},b3={0};
    PHASE(0,0,0,1, stA(1,1,kt+64), 0)
    PHASE(0,0,1,0, stB(1,1,kt+64), 1)
    PHASE(0,1,0,1, stA(0,0,ktp),   0)
    PHASE(0,1,1,0, stB(0,0,ktp),   1)
    PHASE(1,0,0,1, stA(0,1,ktp),   0)
    PHASE(1,0,1,0, stB(0,1,ktp),   1)
    PHASE(1,1,0,1, stA(1,0,ktq),   0)
    PHASE(1,1,1,0, stB(1,0,ktq),   1)
  }

  const int cr = (lane>>4)<<2, cc = lane&15;
  #pragma unroll
  for(int mi=0;mi<8;mi++){
    #pragma unroll
    for(int ni=0;ni<4;ni++){
      const int row0 = bm*256 + wm*128 + mi*16 + cr;
      const int col  = bn*256 + wn*64  + ni*16 + cc;
      if (col < Nreal){
        #pragma unroll
        for(int rr=0;rr<4;rr++){
          size_t idx = (size_t)(row0+rr)*Nld + col;
          float v = acc[mi][ni][rr];
          if (EPI==1 || EPI==3) v += resid[idx];
          if (EPI==2 || EPI==3) v += bias[col];
          if (EPI==2){ v = fmaxf(v, 0.f); Cb[idx] = f2bf(v); }
          else if (EPI==4){ Cb[idx] = f2bf(v); }
          else C[idx] = v;
        }
      }
    }
  }
}

// ================== MFMA TTT scan ==================
// Per step, TWO regions (X | Y), one BARS each:
//  X: waves 0,1 compute the FULL Zk->LN-bwd->gradT chain (2x dup; wave0 writes
//     gradT mtiles 0,1, wave1 writes 2,3). wave 4: output chain of step n-1
//     (C2 from gradTbf[pb]/etaA[pb] + LN + Y stores) then Zq(n) into fresh regs.
//     wave 7: At -> etaA[cur].
//  Y: waves 0-3: W1 MFMA update (own mtile m=wv; read gradTbf[cur]+exkT[cur]),
//     write W1bf[cur^1]. wave 5: b1 update (16-term dot). all: stage(n+1).
// gradTbf/etaA double-buffered so X(n+1)'s output-read of step-n data never
// races X(n+1)'s writes. LN params + tok hoisted to registers. tgT/xqT are
// [i][d] so readers use ds_read_b128 x4 instead of 16 scalar b32.
#define W1LD 72   // bf16 elems per row of W1bf (pad 64->72)
#define XLD  72   // xqbf/xkbf row stride
#define GTLD 40   // gradTbf row stride (16 cols used, [16,32) zero for K=32 frags)
#define EKLD 40   // exkT row stride
#define EALD 40   // etaA row stride
#define TD2  68   // f32 [i][d] row stride (pad 64->68)

__global__ __launch_bounds__(512, 1) void ttt_scan(
    const u16* __restrict__ XQKV,   // 8192 x 6272 bf16: [q|k|v|lr_pre(32)+pad]
    const float* __restrict__ ropec, const float* __restrict__ ropes,
    const float* __restrict__ tokp,
    const float* __restrict__ nw, const float* __restrict__ nb,
    const float* __restrict__ lrb,
    const float* __restrict__ W1i,  // NH x 64 x 64  (W1i[h][k][d])
    const float* __restrict__ b1i,  // NH x 64
    float* __restrict__ Y)          // 8192 x 2048
{
  const int blk = blockIdx.x, b = blk>>5, h = blk&31;
  const int t = threadIdx.x, lane = t&63, wv = t>>6;
  const int fr = lane&15, quad = lane>>4;
  const int i0 = wv*2, i1 = i0+1;      // rows this wave stages

  __shared__ u16 W1bf[2][64*W1LD];     // double-buffered W1t[d][k] bf16
  __shared__ u16 xqbf[2][16*XLD];      // [i][k]
  __shared__ u16 xkbf[2][16*XLD];
  __shared__ u16 exkT[2][64*EKLD];     // [k][j] = -e_j * xk[j][k]
  __shared__ u16 gradTbf[2][64*GTLD];  // [d][j], double-buffered
  __shared__ u16 etaA[2][16*EALD];     // [i][j], double-buffered
  __shared__ float tgT2[2][16*TD2];    // [i][d] = (v - xk)[i][d]
  __shared__ float xqT2[2][16*TD2];    // [i][d]
  __shared__ float b1s[64];
  __shared__ float lrs[2][16];

  const float lrbh = lrb[h];
  const float cc0 = ropec[i0*64 + lane], ss0 = ropes[i0*64 + lane];
  const float cc1 = ropec[i1*64 + lane], ss1 = ropes[i1*64 + lane];
  const float ct = tokp[15]*(1.f/64.f);
  const float sg = (lane<32)? -1.f : 1.f;

  // loop-invariant LN params / tok in registers
  f32x2 lwr[16];
  #pragma unroll
  for(int m=0;m<4;m++)
    #pragma unroll
    for(int r=0;r<4;r++){
      int d = m*16+quad*4+r;
      lwr[m*4+r] = (f32x2){nw[h*64+d], nb[h*64+d]};
    }
  float tki[4];
  #pragma unroll
  for(int r=0;r<4;r++) tki[r] = tokp[quad*4+r];

  // ---- W1 state: wave wv (0..3) owns tiles (m=wv, n=0..3)
  f32x4 wf0, wf1, wf2, wf3;
  if (wv < 4){
    const float* wsrc = W1i + (size_t)h*4096;
    #pragma unroll
    for(int r=0;r<4;r++){
      int d = wv*16+quad*4+r;
      wf0[r] = wsrc[( 0+fr)*64 + d];
      wf1[r] = wsrc[(16+fr)*64 + d];
      wf2[r] = wsrc[(32+fr)*64 + d];
      wf3[r] = wsrc[(48+fr)*64 + d];
    }
    #pragma unroll
    for(int r=0;r<4;r++){
      int d = wv*16+quad*4+r;
      W1bf[0][d*W1LD +  0 + fr] = f2bf(wf0[r]);
      W1bf[0][d*W1LD + 16 + fr] = f2bf(wf1[r]);
      W1bf[0][d*W1LD + 32 + fr] = f2bf(wf2[r]);
      W1bf[0][d*W1LD + 48 + fr] = f2bf(wf3[r]);
    }
  }
  // zero pads (cols [16,40) so K=32 fragments see zeros) — both buffers
  for(int i=t;i<64*24;i+=512){
    int rr=i/24, cp=16+i%24;
    gradTbf[0][rr*GTLD+cp]=0; gradTbf[1][rr*GTLD+cp]=0;
    exkT[0][rr*EKLD+cp]=0;    exkT[1][rr*EKLD+cp]=0;
  }
  for(int i=t;i<16*24;i+=512){
    int rr=i/24, cp=16+i%24;
    etaA[0][rr*EALD+cp]=0; etaA[1][rr*EALD+cp]=0;
  }
  if (t<64) b1s[t]=b1i[h*64+t];

  // stage minibatch data (RoPE + transposed copies) into buffer bf
  auto stage = [&](int bf, u16 Pq0,u16 Pk0,u16 Pv0,u16 Pl0,
                           u16 Pq1,u16 Pk1,u16 Pv1,u16 Pl1){
    float q0=bf2f(Pq0), k0=bf2f(Pk0), v0=bf2f(Pv0);
    float q1=bf2f(Pq1), k1=bf2f(Pk1), v1=bf2f(Pv1);
    float qr0 = q0*cc0 + sg*swap32(q0)*ss0;
    float kr0 = k0*cc0 + sg*swap32(k0)*ss0;
    float qr1 = q1*cc1 + sg*swap32(q1)*ss1;
    float kr1 = k1*cc1 + sg*swap32(k1)*ss1;
    float lr0 = 1.f/(1.f + expf(-(bf2f(Pl0) + lrbh)));
    float lr1 = 1.f/(1.f + expf(-(bf2f(Pl1) + lrbh)));
    xqbf[bf][i0*XLD+lane] = f2bf(qr0);
    xqbf[bf][i1*XLD+lane] = f2bf(qr1);
    xkbf[bf][i0*XLD+lane] = f2bf(kr0);
    xkbf[bf][i1*XLD+lane] = f2bf(kr1);
    exkT[bf][lane*EKLD+i0] = f2bf(-ct*lr0*kr0);
    exkT[bf][lane*EKLD+i1] = f2bf(-ct*lr1*kr1);
    tgT2[bf][i0*TD2+lane] = v0 - kr0;
    tgT2[bf][i1*TD2+lane] = v1 - kr1;
    xqT2[bf][i0*TD2+lane] = qr0;
    xqT2[bf][i1*TD2+lane] = qr1;
    if (lane==0){ lrs[bf][i0]=lr0; lrs[bf][i1]=lr1; }
  };

  // prologue: stage minibatch 0
  {
    const size_t rb = (size_t)b*2048;
    const u16* p0 = XQKV + (rb+i0)*6272 + h*64 + lane;
    const u16* p1 = XQKV + (rb+i1)*6272 + h*64 + lane;
    u16 l0 = XQKV[(rb+i0)*6272 + 6144 + h];
    u16 l1 = XQKV[(rb+i1)*6272 + 6144 + h];
    stage(0, p0[0],p0[2048],p0[4096],l0, p1[0],p1[2048],p1[4096],l1);
  }
  __syncthreads();

  const f32x4 fzero = (f32x4){0.f,0.f,0.f,0.f};

  // wave-4 carried state (output pipeline depth 1)
  f32x4 zqP0=fzero, zqP1=fzero, zqP2=fzero, zqP3=fzero;
  f32x4 b1qP0=fzero, b1qP1=fzero, b1qP2=fzero, b1qP3=fzero;

  // output chain for the step whose data sits in buffer parity pbuf
  auto do_out = [&](int pbuf, size_t rb){
    short8 be = *(const short8*)&etaA[pbuf][fr*EALD + quad*8];
    f32x4 c20,c21,c22,c23;
    c20 = __builtin_amdgcn_mfma_f32_16x16x32_bf16(*(const short8*)&gradTbf[pbuf][( 0+fr)*GTLD + quad*8], be, fzero, 0,0,0);
    c21 = __builtin_amdgcn_mfma_f32_16x16x32_bf16(*(const short8*)&gradTbf[pbuf][(16+fr)*GTLD + quad*8], be, fzero, 0,0,0);
    c22 = __builtin_amdgcn_mfma_f32_16x16x32_bf16(*(const short8*)&gradTbf[pbuf][(32+fr)*GTLD + quad*8], be, fzero, 0,0,0);
    c23 = __builtin_amdgcn_mfma_f32_16x16x32_bf16(*(const short8*)&gradTbf[pbuf][(48+fr)*GTLD + quad*8], be, fzero, 0,0,0);
    f32x4 xqv0 = *(const f32x4*)&xqT2[pbuf][fr*TD2 +  0 + quad*4];
    f32x4 xqv1 = *(const f32x4*)&xqT2[pbuf][fr*TD2 + 16 + quad*4];
    f32x4 xqv2 = *(const f32x4*)&xqT2[pbuf][fr*TD2 + 32 + quad*4];
    f32x4 xqv3 = *(const f32x4*)&xqT2[pbuf][fr*TD2 + 48 + quad*4];
    f32x4 zb0,zb1,zb2,zb3;
    float s1=0.f, s2=0.f;
    #pragma unroll
    for(int r=0;r<4;r++){
      zb0[r] = zqP0[r] + b1qP0[r] + c20[r];
      zb1[r] = zqP1[r] + b1qP1[r] + c21[r];
      zb2[r] = zqP2[r] + b1qP2[r] + c22[r];
      zb3[r] = zqP3[r] + b1qP3[r] + c23[r];
      s1 += zb0[r]+zb1[r]+zb2[r]+zb3[r];
      s2 += zb0[r]*zb0[r]+zb1[r]*zb1[r]+zb2[r]*zb2[r]+zb3[r]*zb3[r];
    }
    s1 = qsum(s1); s2 = qsum(s2);
    float mu = s1*(1.f/64.f);
    float var = s2*(1.f/64.f) - mu*mu;
    float rstd = rsqrtf(var + 1e-6f);
    #pragma unroll
    for(int m=0;m<4;m++){
      f32x4* zp = (m==0)?&zb0:(m==1)?&zb1:(m==2)?&zb2:&zb3;
      const f32x4* xp = (m==0)?&xqv0:(m==1)?&xqv1:(m==2)?&xqv2:&xqv3;
      f32x4 o;
      #pragma unroll
      for(int r=0;r<4;r++){
        f32x2 wb = lwr[m*4+r];
        float xh = ((*zp)[r] - mu)*rstd;
        o[r] = (*xp)[r] + xh*wb[0] + wb[1];
      }
      *(f32x4*)&Y[(rb+fr)*2048 + h*64 + m*16 + quad*4] = o;
    }
  };

  for(int n=0;n<128;n++){
    const int cur = n&1, nxt = cur^1, pb = cur^1;
    const int cb = cur, nbuf = cur^1;          // W1 state buffers
    const size_t rbase = (size_t)b*2048 + n*16;

    // prefetch next minibatch into regs
    u16 Pq0=0,Pk0=0,Pv0=0,Pl0=0,Pq1=0,Pk1=0,Pv1=0,Pl1=0;
    if (n<127){
      const size_t rb2 = rbase + 16;
      const u16* p0 = XQKV + (rb2+i0)*6272 + h*64 + lane;
      const u16* p1 = XQKV + (rb2+i1)*6272 + h*64 + lane;
      Pq0=p0[0]; Pk0=p0[2048]; Pv0=p0[4096];
      Pq1=p1[0]; Pk1=p1[2048]; Pv1=p1[4096];
      Pl0=XQKV[(rb2+i0)*6272 + 6144 + h];
      Pl1=XQKV[(rb2+i1)*6272 + 6144 + h];
    }

    // ---------------- region X ----------------
    if (wv < 2){
      // hoisted operand loads
      f32x4 b1v0 = *(const f32x4*)&b1s[ 0+quad*4];
      f32x4 b1v1 = *(const f32x4*)&b1s[16+quad*4];
      f32x4 b1v2 = *(const f32x4*)&b1s[32+quad*4];
      f32x4 b1v3 = *(const f32x4*)&b1s[48+quad*4];
      f32x4 tgv0 = *(const f32x4*)&tgT2[cur][fr*TD2 +  0 + quad*4];
      f32x4 tgv1 = *(const f32x4*)&tgT2[cur][fr*TD2 + 16 + quad*4];
      f32x4 tgv2 = *(const f32x4*)&tgT2[cur][fr*TD2 + 32 + quad*4];
      f32x4 tgv3 = *(const f32x4*)&tgT2[cur][fr*TD2 + 48 + quad*4];
      // Zk^T = W1t (x) xk : C[d][i], full 64x16 (dup x2: waves 0,1)
      short8 bk0 = *(const short8*)&xkbf[cur][fr*XLD + quad*8];
      short8 bk1 = *(const short8*)&xkbf[cur][fr*XLD + 32 + quad*8];
      f32x4 z0,z1,z2,z3;
      z0 = __builtin_amdgcn_mfma_f32_16x16x32_bf16(*(const short8*)&W1bf[cb][( 0+fr)*W1LD + quad*8],      bk0, fzero, 0,0,0);
      z0 = __builtin_amdgcn_mfma_f32_16x16x32_bf16(*(const short8*)&W1bf[cb][( 0+fr)*W1LD + 32 + quad*8], bk1, z0,    0,0,0);
      z1 = __builtin_amdgcn_mfma_f32_16x16x32_bf16(*(const short8*)&W1bf[cb][(16+fr)*W1LD + quad*8],      bk0, fzero, 0,0,0);
      z1 = __builtin_amdgcn_mfma_f32_16x16x32_bf16(*(const short8*)&W1bf[cb][(16+fr)*W1LD + 32 + quad*8], bk1, z1,    0,0,0);
      z2 = __builtin_amdgcn_mfma_f32_16x16x32_bf16(*(const short8*)&W1bf[cb][(32+fr)*W1LD + quad*8],      bk0, fzero, 0,0,0);
      z2 = __builtin_amdgcn_mfma_f32_16x16x32_bf16(*(const short8*)&W1bf[cb][(32+fr)*W1LD + 32 + quad*8], bk1, z2,    0,0,0);
      z3 = __builtin_amdgcn_mfma_f32_16x16x32_bf16(*(const short8*)&W1bf[cb][(48+fr)*W1LD + quad*8],      bk0, fzero, 0,0,0);
      z3 = __builtin_amdgcn_mfma_f32_16x16x32_bf16(*(const short8*)&W1bf[cb][(48+fr)*W1LD + 32 + quad*8], bk1, z3,    0,0,0);
      // LN-l2 backward
      f32x4 xh0,xh1,xh2,xh3;
      {
        float s1=0.f, s2=0.f;
        #pragma unroll
        for(int r=0;r<4;r++){
          z0[r] += b1v0[r];
          z1[r] += b1v1[r];
          z2[r] += b1v2[r];
          z3[r] += b1v3[r];
          s1 += z0[r]+z1[r]+z2[r]+z3[r];
          s2 += z0[r]*z0[r]+z1[r]*z1[r]+z2[r]*z2[r]+z3[r]*z3[r];
        }
        s1 = qsum(s1); s2 = qsum(s2);
        float mu = s1*(1.f/64.f);
        float var = s2*(1.f/64.f) - mu*mu;
        float rstd = rsqrtf(var + 1e-6f);
        float u1=0.f, u2=0.f;
        #pragma unroll
        for(int m=0;m<4;m++){
          f32x4* zp = (m==0)?&z0:(m==1)?&z1:(m==2)?&z2:&z3;
          f32x4* xp = (m==0)?&xh0:(m==1)?&xh1:(m==2)?&xh2:&xh3;
          const f32x4* tp = (m==0)?&tgv0:(m==1)?&tgv1:(m==2)?&tgv2:&tgv3;
          #pragma unroll
          for(int r=0;r<4;r++){
            f32x2 wb = lwr[m*4+r];
            float xh = ((*zp)[r] - mu)*rstd;
            float gx = (wb[0]*xh + wb[1] - (*tp)[r])*wb[0];
            (*xp)[r] = xh;
            (*zp)[r] = gx;
            u1 += gx; u2 += gx*xh;
          }
        }
        u1 = qsum(u1); u2 = qsum(u2);
        const float c64 = rstd*(1.f/64.f);
        #pragma unroll
        for(int m=0;m<4;m++){
          f32x4* zp = (m==0)?&z0:(m==1)?&z1:(m==2)?&z2:&z3;
          f32x4* xp = (m==0)?&xh0:(m==1)?&xh1:(m==2)?&xh2:&xh3;
          #pragma unroll
          for(int r=0;r<4;r++)
            (*zp)[r] = (64.f*(*zp)[r] - u1 - (*xp)[r]*u2)*c64;   // gradT
        }
      }
      // wave0 writes mtiles 0,1; wave1 writes 2,3
      f32x4 zA = (wv==0)? z0 : z2;
      f32x4 zB = (wv==0)? z1 : z3;
      const int rb0 = wv*32;
      #pragma unroll
      for(int r=0;r<4;r++){
        gradTbf[cur][(rb0+quad*4+r)*GTLD + fr]    = f2bf(zA[r]);
        gradTbf[cur][(rb0+16+quad*4+r)*GTLD + fr] = f2bf(zB[r]);
      }
    }
    else if (wv == 4){
      // Zq(n): independent MFMAs into fresh regs
      short8 bq0 = *(const short8*)&xqbf[cur][fr*XLD + quad*8];
      short8 bq1 = *(const short8*)&xqbf[cur][fr*XLD + 32 + quad*8];
      f32x4 zqN0,zqN1,zqN2,zqN3;
      zqN0 = __builtin_amdgcn_mfma_f32_16x16x32_bf16(*(const short8*)&W1bf[cb][( 0+fr)*W1LD + quad*8],      bq0, fzero, 0,0,0);
      zqN0 = __builtin_amdgcn_mfma_f32_16x16x32_bf16(*(const short8*)&W1bf[cb][( 0+fr)*W1LD + 32 + quad*8], bq1, zqN0,  0,0,0);
      zqN1 = __builtin_amdgcn_mfma_f32_16x16x32_bf16(*(const short8*)&W1bf[cb][(16+fr)*W1LD + quad*8],      bq0, fzero, 0,0,0);
      zqN1 = __builtin_amdgcn_mfma_f32_16x16x32_bf16(*(const short8*)&W1bf[cb][(16+fr)*W1LD + 32 + quad*8], bq1, zqN1,  0,0,0);
      zqN2 = __builtin_amdgcn_mfma_f32_16x16x32_bf16(*(const short8*)&W1bf[cb][(32+fr)*W1LD + quad*8],      bq0, fzero, 0,0,0);
      zqN2 = __builtin_amdgcn_mfma_f32_16x16x32_bf16(*(const short8*)&W1bf[cb][(32+fr)*W1LD + 32 + quad*8], bq1, zqN2,  0,0,0);
      zqN3 = __builtin_amdgcn_mfma_f32_16x16x32_bf16(*(const short8*)&W1bf[cb][(48+fr)*W1LD + quad*8],      bq0, fzero, 0,0,0);
      zqN3 = __builtin_amdgcn_mfma_f32_16x16x32_bf16(*(const short8*)&W1bf[cb][(48+fr)*W1LD + 32 + quad*8], bq1, zqN3,  0,0,0);
      // output of step n-1 (reads step-(n-1) buffers, consumes zqP/b1qP)
      if (n > 0) do_out(pb, rbase - 16);
      // rotate pipeline state
      zqP0=zqN0; zqP1=zqN1; zqP2=zqN2; zqP3=zqN3;
      b1qP0 = *(const f32x4*)&b1s[ 0+quad*4];   // b1 pre-update for step n
      b1qP1 = *(const f32x4*)&b1s[16+quad*4];
      b1qP2 = *(const f32x4*)&b1s[32+quad*4];
      b1qP3 = *(const f32x4*)&b1s[48+quad*4];
    }
    else if (wv == 7){
      // At = xq (x) xk : C[i][j] -> etaA[cur]
      short8 aq0 = *(const short8*)&xqbf[cur][fr*XLD + quad*8];
      short8 aq1 = *(const short8*)&xqbf[cur][fr*XLD + 32 + quad*8];
      short8 bk0 = *(const short8*)&xkbf[cur][fr*XLD + quad*8];
      short8 bk1 = *(const short8*)&xkbf[cur][fr*XLD + 32 + quad*8];
      f32x4 at;
      at = __builtin_amdgcn_mfma_f32_16x16x32_bf16(aq0, bk0, fzero, 0,0,0);
      at = __builtin_amdgcn_mfma_f32_16x16x32_bf16(aq1, bk1, at,    0,0,0);
      float lrj = lrs[cur][fr]*(1.f/64.f);
      #pragma unroll
      for(int r=0;r<4;r++){
        int i = quad*4 + r;
        float val = (fr <= i) ? -tki[r]*lrj*(1.f + at[r]) : 0.f;
        etaA[cur][i*EALD + fr] = f2bf(val);
      }
    }
    BARS();

    // ---------------- region Y ----------------
    if (wv < 4){
      // W1 update: wave wv owns mtile m=wv, tiles n=0..3
      short8 ga = *(const short8*)&gradTbf[cur][(wv*16+fr)*GTLD + quad*8];
      short8 e0 = *(const short8*)&exkT[cur][( 0+fr)*EKLD + quad*8];
      short8 e1 = *(const short8*)&exkT[cur][(16+fr)*EKLD + quad*8];
      short8 e2 = *(const short8*)&exkT[cur][(32+fr)*EKLD + quad*8];
      short8 e3 = *(const short8*)&exkT[cur][(48+fr)*EKLD + quad*8];
      wf0 = __builtin_amdgcn_mfma_f32_16x16x32_bf16(ga, e0, wf0, 0,0,0);
      wf1 = __builtin_amdgcn_mfma_f32_16x16x32_bf16(ga, e1, wf1, 0,0,0);
      wf2 = __builtin_amdgcn_mfma_f32_16x16x32_bf16(ga, e2, wf2, 0,0,0);
      wf3 = __builtin_amdgcn_mfma_f32_16x16x32_bf16(ga, e3, wf3, 0,0,0);
      #pragma unroll
      for(int r=0;r<4;r++){
        int d = wv*16+quad*4+r;
        W1bf[nbuf][d*W1LD +  0 + fr] = f2bf(wf0[r]);
        W1bf[nbuf][d*W1LD + 16 + fr] = f2bf(wf1[r]);
        W1bf[nbuf][d*W1LD + 32 + fr] = f2bf(wf2[r]);
        W1bf[nbuf][d*W1LD + 48 + fr] = f2bf(wf3[r]);
      }
    }
    else if (wv == 5){
      // b1 update: b1s[d] -= ct * sum_j lrs[j] * gradT[d][j]
      const int d = lane;
      short8 g0 = *(const short8*)&gradTbf[cur][d*GTLD + 0];
      short8 g1 = *(const short8*)&gradTbf[cur][d*GTLD + 8];
      float s = 0.f;
      #pragma unroll
      for(int j=0;j<8;j++) s += lrs[cur][j]   * bf2f((u16)g0[j]);
      #pragma unroll
      for(int j=0;j<8;j++) s += lrs[cur][8+j] * bf2f((u16)g1[j]);
      b1s[d] -= ct * s;
    }
    if (n<127) stage(nxt, Pq0,Pk0,Pv0,Pl0, Pq1,Pk1,Pv1,Pl1);
    BARS();
  }

  // epilogue: output of the last step (n=127, buffers parity 1)
  if (wv == 4) do_out(1, (size_t)b*2048 + 127*16);
}

// ---------------- host launch ----------------
extern "C" void kernel_launch(void* const* d_in, const int* in_sizes, int n_in,
                              void* d_out, int out_size, void* d_ws, size_t ws_size,
                              hipStream_t stream)
{
  const float* enc   = (const float*)d_in[0];
  const float* ln1w  = (const float*)d_in[1];
  const float* ln1b  = (const float*)d_in[2];
  const float* qw    = (const float*)d_in[3];
  const float* kw    = (const float*)d_in[4];
  const float* vw    = (const float*)d_in[5];
  const float* ow    = (const float*)d_in[6];
  const float* lrw   = (const float*)d_in[7];
  const float* lrb   = (const float*)d_in[8];
  const float* tio   = (const float*)d_in[9];
  const float* tnw   = (const float*)d_in[10];
  const float* tnb   = (const float*)d_in[11];
  const float* W1i   = (const float*)d_in[12];
  const float* b1i   = (const float*)d_in[13];
  const float* postw = (const float*)d_in[14];
  const float* postb = (const float*)d_in[15];
  const float* flnw  = (const float*)d_in[16];
  const float* flnb  = (const float*)d_in[17];
  const float* w1f   = (const float*)d_in[18];
  const float* b1f   = (const float*)d_in[19];
  const float* w2f   = (const float*)d_in[20];
  const float* b2f   = (const float*)d_in[21];
  float* out = (float*)d_out;

  char* ws = (char*)d_ws;
  size_t off = 0;
  auto alloc = [&](size_t bytes)->void*{ void* p = ws + off; off += (bytes + 255) & ~(size_t)255; return p; };
  u16*   regA  = (u16*)  alloc(8192ull*2048*2);   // x_bf -> ypost_bf -> z_bf
  u16*   wqkvT = (u16*)  alloc(6400ull*2048*2);   // [qT|kT|vT|lr(32)+zeros..6400); later oT/w1fT/w2fT
  u16*   XQKV  = (u16*)  alloc(8192ull*6272*2);   // later: h_bf
  float* yb    = (float*)alloc(8192ull*2048*4);   // y -> y2
  float* ropec = (float*)alloc(1024*4);
  float* ropes = (float*)alloc(1024*4);
  float* tokb  = (float*)alloc(64*4);

  u16* oT   = wqkvT;
  u16* w1fT = wqkvT + 2048ull*2048;
  u16* w2fT = w1fT + 1024ull*2048;
  u16* hbf  = XQKV;
  float* y2 = yb;

  static bool s_attr = false;
  if (!s_attr){
    s_attr = true;
    (void)hipFuncSetAttribute(reinterpret_cast<const void*>(gemm256<4>), hipFuncAttributeMaxDynamicSharedMemorySize, 131072);
    (void)hipFuncSetAttribute(reinterpret_cast<const void*>(gemm256<1>), hipFuncAttributeMaxDynamicSharedMemorySize, 131072);
    (void)hipFuncSetAttribute(reinterpret_cast<const void*>(gemm256<2>), hipFuncAttributeMaxDynamicSharedMemorySize, 131072);
    (void)hipFuncSetAttribute(reinterpret_cast<const void*>(gemm256<3>), hipFuncAttributeMaxDynamicSharedMemorySize, 131072);
  }

  rope_init<<<4, 256, 0, stream>>>(tio, ropec, ropes, tokb);

  dim3 tg1(64, 64);
  transpose_cast<<<tg1, 256, 0, stream>>>(qw, wqkvT,               2048, 2048);
  transpose_cast<<<tg1, 256, 0, stream>>>(kw, wqkvT + 2048ull*2048, 2048, 2048);
  transpose_cast<<<tg1, 256, 0, stream>>>(vw, wqkvT + 4096ull*2048, 2048, 2048);
  cast_lrw<<<2048, 256, 0, stream>>>(lrw, wqkvT + 6144ull*2048);

  ln_row<<<8192, 256, 0, stream>>>(enc, ln1w, ln1b, 1e-5f, regA);

  // QKV + lr projection: logical N=6400 (25 tiles), real cols 6272, ldc 6272
  gemm256<4><<<32*25, 512, 131072, stream>>>(regA, wqkvT, nullptr, XQKV,
                                             nullptr, nullptr, 6272, 6272, 2048, 25);

  // transpose remaining weights (reuses wqkvT region; QKV GEMM already consumed it)
  transpose_cast<<<tg1, 256, 0, stream>>>(ow, oT, 2048, 2048);
  dim3 tg2(64, 32);
  transpose_cast<<<tg2, 256, 0, stream>>>(w1f, w1fT, 2048, 1024);
  dim3 tg3(32, 64);
  transpose_cast<<<tg3, 256, 0, stream>>>(w2f, w2fT, 1024, 2048);

  // sequential TTT scan (MFMA formulation)
  ttt_scan<<<128, 512, 0, stream>>>(XQKV, ropec, ropes, tokb, tnw, tnb, lrb, W1i, b1i, yb);

  // post-LN + O-projection + residual(enc)
  ln_row<<<8192, 256, 0, stream>>>(yb, postw, postb, 1e-6f, regA);
  gemm256<1><<<32*8, 512, 131072, stream>>>(regA, oT, y2, nullptr,
                                            nullptr, enc, 2048, 2048, 2048, 8);

  // FFN
  ln_row<<<8192, 256, 0, stream>>>(y2, flnw, flnb, 1e-6f, regA);
  gemm256<2><<<32*4, 512, 131072, stream>>>(regA, w1fT, nullptr, hbf,
                                            b1f, nullptr, 1024, 1024, 2048, 4);
  gemm256<3><<<32*8, 512, 131072, stream>>>(hbf, w2fT, out, nullptr,
                                            b2f, y2, 2048, 2048, 1024, 8);
}

// Round 6
// 768.557 us; speedup vs baseline: 1.2990x; 1.0419x over previous
//
#include <hip/hip_runtime.h>

typedef unsigned short u16;
typedef __attribute__((ext_vector_type(8))) short short8;
typedef __attribute__((ext_vector_type(8))) unsigned short ushort8;
typedef __attribute__((ext_vector_type(4))) unsigned short us4;
typedef __attribute__((ext_vector_type(4))) float f32x4;
typedef __attribute__((ext_vector_type(2))) float f32x2;
typedef __attribute__((ext_vector_type(2))) unsigned int uint2v;

#define DEV __device__ __forceinline__

DEV float bf2f(u16 u){ union{unsigned int i; float f;} v; v.i = ((unsigned int)u)<<16u; return v.f; }
DEV u16 f2bf(float f){ union{float f; unsigned int i;} v; v.f=f; unsigned int r = v.i + 0x7FFFu + ((v.i>>16)&1u); return (u16)(r>>16); }

DEV void gload16(const u16* g, u16* l){
  __builtin_amdgcn_global_load_lds((const __attribute__((address_space(1))) void*)g,
                                   (__attribute__((address_space(3))) void*)l, 16, 0, 0);
}

DEV float wsum(float v){
  v += __shfl_xor(v, 32, 64);
  v += __shfl_xor(v, 16, 64);
  v += __shfl_xor(v, 8, 64);
  v += __shfl_xor(v, 4, 64);
  v += __shfl_xor(v, 2, 64);
  v += __shfl_xor(v, 1, 64);
  return v;
}

// sum over the 4 lanes sharing (lane&15). permlane pair-sum is
// orientation-agnostic (a[0]+a[1] == v + v[lane^k]) -> safe. (R2-verified.)
#if __has_builtin(__builtin_amdgcn_permlane16_swap) && __has_builtin(__builtin_amdgcn_permlane32_swap)
DEV float qsum(float v){
  unsigned u = __float_as_uint(v);
  uint2v a = __builtin_amdgcn_permlane16_swap(u, u, false, false);
  float s = __uint_as_float(a[0]) + __uint_as_float(a[1]);
  unsigned u2 = __float_as_uint(s);
  uint2v bsw = __builtin_amdgcn_permlane32_swap(u2, u2, false, false);
  return __uint_as_float(bsw[0]) + __uint_as_float(bsw[1]);
}
#else
DEV float qsum(float v){
  v += __shfl_xor(v, 16, 64);
  v += __shfl_xor(v, 32, 64);
  return v;
}
#endif

// exact element v[lane^32]: MUST be orientation-correct -> proven shfl only.
// (R3 post-mortem: permlane32_swap pair-select orientation was wrong.)
DEV float swap32(float v){ return __shfl_xor(v, 32, 64); }

// raw workgroup barrier: drain own LDS ops only
#define BARS() do{ asm volatile("s_waitcnt lgkmcnt(0)" ::: "memory"); \
  __builtin_amdgcn_s_barrier(); __builtin_amdgcn_sched_barrier(0); }while(0)

// ---------------- LN over rows of 2048, one row per WAVE (no block barriers) ----------------
__global__ __launch_bounds__(256) void ln_row(
    const float* __restrict__ in, const float* __restrict__ w, const float* __restrict__ bb,
    float eps, u16* __restrict__ outb)
{
  const int wv = threadIdx.x>>6, lane = threadIdx.x&63;
  const int row = blockIdx.x*4 + wv;
  const float* p = in + (size_t)row*2048 + lane*4;
  f32x4 a[8];
  #pragma unroll
  for(int j=0;j<8;j++) a[j] = *(const f32x4*)(p + j*256);
  float s = 0.f;
  #pragma unroll
  for(int j=0;j<8;j++) s += a[j][0]+a[j][1]+a[j][2]+a[j][3];
  s = wsum(s);
  float mu = s*(1.f/2048.f);
  float vs = 0.f;
  #pragma unroll
  for(int j=0;j<8;j++)
    #pragma unroll
    for(int r=0;r<4;r++){ float d=a[j][r]-mu; vs += d*d; }
  vs = wsum(vs);
  float rstd = rsqrtf(vs*(1.f/2048.f) + eps);
  #pragma unroll
  for(int j=0;j<8;j++){
    f32x4 wj = *(const f32x4*)(w  + j*256 + lane*4);
    f32x4 bj = *(const f32x4*)(bb + j*256 + lane*4);
    us4 o;
    #pragma unroll
    for(int r=0;r<4;r++) o[r] = f2bf((a[j][r]-mu)*rstd*wj[r] + bj[r]);
    *(us4*)(outb + (size_t)row*2048 + j*256 + lane*4) = o;
  }
}

// ---------------- transpose + cast fp32 (K x N) -> bf16 (N x K) ----------------
__global__ __launch_bounds__(256) void transpose_cast(
    const float* __restrict__ src, u16* __restrict__ dst, int K, int N)
{
  __shared__ float tile[32][33];
  const int kb = blockIdx.x*32, nb = blockIdx.y*32;
  const int tx = threadIdx.x & 31, ty = threadIdx.x >> 5; // 32 x 8
  #pragma unroll
  for(int i=0;i<4;i++){
    int k = ty + i*8;
    tile[k][tx] = src[(size_t)(kb+k)*N + nb + tx];
  }
  __syncthreads();
  #pragma unroll
  for(int i=0;i<4;i++){
    int nn = ty + i*8;
    dst[(size_t)(nb+nn)*K + kb + tx] = f2bf(tile[tx][nn]);
  }
}

// cast lr_w (32 x 2048) into rows [0..31] of a 256x2048 block, zero the rest
__global__ __launch_bounds__(256) void cast_lrw(const float* __restrict__ lrw, u16* __restrict__ dst)
{
  int i = blockIdx.x*256 + threadIdx.x;       // 256*2048 total
  if (i < 32*2048) dst[i] = f2bf(lrw[i]);
  else dst[i] = 0;
}

// rope tables (pos 0..15, d 0..63) + tok vector
__global__ void rope_init(const float* __restrict__ tio, float* __restrict__ cosb,
                          float* __restrict__ sinb, float* __restrict__ tokb)
{
  int t = blockIdx.x*256 + threadIdx.x;
  if (t < 1024){
    int p = t>>6, d = t&63;
    float inv = powf(10000.f, -(float)(2*(d&31))/64.f);
    float fr = (float)p * inv;
    cosb[t] = cosf(fr);
    sinb[t] = sinf(fr);
  }
  if (blockIdx.x==0 && threadIdx.x<16)
    tokb[threadIdx.x] = fmaxf(1.f/(float)(threadIdx.x+1) + tio[threadIdx.x], 0.f);
}

// ================== 256x256 8-phase bf16 GEMM (BK=64, 8 waves) ==================
#define MM(MI,NI,AA,BB) acc[MI][NI] = __builtin_amdgcn_mfma_f32_16x16x32_bf16(AA, BB, acc[MI][NI], 0, 0, 0)

#define RD_A(D,KH,MF) (*(const short8*)(ldsb + ((D)<<16) + ((KH)<<14) + (wm<<13) + ((MF)<<10) + loff))
#define RD_B(D,KH,NF) (*(const short8*)(ldsb + ((D)<<16) + 32768 + ((KH)<<14) + (wn<<12) + ((NF)<<10) + loff))

#define PHASE(D,KH,MH,RB,STG,VM) { \
  __builtin_amdgcn_sched_barrier(0); \
  if (RB){ b0 = RD_B(D,KH,0); b1 = RD_B(D,KH,1); b2 = RD_B(D,KH,2); b3 = RD_B(D,KH,3); } \
  short8 a0 = RD_A(D,KH,4*(MH)+0); \
  short8 a1 = RD_A(D,KH,4*(MH)+1); \
  short8 a2 = RD_A(D,KH,4*(MH)+2); \
  short8 a3 = RD_A(D,KH,4*(MH)+3); \
  STG; \
  __builtin_amdgcn_sched_barrier(0); \
  __builtin_amdgcn_s_barrier(); \
  asm volatile("s_waitcnt lgkmcnt(0)" ::: "memory"); \
  __builtin_amdgcn_sched_barrier(0); \
  __builtin_amdgcn_s_setprio(1); \
  MM(4*(MH)+0,0,a0,b0); MM(4*(MH)+1,0,a1,b0); MM(4*(MH)+2,0,a2,b0); MM(4*(MH)+3,0,a3,b0); \
  MM(4*(MH)+0,1,a0,b1); MM(4*(MH)+1,1,a1,b1); MM(4*(MH)+2,1,a2,b1); MM(4*(MH)+3,1,a3,b1); \
  MM(4*(MH)+0,2,a0,b2); MM(4*(MH)+1,2,a1,b2); MM(4*(MH)+2,2,a2,b2); MM(4*(MH)+3,2,a3,b2); \
  MM(4*(MH)+0,3,a0,b3); MM(4*(MH)+1,3,a1,b3); MM(4*(MH)+2,3,a2,b3); MM(4*(MH)+3,3,a3,b3); \
  __builtin_amdgcn_s_setprio(0); \
  if (VM){ asm volatile("s_waitcnt vmcnt(8)" ::: "memory"); } \
  __builtin_amdgcn_sched_barrier(0); \
  __builtin_amdgcn_s_barrier(); \
}

template<int EPI>
__global__ __launch_bounds__(512, 2) void gemm256(
    const u16* __restrict__ A, const u16* __restrict__ Bt,
    float* __restrict__ C, u16* __restrict__ Cb,
    const float* __restrict__ bias, const float* __restrict__ resid,
    int Nld, int Nreal, int K, int ntN)
{
  extern __shared__ u16 lds[];
  const int t = threadIdx.x, lane = t&63, wv = t>>6;
  const int wm = wv>>2, wn = wv&3;          // 2 (M) x 4 (N) waves
  const int fr = lane&15, kq = lane>>4;

  int bid = blockIdx.x;
  {
    int nwg = gridDim.x;                    // bijective XCD swizzle
    int q = nwg>>3, r = nwg&7;
    int x = bid&7, l = bid>>3;
    bid = (x<r) ? (x*(q+1)+l) : (r*(q+1)+(x-r)*q+l);
  }
  const int bm = bid/ntN, bn = bid%ntN;

  f32x4 acc[8][4];
  #pragma unroll
  for(int i=0;i<8;i++)
    #pragma unroll
    for(int j=0;j<4;j++) acc[i][j]=(f32x4){0.f,0.f,0.f,0.f};

  const u16* gA = A  + (size_t)(bm*256)*K;
  const u16* gB = Bt + (size_t)(bn*256)*K;

  const int Ls   = (t&7) ^ ((t>>3)&7);
  const int rstg = ((t>>3)<<1) | (Ls>>2);
  const int cstg = (Ls&3)<<3;
  u16* const ldsw = lds + (wv<<9);

  const int Plane = (((fr&1)<<2) | kq) ^ (fr>>1);
  const int loff  = ((fr>>1)<<7) | (Plane<<4);
  const char* const ldsb = (const char*)lds;

  auto stA = [&](int d, int kh, int kts){
    u16* lb = ldsw + (d<<15) + (kh<<13);
    const u16* g = gA + (size_t)rstg*K + kts + (kh<<5) + cstg;
    gload16(g, lb);
    gload16(g + ((size_t)K<<7), lb + 4096);
  };
  auto stB = [&](int d, int kh, int kts){
    u16* lb = ldsw + (d<<15) + 16384 + (kh<<13);
    const u16* g = gB + (size_t)rstg*K + kts + (kh<<5) + cstg;
    gload16(g, lb);
    gload16(g + ((size_t)K<<7), lb + 4096);
  };

  stA(0,0,0); stB(0,0,0); stA(0,1,0); stB(0,1,0); stA(1,0,64); stB(1,0,64);
  asm volatile("s_waitcnt vmcnt(8)" ::: "memory");
  __builtin_amdgcn_sched_barrier(0);
  __builtin_amdgcn_s_barrier();

  for (int kt = 0; kt < K; kt += 128){
    const int ktp = (kt+128 < K) ? kt+128 : 0;
    const int ktq = (kt+192 < K) ? kt+192 : kt+192-K;
    short8 b0={0},b1={0},b2={0},b3={0};
    PHASE(0,0,0,1, stA(1,1,kt+64), 0)
    PHASE(0,0,1,0, stB(1,1,kt+64), 1)
    PHASE(0,1,0,1, stA(0,0,ktp),   0)
    PHASE(0,1,1,0, stB(0,0,ktp),   1)
    PHASE(1,0,0,1, stA(0,1,ktp),   0)
    PHASE(1,0,1,0, stB(0,1,ktp),   1)
    PHASE(1,1,0,1, stA(1,0,ktq),   0)
    PHASE(1,1,1,0, stB(1,0,ktq),   1)
  }

  const int cr = (lane>>4)<<2, cc = lane&15;
  #pragma unroll
  for(int mi=0;mi<8;mi++){
    #pragma unroll
    for(int ni=0;ni<4;ni++){
      const int row0 = bm*256 + wm*128 + mi*16 + cr;
      const int col  = bn*256 + wn*64  + ni*16 + cc;
      if (col < Nreal){
        #pragma unroll
        for(int rr=0;rr<4;rr++){
          size_t idx = (size_t)(row0+rr)*Nld + col;
          float v = acc[mi][ni][rr];
          if (EPI==1 || EPI==3) v += resid[idx];
          if (EPI==2 || EPI==3) v += bias[col];
          if (EPI==2){ v = fmaxf(v, 0.f); Cb[idx] = f2bf(v); }
          else if (EPI==4){ Cb[idx] = f2bf(v); }
          else C[idx] = v;
        }
      }
    }
  }
}

// ================== MFMA TTT scan ==================
// Role split (this round): the per-wave SERIAL SUM is the step cost, so the
// X-heavy waves get empty Y regions:
//  X: waves 0,1: full Zk->LN-bwd->gradT chain (2x dup; gradTbf[n&1]).
//     wave 4: Zq(n) + do_out(n-1) (output pipeline depth 1).
//     wave 7: At -> etaA[n&1].
//     waves 2,3,5,6 ("stagers"): stage(n+1) from prefetched regs -> slot
//     (n+1)%3, then issue global prefetch for n+2.
//  Y: waves 2,3,5,6: W1 MFMA update (own mtile, wf regs), write W1bf[(n&1)^1].
//     wave 7: b1 update. waves 0,1,4: idle.
// Staged arrays are TRIPLE-buffered (slot = minibatch%3) so wave-4's
// do_out(n-1) reads never race the stagers' (n+1) writes in the same region.
#define W1LD 72   // bf16 elems per row of W1bf (pad 64->72)
#define XLD  72   // xqbf/xkbf row stride
#define GTLD 40   // gradTbf row stride (16 cols used, [16,32) zero for K=32 frags)
#define EKLD 40   // exkT row stride
#define EALD 40   // etaA row stride
#define TD2  68   // f32 [i][d] row stride (pad 64->68)

__global__ __launch_bounds__(512, 1) void ttt_scan(
    const u16* __restrict__ XQKV,   // 8192 x 6272 bf16: [q|k|v|lr_pre(32)+pad]
    const float* __restrict__ ropec, const float* __restrict__ ropes,
    const float* __restrict__ tokp,
    const float* __restrict__ nw, const float* __restrict__ nb,
    const float* __restrict__ lrb,
    const float* __restrict__ W1i,  // NH x 64 x 64  (W1i[h][k][d])
    const float* __restrict__ b1i,  // NH x 64
    float* __restrict__ Y)          // 8192 x 2048
{
  const int blk = blockIdx.x, b = blk>>5, h = blk&31;
  const int t = threadIdx.x, lane = t&63, wv = t>>6;
  const int fr = lane&15, quad = lane>>4;
  const bool isStager = (wv==2)||(wv==3)||(wv==5)||(wv==6);
  const int sm = (wv>=5)? wv-3 : wv-2;     // 0..3 for stagers (mtile / row-group)

  __shared__ u16 W1bf[2][64*W1LD];     // double-buffered W1t[d][k] bf16
  __shared__ u16 xqbf[3][16*XLD];      // [i][k], slot = minibatch%3
  __shared__ u16 xkbf[3][16*XLD];
  __shared__ u16 exkT[3][64*EKLD];     // [k][j] = -e_j * xk[j][k]
  __shared__ u16 gradTbf[2][64*GTLD];  // [d][j], parity = step&1
  __shared__ u16 etaA[2][16*EALD];     // [i][j], parity = step&1
  __shared__ float tgT2[3][16*TD2];    // [i][d] = (v - xk)[i][d]
  __shared__ float xqT2[3][16*TD2];    // [i][d]
  __shared__ float b1s[64];
  __shared__ float lrs[3][16];

  const float lrbh = lrb[h];
  const float ct = tokp[15]*(1.f/64.f);
  const float sg = (lane<32)? -1.f : 1.f;

  // loop-invariant LN params / tok in registers
  f32x2 lwr[16];
  #pragma unroll
  for(int m=0;m<4;m++)
    #pragma unroll
    for(int r=0;r<4;r++){
      int d = m*16+quad*4+r;
      lwr[m*4+r] = (f32x2){nw[h*64+d], nb[h*64+d]};
    }
  float tki[4];
  #pragma unroll
  for(int r=0;r<4;r++) tki[r] = tokp[quad*4+r];

  // stagers: rope tables for their 4 rows, W1 state (mtile sm), prefetch regs
  float ccj[4], ssj[4];
  f32x4 wf0, wf1, wf2, wf3;
  u16 Pq[4], Pk[4], Pv[4], Pl[4];
  if (isStager){
    #pragma unroll
    for(int j=0;j<4;j++){
      ccj[j] = ropec[(sm*4+j)*64 + lane];
      ssj[j] = ropes[(sm*4+j)*64 + lane];
    }
    const float* wsrc = W1i + (size_t)h*4096;
    #pragma unroll
    for(int r=0;r<4;r++){
      int d = sm*16+quad*4+r;
      wf0[r] = wsrc[( 0+fr)*64 + d];
      wf1[r] = wsrc[(16+fr)*64 + d];
      wf2[r] = wsrc[(32+fr)*64 + d];
      wf3[r] = wsrc[(48+fr)*64 + d];
    }
    #pragma unroll
    for(int r=0;r<4;r++){
      int d = sm*16+quad*4+r;
      W1bf[0][d*W1LD +  0 + fr] = f2bf(wf0[r]);
      W1bf[0][d*W1LD + 16 + fr] = f2bf(wf1[r]);
      W1bf[0][d*W1LD + 32 + fr] = f2bf(wf2[r]);
      W1bf[0][d*W1LD + 48 + fr] = f2bf(wf3[r]);
    }
  }
  // zero pads (cols [16,40) so K=32 fragments see zeros) — all buffers
  for(int i=t;i<64*24;i+=512){
    int rr=i/24, cp=16+i%24;
    gradTbf[0][rr*GTLD+cp]=0; gradTbf[1][rr*GTLD+cp]=0;
    exkT[0][rr*EKLD+cp]=0; exkT[1][rr*EKLD+cp]=0; exkT[2][rr*EKLD+cp]=0;
  }
  for(int i=t;i<16*24;i+=512){
    int rr=i/24, cp=16+i%24;
    etaA[0][rr*EALD+cp]=0; etaA[1][rr*EALD+cp]=0;
  }
  if (t<64) b1s[t]=b1i[h*64+t];

  // stager helpers: load minibatch n rows (sm*4..sm*4+3) into P; stage P -> slot
  auto loadP = [&](int n){
    const size_t rb = (size_t)b*2048 + n*16;
    #pragma unroll
    for(int j=0;j<4;j++){
      const u16* p = XQKV + (rb+sm*4+j)*6272 + h*64 + lane;
      Pq[j]=p[0]; Pk[j]=p[2048]; Pv[j]=p[4096];
      Pl[j]=XQKV[(rb+sm*4+j)*6272 + 6144 + h];
    }
  };
  auto stage4 = [&](int slot){
    #pragma unroll
    for(int j=0;j<4;j++){
      const int i = sm*4+j;
      float q=bf2f(Pq[j]), k=bf2f(Pk[j]), v=bf2f(Pv[j]);
      float qr = q*ccj[j] + sg*swap32(q)*ssj[j];
      float kr = k*ccj[j] + sg*swap32(k)*ssj[j];
      float lr = 1.f/(1.f + expf(-(bf2f(Pl[j]) + lrbh)));
      xqbf[slot][i*XLD+lane] = f2bf(qr);
      xkbf[slot][i*XLD+lane] = f2bf(kr);
      exkT[slot][lane*EKLD+i] = f2bf(-ct*lr*kr);
      tgT2[slot][i*TD2+lane] = v - kr;
      xqT2[slot][i*TD2+lane] = qr;
      if (lane==0) lrs[slot][i]=lr;
    }
  };

  // prologue: stage minibatch 0 into slot 0; prefetch minibatch 1
  if (isStager){
    loadP(0);
    stage4(0);
    loadP(1);
  }
  __syncthreads();

  const f32x4 fzero = (f32x4){0.f,0.f,0.f,0.f};

  // wave-4 carried state (output pipeline depth 1)
  f32x4 zqP0=fzero, zqP1=fzero, zqP2=fzero, zqP3=fzero;
  f32x4 b1qP0=fzero, b1qP1=fzero, b1qP2=fzero, b1qP3=fzero;

  // output chain for step s: parity2 = s&1 (etaA/gradT), slot3 = s%3 (xqT2)
  auto do_out = [&](int p2, int p3, size_t rb){
    short8 be = *(const short8*)&etaA[p2][fr*EALD + quad*8];
    f32x4 c20,c21,c22,c23;
    c20 = __builtin_amdgcn_mfma_f32_16x16x32_bf16(*(const short8*)&gradTbf[p2][( 0+fr)*GTLD + quad*8], be, fzero, 0,0,0);
    c21 = __builtin_amdgcn_mfma_f32_16x16x32_bf16(*(const short8*)&gradTbf[p2][(16+fr)*GTLD + quad*8], be, fzero, 0,0,0);
    c22 = __builtin_amdgcn_mfma_f32_16x16x32_bf16(*(const short8*)&gradTbf[p2][(32+fr)*GTLD + quad*8], be, fzero, 0,0,0);
    c23 = __builtin_amdgcn_mfma_f32_16x16x32_bf16(*(const short8*)&gradTbf[p2][(48+fr)*GTLD + quad*8], be, fzero, 0,0,0);
    f32x4 xqv0 = *(const f32x4*)&xqT2[p3][fr*TD2 +  0 + quad*4];
    f32x4 xqv1 = *(const f32x4*)&xqT2[p3][fr*TD2 + 16 + quad*4];
    f32x4 xqv2 = *(const f32x4*)&xqT2[p3][fr*TD2 + 32 + quad*4];
    f32x4 xqv3 = *(const f32x4*)&xqT2[p3][fr*TD2 + 48 + quad*4];
    f32x4 zb0,zb1,zb2,zb3;
    float s1=0.f, s2=0.f;
    #pragma unroll
    for(int r=0;r<4;r++){
      zb0[r] = zqP0[r] + b1qP0[r] + c20[r];
      zb1[r] = zqP1[r] + b1qP1[r] + c21[r];
      zb2[r] = zqP2[r] + b1qP2[r] + c22[r];
      zb3[r] = zqP3[r] + b1qP3[r] + c23[r];
      s1 += zb0[r]+zb1[r]+zb2[r]+zb3[r];
      s2 += zb0[r]*zb0[r]+zb1[r]*zb1[r]+zb2[r]*zb2[r]+zb3[r]*zb3[r];
    }
    s1 = qsum(s1); s2 = qsum(s2);
    float mu = s1*(1.f/64.f);
    float var = s2*(1.f/64.f) - mu*mu;
    float rstd = rsqrtf(var + 1e-6f);
    #pragma unroll
    for(int m=0;m<4;m++){
      f32x4* zp = (m==0)?&zb0:(m==1)?&zb1:(m==2)?&zb2:&zb3;
      const f32x4* xp = (m==0)?&xqv0:(m==1)?&xqv1:(m==2)?&xqv2:&xqv3;
      f32x4 o;
      #pragma unroll
      for(int r=0;r<4;r++){
        f32x2 wb = lwr[m*4+r];
        float xh = ((*zp)[r] - mu)*rstd;
        o[r] = (*xp)[r] + xh*wb[0] + wb[1];
      }
      *(f32x4*)&Y[(rb+fr)*2048 + h*64 + m*16 + quad*4] = o;
    }
  };

  int c3 = 0;   // n%3
  for(int n=0;n<128;n++){
    const int cur2 = n&1, pb2 = cur2^1;
    const int cur3 = c3;
    const int nxt3 = (c3==2)? 0 : c3+1;
    const int pb3  = (c3==0)? 2 : c3-1;
    const size_t rbase = (size_t)b*2048 + n*16;

    // ---------------- region X ----------------
    if (wv < 2){
      f32x4 b1v0 = *(const f32x4*)&b1s[ 0+quad*4];
      f32x4 b1v1 = *(const f32x4*)&b1s[16+quad*4];
      f32x4 b1v2 = *(const f32x4*)&b1s[32+quad*4];
      f32x4 b1v3 = *(const f32x4*)&b1s[48+quad*4];
      f32x4 tgv0 = *(const f32x4*)&tgT2[cur3][fr*TD2 +  0 + quad*4];
      f32x4 tgv1 = *(const f32x4*)&tgT2[cur3][fr*TD2 + 16 + quad*4];
      f32x4 tgv2 = *(const f32x4*)&tgT2[cur3][fr*TD2 + 32 + quad*4];
      f32x4 tgv3 = *(const f32x4*)&tgT2[cur3][fr*TD2 + 48 + quad*4];
      // Zk^T = W1t (x) xk : C[d][i], full 64x16 (dup x2: waves 0,1)
      short8 bk0 = *(const short8*)&xkbf[cur3][fr*XLD + quad*8];
      short8 bk1 = *(const short8*)&xkbf[cur3][fr*XLD + 32 + quad*8];
      f32x4 z0,z1,z2,z3;
      z0 = __builtin_amdgcn_mfma_f32_16x16x32_bf16(*(const short8*)&W1bf[cur2][( 0+fr)*W1LD + quad*8],      bk0, fzero, 0,0,0);
      z0 = __builtin_amdgcn_mfma_f32_16x16x32_bf16(*(const short8*)&W1bf[cur2][( 0+fr)*W1LD + 32 + quad*8], bk1, z0,    0,0,0);
      z1 = __builtin_amdgcn_mfma_f32_16x16x32_bf16(*(const short8*)&W1bf[cur2][(16+fr)*W1LD + quad*8],      bk0, fzero, 0,0,0);
      z1 = __builtin_amdgcn_mfma_f32_16x16x32_bf16(*(const short8*)&W1bf[cur2][(16+fr)*W1LD + 32 + quad*8], bk1, z1,    0,0,0);
      z2 = __builtin_amdgcn_mfma_f32_16x16x32_bf16(*(const short8*)&W1bf[cur2][(32+fr)*W1LD + quad*8],      bk0, fzero, 0,0,0);
      z2 = __builtin_amdgcn_mfma_f32_16x16x32_bf16(*(const short8*)&W1bf[cur2][(32+fr)*W1LD + 32 + quad*8], bk1, z2,    0,0,0);
      z3 = __builtin_amdgcn_mfma_f32_16x16x32_bf16(*(const short8*)&W1bf[cur2][(48+fr)*W1LD + quad*8],      bk0, fzero, 0,0,0);
      z3 = __builtin_amdgcn_mfma_f32_16x16x32_bf16(*(const short8*)&W1bf[cur2][(48+fr)*W1LD + 32 + quad*8], bk1, z3,    0,0,0);
      // LN-l2 backward
      f32x4 xh0,xh1,xh2,xh3;
      {
        float s1=0.f, s2=0.f;
        #pragma unroll
        for(int r=0;r<4;r++){
          z0[r] += b1v0[r];
          z1[r] += b1v1[r];
          z2[r] += b1v2[r];
          z3[r] += b1v3[r];
          s1 += z0[r]+z1[r]+z2[r]+z3[r];
          s2 += z0[r]*z0[r]+z1[r]*z1[r]+z2[r]*z2[r]+z3[r]*z3[r];
        }
        s1 = qsum(s1); s2 = qsum(s2);
        float mu = s1*(1.f/64.f);
        float var = s2*(1.f/64.f) - mu*mu;
        float rstd = rsqrtf(var + 1e-6f);
        float u1=0.f, u2=0.f;
        #pragma unroll
        for(int m=0;m<4;m++){
          f32x4* zp = (m==0)?&z0:(m==1)?&z1:(m==2)?&z2:&z3;
          f32x4* xp = (m==0)?&xh0:(m==1)?&xh1:(m==2)?&xh2:&xh3;
          const f32x4* tp = (m==0)?&tgv0:(m==1)?&tgv1:(m==2)?&tgv2:&tgv3;
          #pragma unroll
          for(int r=0;r<4;r++){
            f32x2 wb = lwr[m*4+r];
            float xh = ((*zp)[r] - mu)*rstd;
            float gx = (wb[0]*xh + wb[1] - (*tp)[r])*wb[0];
            (*xp)[r] = xh;
            (*zp)[r] = gx;
            u1 += gx; u2 += gx*xh;
          }
        }
        u1 = qsum(u1); u2 = qsum(u2);
        const float c64 = rstd*(1.f/64.f);
        #pragma unroll
        for(int m=0;m<4;m++){
          f32x4* zp = (m==0)?&z0:(m==1)?&z1:(m==2)?&z2:&z3;
          f32x4* xp = (m==0)?&xh0:(m==1)?&xh1:(m==2)?&xh2:&xh3;
          #pragma unroll
          for(int r=0;r<4;r++)
            (*zp)[r] = (64.f*(*zp)[r] - u1 - (*xp)[r]*u2)*c64;   // gradT
        }
      }
      // wave0 writes mtiles 0,1; wave1 writes 2,3
      f32x4 zA = (wv==0)? z0 : z2;
      f32x4 zB = (wv==0)? z1 : z3;
      const int rb0 = wv*32;
      #pragma unroll
      for(int r=0;r<4;r++){
        gradTbf[cur2][(rb0+quad*4+r)*GTLD + fr]    = f2bf(zA[r]);
        gradTbf[cur2][(rb0+16+quad*4+r)*GTLD + fr] = f2bf(zB[r]);
      }
    }
    else if (wv == 4){
      // Zq(n): independent MFMAs into fresh regs
      short8 bq0 = *(const short8*)&xqbf[cur3][fr*XLD + quad*8];
      short8 bq1 = *(const short8*)&xqbf[cur3][fr*XLD + 32 + quad*8];
      f32x4 zqN0,zqN1,zqN2,zqN3;
      zqN0 = __builtin_amdgcn_mfma_f32_16x16x32_bf16(*(const short8*)&W1bf[cur2][( 0+fr)*W1LD + quad*8],      bq0, fzero, 0,0,0);
      zqN0 = __builtin_amdgcn_mfma_f32_16x16x32_bf16(*(const short8*)&W1bf[cur2][( 0+fr)*W1LD + 32 + quad*8], bq1, zqN0,  0,0,0);
      zqN1 = __builtin_amdgcn_mfma_f32_16x16x32_bf16(*(const short8*)&W1bf[cur2][(16+fr)*W1LD + quad*8],      bq0, fzero, 0,0,0);
      zqN1 = __builtin_amdgcn_mfma_f32_16x16x32_bf16(*(const short8*)&W1bf[cur2][(16+fr)*W1LD + 32 + quad*8], bq1, zqN1,  0,0,0);
      zqN2 = __builtin_amdgcn_mfma_f32_16x16x32_bf16(*(const short8*)&W1bf[cur2][(32+fr)*W1LD + quad*8],      bq0, fzero, 0,0,0);
      zqN2 = __builtin_amdgcn_mfma_f32_16x16x32_bf16(*(const short8*)&W1bf[cur2][(32+fr)*W1LD + 32 + quad*8], bq1, zqN2,  0,0,0);
      zqN3 = __builtin_amdgcn_mfma_f32_16x16x32_bf16(*(const short8*)&W1bf[cur2][(48+fr)*W1LD + quad*8],      bq0, fzero, 0,0,0);
      zqN3 = __builtin_amdgcn_mfma_f32_16x16x32_bf16(*(const short8*)&W1bf[cur2][(48+fr)*W1LD + 32 + quad*8], bq1, zqN3,  0,0,0);
      // output of step n-1
      if (n > 0) do_out(pb2, pb3, rbase - 16);
      // rotate pipeline state
      zqP0=zqN0; zqP1=zqN1; zqP2=zqN2; zqP3=zqN3;
      b1qP0 = *(const f32x4*)&b1s[ 0+quad*4];   // b1 pre-update for step n
      b1qP1 = *(const f32x4*)&b1s[16+quad*4];
      b1qP2 = *(const f32x4*)&b1s[32+quad*4];
      b1qP3 = *(const f32x4*)&b1s[48+quad*4];
    }
    else if (wv == 7){
      // At = xq (x) xk : C[i][j] -> etaA[cur2]
      short8 aq0 = *(const short8*)&xqbf[cur3][fr*XLD + quad*8];
      short8 aq1 = *(const short8*)&xqbf[cur3][fr*XLD + 32 + quad*8];
      short8 bk0 = *(const short8*)&xkbf[cur3][fr*XLD + quad*8];
      short8 bk1 = *(const short8*)&xkbf[cur3][fr*XLD + 32 + quad*8];
      f32x4 at;
      at = __builtin_amdgcn_mfma_f32_16x16x32_bf16(aq0, bk0, fzero, 0,0,0);
      at = __builtin_amdgcn_mfma_f32_16x16x32_bf16(aq1, bk1, at,    0,0,0);
      float lrj = lrs[cur3][fr]*(1.f/64.f);
      #pragma unroll
      for(int r=0;r<4;r++){
        int i = quad*4 + r;
        float val = (fr <= i) ? -tki[r]*lrj*(1.f + at[r]) : 0.f;
        etaA[cur2][i*EALD + fr] = f2bf(val);
      }
    }
    else {
      // stagers: stage(n+1) into slot nxt3; prefetch minibatch n+2
      if (n < 127) stage4(nxt3);
      if (n < 126) loadP(n+2);
    }
    BARS();

    // ---------------- region Y ----------------
    if (isStager){
      // W1 update: wave owns mtile sm, tiles n=0..3
      short8 ga = *(const short8*)&gradTbf[cur2][(sm*16+fr)*GTLD + quad*8];
      short8 e0 = *(const short8*)&exkT[cur3][( 0+fr)*EKLD + quad*8];
      short8 e1 = *(const short8*)&exkT[cur3][(16+fr)*EKLD + quad*8];
      short8 e2 = *(const short8*)&exkT[cur3][(32+fr)*EKLD + quad*8];
      short8 e3 = *(const short8*)&exkT[cur3][(48+fr)*EKLD + quad*8];
      wf0 = __builtin_amdgcn_mfma_f32_16x16x32_bf16(ga, e0, wf0, 0,0,0);
      wf1 = __builtin_amdgcn_mfma_f32_16x16x32_bf16(ga, e1, wf1, 0,0,0);
      wf2 = __builtin_amdgcn_mfma_f32_16x16x32_bf16(ga, e2, wf2, 0,0,0);
      wf3 = __builtin_amdgcn_mfma_f32_16x16x32_bf16(ga, e3, wf3, 0,0,0);
      #pragma unroll
      for(int r=0;r<4;r++){
        int d = sm*16+quad*4+r;
        W1bf[pb2][d*W1LD +  0 + fr] = f2bf(wf0[r]);
        W1bf[pb2][d*W1LD + 16 + fr] = f2bf(wf1[r]);
        W1bf[pb2][d*W1LD + 32 + fr] = f2bf(wf2[r]);
        W1bf[pb2][d*W1LD + 48 + fr] = f2bf(wf3[r]);
      }
    }
    else if (wv == 7){
      // b1 update: b1s[d] -= ct * sum_j lrs[j] * gradT[d][j]
      const int d = lane;
      short8 g0 = *(const short8*)&gradTbf[cur2][d*GTLD + 0];
      short8 g1 = *(const short8*)&gradTbf[cur2][d*GTLD + 8];
      float s = 0.f;
      #pragma unroll
      for(int j=0;j<8;j++) s += lrs[cur3][j]   * bf2f((u16)g0[j]);
      #pragma unroll
      for(int j=0;j<8;j++) s += lrs[cur3][8+j] * bf2f((u16)g1[j]);
      b1s[d] -= ct * s;
    }
    BARS();
    c3 = nxt3;
  }

  // epilogue: output of the last step (n=127): parity2 = 1, slot3 = 127%3 = 1
  if (wv == 4) do_out(1, 1, (size_t)b*2048 + 127*16);
}

// ---------------- host launch ----------------
extern "C" void kernel_launch(void* const* d_in, const int* in_sizes, int n_in,
                              void* d_out, int out_size, void* d_ws, size_t ws_size,
                              hipStream_t stream)
{
  const float* enc   = (const float*)d_in[0];
  const float* ln1w  = (const float*)d_in[1];
  const float* ln1b  = (const float*)d_in[2];
  const float* qw    = (const float*)d_in[3];
  const float* kw    = (const float*)d_in[4];
  const float* vw    = (const float*)d_in[5];
  const float* ow    = (const float*)d_in[6];
  const float* lrw   = (const float*)d_in[7];
  const float* lrb   = (const float*)d_in[8];
  const float* tio   = (const float*)d_in[9];
  const float* tnw   = (const float*)d_in[10];
  const float* tnb   = (const float*)d_in[11];
  const float* W1i   = (const float*)d_in[12];
  const float* b1i   = (const float*)d_in[13];
  const float* postw = (const float*)d_in[14];
  const float* postb = (const float*)d_in[15];
  const float* flnw  = (const float*)d_in[16];
  const float* flnb  = (const float*)d_in[17];
  const float* w1f   = (const float*)d_in[18];
  const float* b1f   = (const float*)d_in[19];
  const float* w2f   = (const float*)d_in[20];
  const float* b2f   = (const float*)d_in[21];
  float* out = (float*)d_out;

  char* ws = (char*)d_ws;
  size_t off = 0;
  auto alloc = [&](size_t bytes)->void*{ void* p = ws + off; off += (bytes + 255) & ~(size_t)255; return p; };
  u16*   regA  = (u16*)  alloc(8192ull*2048*2);   // x_bf -> ypost_bf -> z_bf
  u16*   wqkvT = (u16*)  alloc(6400ull*2048*2);   // [qT|kT|vT|lr(32)+zeros..6400); later oT/w1fT/w2fT
  u16*   XQKV  = (u16*)  alloc(8192ull*6272*2);   // later: h_bf
  float* yb    = (float*)alloc(8192ull*2048*4);   // y -> y2
  float* ropec = (float*)alloc(1024*4);
  float* ropes = (float*)alloc(1024*4);
  float* tokb  = (float*)alloc(64*4);

  u16* oT   = wqkvT;
  u16* w1fT = wqkvT + 2048ull*2048;
  u16* w2fT = w1fT + 1024ull*2048;
  u16* hbf  = XQKV;
  float* y2 = yb;

  static bool s_attr = false;
  if (!s_attr){
    s_attr = true;
    (void)hipFuncSetAttribute(reinterpret_cast<const void*>(gemm256<4>), hipFuncAttributeMaxDynamicSharedMemorySize, 131072);
    (void)hipFuncSetAttribute(reinterpret_cast<const void*>(gemm256<1>), hipFuncAttributeMaxDynamicSharedMemorySize, 131072);
    (void)hipFuncSetAttribute(reinterpret_cast<const void*>(gemm256<2>), hipFuncAttributeMaxDynamicSharedMemorySize, 131072);
    (void)hipFuncSetAttribute(reinterpret_cast<const void*>(gemm256<3>), hipFuncAttributeMaxDynamicSharedMemorySize, 131072);
  }

  rope_init<<<4, 256, 0, stream>>>(tio, ropec, ropes, tokb);

  dim3 tg1(64, 64);
  transpose_cast<<<tg1, 256, 0, stream>>>(qw, wqkvT,               2048, 2048);
  transpose_cast<<<tg1, 256, 0, stream>>>(kw, wqkvT + 2048ull*2048, 2048, 2048);
  transpose_cast<<<tg1, 256, 0, stream>>>(vw, wqkvT + 4096ull*2048, 2048, 2048);
  cast_lrw<<<2048, 256, 0, stream>>>(lrw, wqkvT + 6144ull*2048);

  ln_row<<<2048, 256, 0, stream>>>(enc, ln1w, ln1b, 1e-5f, regA);

  // QKV + lr projection: logical N=6400 (25 tiles), real cols 6272, ldc 6272
  gemm256<4><<<32*25, 512, 131072, stream>>>(regA, wqkvT, nullptr, XQKV,
                                             nullptr, nullptr, 6272, 6272, 2048, 25);

  // transpose remaining weights (reuses wqkvT region; QKV GEMM already consumed it)
  transpose_cast<<<tg1, 256, 0, stream>>>(ow, oT, 2048, 2048);
  dim3 tg2(64, 32);
  transpose_cast<<<tg2, 256, 0, stream>>>(w1f, w1fT, 2048, 1024);
  dim3 tg3(32, 64);
  transpose_cast<<<tg3, 256, 0, stream>>>(w2f, w2fT, 1024, 2048);

  // sequential TTT scan (MFMA formulation)
  ttt_scan<<<128, 512, 0, stream>>>(XQKV, ropec, ropes, tokb, tnw, tnb, lrb, W1i, b1i, yb);

  // post-LN + O-projection + residual(enc)
  ln_row<<<2048, 256, 0, stream>>>(yb, postw, postb, 1e-6f, regA);
  gemm256<1><<<32*8, 512, 131072, stream>>>(regA, oT, y2, nullptr,
                                            nullptr, enc, 2048, 2048, 2048, 8);

  // FFN
  ln_row<<<2048, 256, 0, stream>>>(y2, flnw, flnb, 1e-6f, regA);
  gemm256<2><<<32*4, 512, 131072, stream>>>(regA, w1fT, nullptr, hbf,
                                            b1f, nullptr, 1024, 1024, 2048, 4);
  gemm256<3><<<32*8, 512, 131072, stream>>>(hbf, w2fT, out, nullptr,
                                            b2f, y2, 2048, 2048, 1024, 8);
}

// Round 7
// 763.856 us; speedup vs baseline: 1.3070x; 1.0062x over previous
//
#include <hip/hip_runtime.h>

typedef unsigned short u16;
typedef __attribute__((ext_vector_type(8))) short short8;
typedef __attribute__((ext_vector_type(8))) unsigned short ushort8;
typedef __attribute__((ext_vector_type(4))) unsigned short us4;
typedef __attribute__((ext_vector_type(4))) float f32x4;
typedef __attribute__((ext_vector_type(2))) float f32x2;
typedef __attribute__((ext_vector_type(2))) unsigned int uint2v;

#define DEV __device__ __forceinline__

DEV float bf2f(u16 u){ union{unsigned int i; float f;} v; v.i = ((unsigned int)u)<<16u; return v.f; }
DEV u16 f2bf(float f){ union{float f; unsigned int i;} v; v.f=f; unsigned int r = v.i + 0x7FFFu + ((v.i>>16)&1u); return (u16)(r>>16); }

DEV void gload16(const u16* g, u16* l){
  __builtin_amdgcn_global_load_lds((const __attribute__((address_space(1))) void*)g,
                                   (__attribute__((address_space(3))) void*)l, 16, 0, 0);
}

DEV float wsum(float v){
  v += __shfl_xor(v, 32, 64);
  v += __shfl_xor(v, 16, 64);
  v += __shfl_xor(v, 8, 64);
  v += __shfl_xor(v, 4, 64);
  v += __shfl_xor(v, 2, 64);
  v += __shfl_xor(v, 1, 64);
  return v;
}

// sum over the 4 lanes sharing (lane&15). permlane pair-sum is
// orientation-agnostic (a[0]+a[1] == v + v[lane^k]) -> safe. (R2-verified.)
#if __has_builtin(__builtin_amdgcn_permlane16_swap) && __has_builtin(__builtin_amdgcn_permlane32_swap)
DEV float qsum(float v){
  unsigned u = __float_as_uint(v);
  uint2v a = __builtin_amdgcn_permlane16_swap(u, u, false, false);
  float s = __uint_as_float(a[0]) + __uint_as_float(a[1]);
  unsigned u2 = __float_as_uint(s);
  uint2v bsw = __builtin_amdgcn_permlane32_swap(u2, u2, false, false);
  return __uint_as_float(bsw[0]) + __uint_as_float(bsw[1]);
}
#else
DEV float qsum(float v){
  v += __shfl_xor(v, 16, 64);
  v += __shfl_xor(v, 32, 64);
  return v;
}
#endif

// sum over the 16 lanes sharing (lane>>4)
DEV float jsum(float v){
  v += __shfl_xor(v, 1, 64);
  v += __shfl_xor(v, 2, 64);
  v += __shfl_xor(v, 4, 64);
  v += __shfl_xor(v, 8, 64);
  return v;
}

// exact element v[lane^32]: MUST be orientation-correct -> proven shfl only.
// (R3 post-mortem: permlane32_swap pair-select orientation was wrong.)
DEV float swap32(float v){ return __shfl_xor(v, 32, 64); }

// raw workgroup barrier: drain own LDS ops only
#define BARS() do{ asm volatile("s_waitcnt lgkmcnt(0)" ::: "memory"); \
  __builtin_amdgcn_s_barrier(); __builtin_amdgcn_sched_barrier(0); }while(0)

// ---------------- LN over rows of 2048, one row per WAVE (no block barriers) ----------------
__global__ __launch_bounds__(256) void ln_row(
    const float* __restrict__ in, const float* __restrict__ w, const float* __restrict__ bb,
    float eps, u16* __restrict__ outb)
{
  const int wv = threadIdx.x>>6, lane = threadIdx.x&63;
  const int row = blockIdx.x*4 + wv;
  const float* p = in + (size_t)row*2048 + lane*4;
  f32x4 a[8];
  #pragma unroll
  for(int j=0;j<8;j++) a[j] = *(const f32x4*)(p + j*256);
  float s = 0.f;
  #pragma unroll
  for(int j=0;j<8;j++) s += a[j][0]+a[j][1]+a[j][2]+a[j][3];
  s = wsum(s);
  float mu = s*(1.f/2048.f);
  float vs = 0.f;
  #pragma unroll
  for(int j=0;j<8;j++)
    #pragma unroll
    for(int r=0;r<4;r++){ float d=a[j][r]-mu; vs += d*d; }
  vs = wsum(vs);
  float rstd = rsqrtf(vs*(1.f/2048.f) + eps);
  #pragma unroll
  for(int j=0;j<8;j++){
    f32x4 wj = *(const f32x4*)(w  + j*256 + lane*4);
    f32x4 bj = *(const f32x4*)(bb + j*256 + lane*4);
    us4 o;
    #pragma unroll
    for(int r=0;r<4;r++) o[r] = f2bf((a[j][r]-mu)*rstd*wj[r] + bj[r]);
    *(us4*)(outb + (size_t)row*2048 + j*256 + lane*4) = o;
  }
}

// ---------------- transpose + cast fp32 (K x N) -> bf16 (N x K), 3 tensors ----------------
__global__ __launch_bounds__(256) void transpose_cast3(
    const float* __restrict__ s0, u16* __restrict__ d0v, int K0, int N0,
    const float* __restrict__ s1, u16* __restrict__ d1v, int K1, int N1,
    const float* __restrict__ s2, u16* __restrict__ d2v, int K2, int N2)
{
  const int z = blockIdx.z;
  const float* src = (z==0)? s0 : (z==1)? s1 : s2;
  u16* dst = (z==0)? d0v : (z==1)? d1v : d2v;
  const int K = (z==0)? K0 : (z==1)? K1 : K2;
  const int N = (z==0)? N0 : (z==1)? N1 : N2;
  const int kb = blockIdx.x*32, nb = blockIdx.y*32;
  if (kb >= K || nb >= N) return;
  __shared__ float tile[32][33];
  const int tx = threadIdx.x & 31, ty = threadIdx.x >> 5; // 32 x 8
  #pragma unroll
  for(int i=0;i<4;i++){
    int k = ty + i*8;
    tile[k][tx] = src[(size_t)(kb+k)*N + nb + tx];
  }
  __syncthreads();
  #pragma unroll
  for(int i=0;i<4;i++){
    int nn = ty + i*8;
    dst[(size_t)(nb+nn)*K + kb + tx] = f2bf(tile[tx][nn]);
  }
}

// cast lr_w (32 x 2048) into rows [0..31] of a 256x2048 block, zero the rest
__global__ __launch_bounds__(256) void cast_lrw(const float* __restrict__ lrw, u16* __restrict__ dst)
{
  int i = blockIdx.x*256 + threadIdx.x;       // 256*2048 total
  if (i < 32*2048) dst[i] = f2bf(lrw[i]);
  else dst[i] = 0;
}

// rope tables (pos 0..15, d 0..63) + tok vector
__global__ void rope_init(const float* __restrict__ tio, float* __restrict__ cosb,
                          float* __restrict__ sinb, float* __restrict__ tokb)
{
  int t = blockIdx.x*256 + threadIdx.x;
  if (t < 1024){
    int p = t>>6, d = t&63;
    float inv = powf(10000.f, -(float)(2*(d&31))/64.f);
    float fr = (float)p * inv;
    cosb[t] = cosf(fr);
    sinb[t] = sinf(fr);
  }
  if (blockIdx.x==0 && threadIdx.x<16)
    tokb[threadIdx.x] = fmaxf(1.f/(float)(threadIdx.x+1) + tio[threadIdx.x], 0.f);
}

// ================== 256x256 8-phase bf16 GEMM (BK=64, 8 waves) ==================
#define MM(MI,NI,AA,BB) acc[MI][NI] = __builtin_amdgcn_mfma_f32_16x16x32_bf16(AA, BB, acc[MI][NI], 0, 0, 0)

#define RD_A(D,KH,MF) (*(const short8*)(ldsb + ((D)<<16) + ((KH)<<14) + (wm<<13) + ((MF)<<10) + loff))
#define RD_B(D,KH,NF) (*(const short8*)(ldsb + ((D)<<16) + 32768 + ((KH)<<14) + (wn<<12) + ((NF)<<10) + loff))

#define PHASE(D,KH,MH,RB,STG,VM) { \
  __builtin_amdgcn_sched_barrier(0); \
  if (RB){ b0 = RD_B(D,KH,0); b1 = RD_B(D,KH,1); b2 = RD_B(D,KH,2); b3 = RD_B(D,KH,3); } \
  short8 a0 = RD_A(D,KH,4*(MH)+0); \
  short8 a1 = RD_A(D,KH,4*(MH)+1); \
  short8 a2 = RD_A(D,KH,4*(MH)+2); \
  short8 a3 = RD_A(D,KH,4*(MH)+3); \
  STG; \
  __builtin_amdgcn_sched_barrier(0); \
  __builtin_amdgcn_s_barrier(); \
  asm volatile("s_waitcnt lgkmcnt(0)" ::: "memory"); \
  __builtin_amdgcn_sched_barrier(0); \
  __builtin_amdgcn_s_setprio(1); \
  MM(4*(MH)+0,0,a0,b0); MM(4*(MH)+1,0,a1,b0); MM(4*(MH)+2,0,a2,b0); MM(4*(MH)+3,0,a3,b0); \
  MM(4*(MH)+0,1,a0,b1); MM(4*(MH)+1,1,a1,b1); MM(4*(MH)+2,1,a2,b1); MM(4*(MH)+3,1,a3,b1); \
  MM(4*(MH)+0,2,a0,b2); MM(4*(MH)+1,2,a1,b2); MM(4*(MH)+2,2,a2,b2); MM(4*(MH)+3,2,a3,b2); \
  MM(4*(MH)+0,3,a0,b3); MM(4*(MH)+1,3,a1,b3); MM(4*(MH)+2,3,a2,b3); MM(4*(MH)+3,3,a3,b3); \
  __builtin_amdgcn_s_setprio(0); \
  if (VM){ asm volatile("s_waitcnt vmcnt(8)" ::: "memory"); } \
  __builtin_amdgcn_sched_barrier(0); \
  __builtin_amdgcn_s_barrier(); \
}

template<int EPI>
__global__ __launch_bounds__(512, 2) void gemm256(
    const u16* __restrict__ A, const u16* __restrict__ Bt,
    float* __restrict__ C, u16* __restrict__ Cb,
    const float* __restrict__ bias, const float* __restrict__ resid,
    int Nld, int Nreal, int K, int ntN)
{
  extern __shared__ u16 lds[];
  const int t = threadIdx.x, lane = t&63, wv = t>>6;
  const int wm = wv>>2, wn = wv&3;          // 2 (M) x 4 (N) waves
  const int fr = lane&15, kq = lane>>4;

  int bid = blockIdx.x;
  {
    int nwg = gridDim.x;                    // bijective XCD swizzle
    int q = nwg>>3, r = nwg&7;
    int x = bid&7, l = bid>>3;
    bid = (x<r) ? (x*(q+1)+l) : (r*(q+1)+(x-r)*q+l);
  }
  const int bm = bid/ntN, bn = bid%ntN;

  f32x4 acc[8][4];
  #pragma unroll
  for(int i=0;i<8;i++)
    #pragma unroll
    for(int j=0;j<4;j++) acc[i][j]=(f32x4){0.f,0.f,0.f,0.f};

  const u16* gA = A  + (size_t)(bm*256)*K;
  const u16* gB = Bt + (size_t)(bn*256)*K;

  const int Ls   = (t&7) ^ ((t>>3)&7);
  const int rstg = ((t>>3)<<1) | (Ls>>2);
  const int cstg = (Ls&3)<<3;
  u16* const ldsw = lds + (wv<<9);

  const int Plane = (((fr&1)<<2) | kq) ^ (fr>>1);
  const int loff  = ((fr>>1)<<7) | (Plane<<4);
  const char* const ldsb = (const char*)lds;

  auto stA = [&](int d, int kh, int kts){
    u16* lb = ldsw + (d<<15) + (kh<<13);
    const u16* g = gA + (size_t)rstg*K + kts + (kh<<5) + cstg;
    gload16(g, lb);
    gload16(g + ((size_t)K<<7), lb + 4096);
  };
  auto stB = [&](int d, int kh, int kts){
    u16* lb = ldsw + (d<<15) + 16384 + (kh<<13);
    const u16* g = gB + (size_t)rstg*K + kts + (kh<<5) + cstg;
    gload16(g, lb);
    gload16(g + ((size_t)K<<7), lb + 4096);
  };

  stA(0,0,0); stB(0,0,0); stA(0,1,0); stB(0,1,0); stA(1,0,64); stB(1,0,64);
  asm volatile("s_waitcnt vmcnt(8)" ::: "memory");
  __builtin_amdgcn_sched_barrier(0);
  __builtin_amdgcn_s_barrier();

  for (int kt = 0; kt < K; kt += 128){
    const int ktp = (kt+128 < K) ? kt+128 : 0;
    const int ktq = (kt+192 < K) ? kt+192 : kt+192-K;
    short8 b0={0},b1={0},b2={0},b3={0};
    PHASE(0,0,0,1, stA(1,1,kt+64), 0)
    PHASE(0,0,1,0, stB(1,1,kt+64), 1)
    PHASE(0,1,0,1, stA(0,0,ktp),   0)
    PHASE(0,1,1,0, stB(0,0,ktp),   1)
    PHASE(1,0,0,1, stA(0,1,ktp),   0)
    PHASE(1,0,1,0, stB(0,1,ktp),   1)
    PHASE(1,1,0,1, stA(1,0,ktq),   0)
    PHASE(1,1,1,0, stB(1,0,ktq),   1)
  }

  const int cr = (lane>>4)<<2, cc = lane&15;
  #pragma unroll
  for(int mi=0;mi<8;mi++){
    #pragma unroll
    for(int ni=0;ni<4;ni++){
      const int row0 = bm*256 + wm*128 + mi*16 + cr;
      const int col  = bn*256 + wn*64  + ni*16 + cc;
      if (col < Nreal){
        #pragma unroll
        for(int rr=0;rr<4;rr++){
          size_t idx = (size_t)(row0+rr)*Nld + col;
          float v = acc[mi][ni][rr];
          if (EPI==1 || EPI==3) v += resid[idx];
          if (EPI==2 || EPI==3) v += bias[col];
          if (EPI==2){ v = fmaxf(v, 0.f); Cb[idx] = f2bf(v); }
          else if (EPI==4){ Cb[idx] = f2bf(v); }
          else C[idx] = v;
        }
      }
    }
  }
}

// ================== MFMA TTT scan ==================
// SINGLE-BARRIER step (this round). Roles per step n:
//  waves 0-3 ("chain", 4x dup): full Zk->LN-bwd->gradT (f32 in regs);
//    write OWN mtile wv -> gradTbf[n&1]; b1 delta via jsum on f32 gradT ->
//    b1s[(n&1)^1]; same-wave readback (lgkmcnt, R2-proven) of own gradT
//    A-frag -> MFMA W1 update of own mtile -> W1bf[(n&1)^1].
//  wave 4: Zq(n) from W1bf[n&1]; do_out(n-1) from gradTbf/etaA[(n&1)^1],
//    xqT2[(n-1)%3]; b1qP <- b1s[n&1].
//  wave 7: At -> etaA[n&1]; stage rows 12-15 -> slot (n+1)%3; prefetch n+2.
//  waves 5,6: stage rows 0-5 / 6-11; prefetch n+2.
// All intra-region reads hit buffers written BEFORE the previous barrier
// (parity/slot-disjoint from this region's writes); b1s double-buffered.
#define W1LD 72   // bf16 elems per row of W1bf (pad 64->72)
#define XLD  72   // xqbf/xkbf row stride
#define GTLD 40   // gradTbf row stride (16 cols used, [16,32) zero for K=32 frags)
#define EKLD 40   // exkT row stride
#define EALD 40   // etaA row stride
#define TD2  68   // f32 [i][d] row stride (pad 64->68)

__global__ __launch_bounds__(512, 1) void ttt_scan(
    const u16* __restrict__ XQKV,   // 8192 x 6272 bf16: [q|k|v|lr_pre(32)+pad]
    const float* __restrict__ ropec, const float* __restrict__ ropes,
    const float* __restrict__ tokp,
    const float* __restrict__ nw, const float* __restrict__ nb,
    const float* __restrict__ lrb,
    const float* __restrict__ W1i,  // NH x 64 x 64  (W1i[h][k][d])
    const float* __restrict__ b1i,  // NH x 64
    float* __restrict__ Y)          // 8192 x 2048
{
  const int blk = blockIdx.x, b = blk>>5, h = blk&31;
  const int t = threadIdx.x, lane = t&63, wv = t>>6;
  const int fr = lane&15, quad = lane>>4;
  const bool isStager = (wv>=5);
  const int nrows = (wv==7)? 4 : 6;
  const int row0 = (wv==5)? 0 : (wv==6)? 6 : 12;

  __shared__ u16 W1bf[2][64*W1LD];     // double-buffered W1t[d][k] bf16
  __shared__ u16 xqbf[3][16*XLD];      // [i][k], slot = minibatch%3
  __shared__ u16 xkbf[3][16*XLD];
  __shared__ u16 exkT[3][64*EKLD];     // [k][j] = -e_j * xk[j][k]
  __shared__ u16 gradTbf[2][64*GTLD];  // [d][j], parity = step&1
  __shared__ u16 etaA[2][16*EALD];     // [i][j], parity = step&1
  __shared__ float tgT2[3][16*TD2];    // [i][d] = (v - xk)[i][d]
  __shared__ float xqT2[3][16*TD2];    // [i][d]
  __shared__ float b1s[2][64];         // double-buffered (read n&1, write ^1)
  __shared__ float lrs[3][16];

  const float lrbh = lrb[h];
  const float ct = tokp[15]*(1.f/64.f);
  const float sg = (lane<32)? -1.f : 1.f;

  // loop-invariant LN params / tok in registers
  f32x2 lwr[16];
  #pragma unroll
  for(int m=0;m<4;m++)
    #pragma unroll
    for(int r=0;r<4;r++){
      int d = m*16+quad*4+r;
      lwr[m*4+r] = (f32x2){nw[h*64+d], nb[h*64+d]};
    }
  float tki[4];
  #pragma unroll
  for(int r=0;r<4;r++) tki[r] = tokp[quad*4+r];

  // chain waves 0-3: W1 state (own mtile wv, tiles n=0..3)
  f32x4 wf0, wf1, wf2, wf3;
  if (wv < 4){
    const float* wsrc = W1i + (size_t)h*4096;
    #pragma unroll
    for(int r=0;r<4;r++){
      int d = wv*16+quad*4+r;
      wf0[r] = wsrc[( 0+fr)*64 + d];
      wf1[r] = wsrc[(16+fr)*64 + d];
      wf2[r] = wsrc[(32+fr)*64 + d];
      wf3[r] = wsrc[(48+fr)*64 + d];
    }
    #pragma unroll
    for(int r=0;r<4;r++){
      int d = wv*16+quad*4+r;
      W1bf[0][d*W1LD +  0 + fr] = f2bf(wf0[r]);
      W1bf[0][d*W1LD + 16 + fr] = f2bf(wf1[r]);
      W1bf[0][d*W1LD + 32 + fr] = f2bf(wf2[r]);
      W1bf[0][d*W1LD + 48 + fr] = f2bf(wf3[r]);
    }
  }
  // stagers: rope tables for their rows + prefetch regs
  float ccj[6], ssj[6];
  u16 Pq[6], Pk[6], Pv[6], Pl[6];
  if (isStager){
    #pragma unroll
    for(int j=0;j<6;j++) if (j < nrows){
      ccj[j] = ropec[(row0+j)*64 + lane];
      ssj[j] = ropes[(row0+j)*64 + lane];
    }
  }
  // zero pads (cols [16,40) so K=32 fragments see zeros) — all buffers
  for(int i=t;i<64*24;i+=512){
    int rr=i/24, cp=16+i%24;
    gradTbf[0][rr*GTLD+cp]=0; gradTbf[1][rr*GTLD+cp]=0;
    exkT[0][rr*EKLD+cp]=0; exkT[1][rr*EKLD+cp]=0; exkT[2][rr*EKLD+cp]=0;
  }
  for(int i=t;i<16*24;i+=512){
    int rr=i/24, cp=16+i%24;
    etaA[0][rr*EALD+cp]=0; etaA[1][rr*EALD+cp]=0;
  }
  if (t<64) b1s[0][t]=b1i[h*64+t];

  // stager helpers
  auto loadP = [&](int n){
    const size_t rb = (size_t)b*2048 + n*16;
    #pragma unroll
    for(int j=0;j<6;j++) if (j < nrows){
      const u16* p = XQKV + (rb+row0+j)*6272 + h*64 + lane;
      Pq[j]=p[0]; Pk[j]=p[2048]; Pv[j]=p[4096];
      Pl[j]=XQKV[(rb+row0+j)*6272 + 6144 + h];
    }
  };
  auto stageN = [&](int slot){
    #pragma unroll
    for(int j=0;j<6;j++) if (j < nrows){
      const int i = row0+j;
      float q=bf2f(Pq[j]), k=bf2f(Pk[j]), v=bf2f(Pv[j]);
      float qr = q*ccj[j] + sg*swap32(q)*ssj[j];
      float kr = k*ccj[j] + sg*swap32(k)*ssj[j];
      float lr = 1.f/(1.f + expf(-(bf2f(Pl[j]) + lrbh)));
      xqbf[slot][i*XLD+lane] = f2bf(qr);
      xkbf[slot][i*XLD+lane] = f2bf(kr);
      exkT[slot][lane*EKLD+i] = f2bf(-ct*lr*kr);
      tgT2[slot][i*TD2+lane] = v - kr;
      xqT2[slot][i*TD2+lane] = qr;
      if (lane==0) lrs[slot][i]=lr;
    }
  };

  // prologue: stage minibatch 0 into slot 0; prefetch minibatch 1
  if (isStager){
    loadP(0);
    stageN(0);
    loadP(1);
  }
  __syncthreads();

  const f32x4 fzero = (f32x4){0.f,0.f,0.f,0.f};

  // wave-4 carried state (output pipeline depth 1)
  f32x4 zqP0=fzero, zqP1=fzero, zqP2=fzero, zqP3=fzero;
  f32x4 b1qP0=fzero, b1qP1=fzero, b1qP2=fzero, b1qP3=fzero;

  // output chain for step s: parity2 = s&1 (etaA/gradT), slot3 = s%3 (xqT2)
  auto do_out = [&](int p2, int p3, size_t rb){
    short8 be = *(const short8*)&etaA[p2][fr*EALD + quad*8];
    f32x4 c20,c21,c22,c23;
    c20 = __builtin_amdgcn_mfma_f32_16x16x32_bf16(*(const short8*)&gradTbf[p2][( 0+fr)*GTLD + quad*8], be, fzero, 0,0,0);
    c21 = __builtin_amdgcn_mfma_f32_16x16x32_bf16(*(const short8*)&gradTbf[p2][(16+fr)*GTLD + quad*8], be, fzero, 0,0,0);
    c22 = __builtin_amdgcn_mfma_f32_16x16x32_bf16(*(const short8*)&gradTbf[p2][(32+fr)*GTLD + quad*8], be, fzero, 0,0,0);
    c23 = __builtin_amdgcn_mfma_f32_16x16x32_bf16(*(const short8*)&gradTbf[p2][(48+fr)*GTLD + quad*8], be, fzero, 0,0,0);
    f32x4 xqv0 = *(const f32x4*)&xqT2[p3][fr*TD2 +  0 + quad*4];
    f32x4 xqv1 = *(const f32x4*)&xqT2[p3][fr*TD2 + 16 + quad*4];
    f32x4 xqv2 = *(const f32x4*)&xqT2[p3][fr*TD2 + 32 + quad*4];
    f32x4 xqv3 = *(const f32x4*)&xqT2[p3][fr*TD2 + 48 + quad*4];
    f32x4 zb0,zb1,zb2,zb3;
    float s1=0.f, s2=0.f;
    #pragma unroll
    for(int r=0;r<4;r++){
      zb0[r] = zqP0[r] + b1qP0[r] + c20[r];
      zb1[r] = zqP1[r] + b1qP1[r] + c21[r];
      zb2[r] = zqP2[r] + b1qP2[r] + c22[r];
      zb3[r] = zqP3[r] + b1qP3[r] + c23[r];
      s1 += zb0[r]+zb1[r]+zb2[r]+zb3[r];
      s2 += zb0[r]*zb0[r]+zb1[r]*zb1[r]+zb2[r]*zb2[r]+zb3[r]*zb3[r];
    }
    s1 = qsum(s1); s2 = qsum(s2);
    float mu = s1*(1.f/64.f);
    float var = s2*(1.f/64.f) - mu*mu;
    float rstd = rsqrtf(var + 1e-6f);
    #pragma unroll
    for(int m=0;m<4;m++){
      f32x4* zp = (m==0)?&zb0:(m==1)?&zb1:(m==2)?&zb2:&zb3;
      const f32x4* xp = (m==0)?&xqv0:(m==1)?&xqv1:(m==2)?&xqv2:&xqv3;
      f32x4 o;
      #pragma unroll
      for(int r=0;r<4;r++){
        f32x2 wb = lwr[m*4+r];
        float xh = ((*zp)[r] - mu)*rstd;
        o[r] = (*xp)[r] + xh*wb[0] + wb[1];
      }
      *(f32x4*)&Y[(rb+fr)*2048 + h*64 + m*16 + quad*4] = o;
    }
  };

  int c3 = 0;   // n%3
  for(int n=0;n<128;n++){
    const int cur2 = n&1, pb2 = cur2^1;
    const int cur3 = c3;
    const int nxt3 = (c3==2)? 0 : c3+1;
    const int pb3  = (c3==0)? 2 : c3-1;
    const size_t rbase = (size_t)b*2048 + n*16;

    // ---------------- single region ----------------
    if (wv < 4){
      f32x4 b1v0 = *(const f32x4*)&b1s[cur2][ 0+quad*4];
      f32x4 b1v1 = *(const f32x4*)&b1s[cur2][16+quad*4];
      f32x4 b1v2 = *(const f32x4*)&b1s[cur2][32+quad*4];
      f32x4 b1v3 = *(const f32x4*)&b1s[cur2][48+quad*4];
      f32x4 tgv0 = *(const f32x4*)&tgT2[cur3][fr*TD2 +  0 + quad*4];
      f32x4 tgv1 = *(const f32x4*)&tgT2[cur3][fr*TD2 + 16 + quad*4];
      f32x4 tgv2 = *(const f32x4*)&tgT2[cur3][fr*TD2 + 32 + quad*4];
      f32x4 tgv3 = *(const f32x4*)&tgT2[cur3][fr*TD2 + 48 + quad*4];
      // Zk^T = W1t (x) xk : C[d][i], full 64x16 (dup x4: waves 0-3)
      short8 bk0 = *(const short8*)&xkbf[cur3][fr*XLD + quad*8];
      short8 bk1 = *(const short8*)&xkbf[cur3][fr*XLD + 32 + quad*8];
      f32x4 z0,z1,z2,z3;
      z0 = __builtin_amdgcn_mfma_f32_16x16x32_bf16(*(const short8*)&W1bf[cur2][( 0+fr)*W1LD + quad*8],      bk0, fzero, 0,0,0);
      z0 = __builtin_amdgcn_mfma_f32_16x16x32_bf16(*(const short8*)&W1bf[cur2][( 0+fr)*W1LD + 32 + quad*8], bk1, z0,    0,0,0);
      z1 = __builtin_amdgcn_mfma_f32_16x16x32_bf16(*(const short8*)&W1bf[cur2][(16+fr)*W1LD + quad*8],      bk0, fzero, 0,0,0);
      z1 = __builtin_amdgcn_mfma_f32_16x16x32_bf16(*(const short8*)&W1bf[cur2][(16+fr)*W1LD + 32 + quad*8], bk1, z1,    0,0,0);
      z2 = __builtin_amdgcn_mfma_f32_16x16x32_bf16(*(const short8*)&W1bf[cur2][(32+fr)*W1LD + quad*8],      bk0, fzero, 0,0,0);
      z2 = __builtin_amdgcn_mfma_f32_16x16x32_bf16(*(const short8*)&W1bf[cur2][(32+fr)*W1LD + 32 + quad*8], bk1, z2,    0,0,0);
      z3 = __builtin_amdgcn_mfma_f32_16x16x32_bf16(*(const short8*)&W1bf[cur2][(48+fr)*W1LD + quad*8],      bk0, fzero, 0,0,0);
      z3 = __builtin_amdgcn_mfma_f32_16x16x32_bf16(*(const short8*)&W1bf[cur2][(48+fr)*W1LD + 32 + quad*8], bk1, z3,    0,0,0);
      // LN-l2 backward
      f32x4 xh0,xh1,xh2,xh3;
      {
        float s1=0.f, s2=0.f;
        #pragma unroll
        for(int r=0;r<4;r++){
          z0[r] += b1v0[r];
          z1[r] += b1v1[r];
          z2[r] += b1v2[r];
          z3[r] += b1v3[r];
          s1 += z0[r]+z1[r]+z2[r]+z3[r];
          s2 += z0[r]*z0[r]+z1[r]*z1[r]+z2[r]*z2[r]+z3[r]*z3[r];
        }
        s1 = qsum(s1); s2 = qsum(s2);
        float mu = s1*(1.f/64.f);
        float var = s2*(1.f/64.f) - mu*mu;
        float rstd = rsqrtf(var + 1e-6f);
        float u1=0.f, u2=0.f;
        #pragma unroll
        for(int m=0;m<4;m++){
          f32x4* zp = (m==0)?&z0:(m==1)?&z1:(m==2)?&z2:&z3;
          f32x4* xp = (m==0)?&xh0:(m==1)?&xh1:(m==2)?&xh2:&xh3;
          const f32x4* tp = (m==0)?&tgv0:(m==1)?&tgv1:(m==2)?&tgv2:&tgv3;
          #pragma unroll
          for(int r=0;r<4;r++){
            f32x2 wb = lwr[m*4+r];
            float xh = ((*zp)[r] - mu)*rstd;
            float gx = (wb[0]*xh + wb[1] - (*tp)[r])*wb[0];
            (*xp)[r] = xh;
            (*zp)[r] = gx;
            u1 += gx; u2 += gx*xh;
          }
        }
        u1 = qsum(u1); u2 = qsum(u2);
        const float c64 = rstd*(1.f/64.f);
        #pragma unroll
        for(int m=0;m<4;m++){
          f32x4* zp = (m==0)?&z0:(m==1)?&z1:(m==2)?&z2:&z3;
          f32x4* xp = (m==0)?&xh0:(m==1)?&xh1:(m==2)?&xh2:&xh3;
          #pragma unroll
          for(int r=0;r<4;r++)
            (*zp)[r] = (64.f*(*zp)[r] - u1 - (*xp)[r]*u2)*c64;   // gradT
        }
      }
      // write OWN mtile of gradT
      f32x4 zsel = (wv==0)?z0:(wv==1)?z1:(wv==2)?z2:z3;
      #pragma unroll
      for(int r=0;r<4;r++)
        gradTbf[cur2][(wv*16+quad*4+r)*GTLD + fr] = f2bf(zsel[r]);
      // b1 update for own mtile (f32 gradT, jsum over 16 token lanes)
      {
        float ej = ct * lrs[cur3][fr];
        f32x4 del;
        #pragma unroll
        for(int r=0;r<4;r++) del[r] = jsum(ej * zsel[r]);
        f32x4 b1own = (wv==0)?b1v0:(wv==1)?b1v1:(wv==2)?b1v2:b1v3;
        if (fr == 0){
          #pragma unroll
          for(int r=0;r<4;r++) b1s[pb2][wv*16+quad*4+r] = b1own[r] - del[r];
        }
      }
      // same-wave readback: W1 update of own mtile (tiles n=0..3)
      asm volatile("s_waitcnt lgkmcnt(0)" ::: "memory");
      __builtin_amdgcn_sched_barrier(0);
      short8 ga = *(const short8*)&gradTbf[cur2][(wv*16+fr)*GTLD + quad*8];
      short8 e0 = *(const short8*)&exkT[cur3][( 0+fr)*EKLD + quad*8];
      short8 e1 = *(const short8*)&exkT[cur3][(16+fr)*EKLD + quad*8];
      short8 e2 = *(const short8*)&exkT[cur3][(32+fr)*EKLD + quad*8];
      short8 e3 = *(const short8*)&exkT[cur3][(48+fr)*EKLD + quad*8];
      wf0 = __builtin_amdgcn_mfma_f32_16x16x32_bf16(ga, e0, wf0, 0,0,0);
      wf1 = __builtin_amdgcn_mfma_f32_16x16x32_bf16(ga, e1, wf1, 0,0,0);
      wf2 = __builtin_amdgcn_mfma_f32_16x16x32_bf16(ga, e2, wf2, 0,0,0);
      wf3 = __builtin_amdgcn_mfma_f32_16x16x32_bf16(ga, e3, wf3, 0,0,0);
      #pragma unroll
      for(int r=0;r<4;r++){
        int d = wv*16+quad*4+r;
        W1bf[pb2][d*W1LD +  0 + fr] = f2bf(wf0[r]);
        W1bf[pb2][d*W1LD + 16 + fr] = f2bf(wf1[r]);
        W1bf[pb2][d*W1LD + 32 + fr] = f2bf(wf2[r]);
        W1bf[pb2][d*W1LD + 48 + fr] = f2bf(wf3[r]);
      }
    }
    else if (wv == 4){
      // Zq(n): independent MFMAs into fresh regs
      short8 bq0 = *(const short8*)&xqbf[cur3][fr*XLD + quad*8];
      short8 bq1 = *(const short8*)&xqbf[cur3][fr*XLD + 32 + quad*8];
      f32x4 zqN0,zqN1,zqN2,zqN3;
      zqN0 = __builtin_amdgcn_mfma_f32_16x16x32_bf16(*(const short8*)&W1bf[cur2][( 0+fr)*W1LD + quad*8],      bq0, fzero, 0,0,0);
      zqN0 = __builtin_amdgcn_mfma_f32_16x16x32_bf16(*(const short8*)&W1bf[cur2][( 0+fr)*W1LD + 32 + quad*8], bq1, zqN0,  0,0,0);
      zqN1 = __builtin_amdgcn_mfma_f32_16x16x32_bf16(*(const short8*)&W1bf[cur2][(16+fr)*W1LD + quad*8],      bq0, fzero, 0,0,0);
      zqN1 = __builtin_amdgcn_mfma_f32_16x16x32_bf16(*(const short8*)&W1bf[cur2][(16+fr)*W1LD + 32 + quad*8], bq1, zqN1,  0,0,0);
      zqN2 = __builtin_amdgcn_mfma_f32_16x16x32_bf16(*(const short8*)&W1bf[cur2][(32+fr)*W1LD + quad*8],      bq0, fzero, 0,0,0);
      zqN2 = __builtin_amdgcn_mfma_f32_16x16x32_bf16(*(const short8*)&W1bf[cur2][(32+fr)*W1LD + 32 + quad*8], bq1, zqN2,  0,0,0);
      zqN3 = __builtin_amdgcn_mfma_f32_16x16x32_bf16(*(const short8*)&W1bf[cur2][(48+fr)*W1LD + quad*8],      bq0, fzero, 0,0,0);
      zqN3 = __builtin_amdgcn_mfma_f32_16x16x32_bf16(*(const short8*)&W1bf[cur2][(48+fr)*W1LD + 32 + quad*8], bq1, zqN3,  0,0,0);
      // output of step n-1
      if (n > 0) do_out(pb2, pb3, rbase - 16);
      // rotate pipeline state
      zqP0=zqN0; zqP1=zqN1; zqP2=zqN2; zqP3=zqN3;
      b1qP0 = *(const f32x4*)&b1s[cur2][ 0+quad*4];   // b1 pre-update for step n
      b1qP1 = *(const f32x4*)&b1s[cur2][16+quad*4];
      b1qP2 = *(const f32x4*)&b1s[cur2][32+quad*4];
      b1qP3 = *(const f32x4*)&b1s[cur2][48+quad*4];
    }
    else {
      if (wv == 7){
        // At = xq (x) xk : C[i][j] -> etaA[cur2]
        short8 aq0 = *(const short8*)&xqbf[cur3][fr*XLD + quad*8];
        short8 aq1 = *(const short8*)&xqbf[cur3][fr*XLD + 32 + quad*8];
        short8 bk0 = *(const short8*)&xkbf[cur3][fr*XLD + quad*8];
        short8 bk1 = *(const short8*)&xkbf[cur3][fr*XLD + 32 + quad*8];
        f32x4 at;
        at = __builtin_amdgcn_mfma_f32_16x16x32_bf16(aq0, bk0, fzero, 0,0,0);
        at = __builtin_amdgcn_mfma_f32_16x16x32_bf16(aq1, bk1, at,    0,0,0);
        float lrj = lrs[cur3][fr]*(1.f/64.f);
        #pragma unroll
        for(int r=0;r<4;r++){
          int i = quad*4 + r;
          float val = (fr <= i) ? -tki[r]*lrj*(1.f + at[r]) : 0.f;
          etaA[cur2][i*EALD + fr] = f2bf(val);
        }
      }
      // stagers (5,6,7): stage(n+1) into slot nxt3; prefetch minibatch n+2
      if (n < 127) stageN(nxt3);
      if (n < 126) loadP(n+2);
    }
    BARS();
    c3 = nxt3;
  }

  // epilogue: output of the last step (n=127): parity2 = 1, slot3 = 127%3 = 1
  if (wv == 4) do_out(1, 1, (size_t)b*2048 + 127*16);
}

// ---------------- host launch ----------------
extern "C" void kernel_launch(void* const* d_in, const int* in_sizes, int n_in,
                              void* d_out, int out_size, void* d_ws, size_t ws_size,
                              hipStream_t stream)
{
  const float* enc   = (const float*)d_in[0];
  const float* ln1w  = (const float*)d_in[1];
  const float* ln1b  = (const float*)d_in[2];
  const float* qw    = (const float*)d_in[3];
  const float* kw    = (const float*)d_in[4];
  const float* vw    = (const float*)d_in[5];
  const float* ow    = (const float*)d_in[6];
  const float* lrw   = (const float*)d_in[7];
  const float* lrb   = (const float*)d_in[8];
  const float* tio   = (const float*)d_in[9];
  const float* tnw   = (const float*)d_in[10];
  const float* tnb   = (const float*)d_in[11];
  const float* W1i   = (const float*)d_in[12];
  const float* b1i   = (const float*)d_in[13];
  const float* postw = (const float*)d_in[14];
  const float* postb = (const float*)d_in[15];
  const float* flnw  = (const float*)d_in[16];
  const float* flnb  = (const float*)d_in[17];
  const float* w1f   = (const float*)d_in[18];
  const float* b1f   = (const float*)d_in[19];
  const float* w2f   = (const float*)d_in[20];
  const float* b2f   = (const float*)d_in[21];
  float* out = (float*)d_out;

  char* ws = (char*)d_ws;
  size_t off = 0;
  auto alloc = [&](size_t bytes)->void*{ void* p = ws + off; off += (bytes + 255) & ~(size_t)255; return p; };
  u16*   regA  = (u16*)  alloc(8192ull*2048*2);   // x_bf -> ypost_bf -> z_bf
  u16*   wqkvT = (u16*)  alloc(6400ull*2048*2);   // [qT|kT|vT|lr(32)+zeros..6400); later oT/w1fT/w2fT
  u16*   XQKV  = (u16*)  alloc(8192ull*6272*2);   // later: h_bf
  float* yb    = (float*)alloc(8192ull*2048*4);   // y -> y2
  float* ropec = (float*)alloc(1024*4);
  float* ropes = (float*)alloc(1024*4);
  float* tokb  = (float*)alloc(64*4);

  u16* oT   = wqkvT;
  u16* w1fT = wqkvT + 2048ull*2048;
  u16* w2fT = w1fT + 1024ull*2048;
  u16* hbf  = XQKV;
  float* y2 = yb;

  static bool s_attr = false;
  if (!s_attr){
    s_attr = true;
    (void)hipFuncSetAttribute(reinterpret_cast<const void*>(gemm256<4>), hipFuncAttributeMaxDynamicSharedMemorySize, 131072);
    (void)hipFuncSetAttribute(reinterpret_cast<const void*>(gemm256<1>), hipFuncAttributeMaxDynamicSharedMemorySize, 131072);
    (void)hipFuncSetAttribute(reinterpret_cast<const void*>(gemm256<2>), hipFuncAttributeMaxDynamicSharedMemorySize, 131072);
    (void)hipFuncSetAttribute(reinterpret_cast<const void*>(gemm256<3>), hipFuncAttributeMaxDynamicSharedMemorySize, 131072);
  }

  rope_init<<<4, 256, 0, stream>>>(tio, ropec, ropes, tokb);

  // fused pre-GEMM weight transposes (q,k,v)
  transpose_cast3<<<dim3(64,64,3), 256, 0, stream>>>(
      qw, wqkvT,                2048, 2048,
      kw, wqkvT + 2048ull*2048, 2048, 2048,
      vw, wqkvT + 4096ull*2048, 2048, 2048);
  cast_lrw<<<2048, 256, 0, stream>>>(lrw, wqkvT + 6144ull*2048);

  ln_row<<<2048, 256, 0, stream>>>(enc, ln1w, ln1b, 1e-5f, regA);

  // QKV + lr projection: logical N=6400 (25 tiles), real cols 6272, ldc 6272
  gemm256<4><<<32*25, 512, 131072, stream>>>(regA, wqkvT, nullptr, XQKV,
                                             nullptr, nullptr, 6272, 6272, 2048, 25);

  // fused post-GEMM weight transposes (o, w1f, w2f) — reuses wqkvT region
  transpose_cast3<<<dim3(64,64,3), 256, 0, stream>>>(
      ow,  oT,   2048, 2048,
      w1f, w1fT, 2048, 1024,
      w2f, w2fT, 1024, 2048);

  // sequential TTT scan (MFMA formulation)
  ttt_scan<<<128, 512, 0, stream>>>(XQKV, ropec, ropes, tokb, tnw, tnb, lrb, W1i, b1i, yb);

  // post-LN + O-projection + residual(enc)
  ln_row<<<2048, 256, 0, stream>>>(yb, postw, postb, 1e-6f, regA);
  gemm256<1><<<32*8, 512, 131072, stream>>>(regA, oT, y2, nullptr,
                                            nullptr, enc, 2048, 2048, 2048, 8);

  // FFN
  ln_row<<<2048, 256, 0, stream>>>(y2, flnw, flnb, 1e-6f, regA);
  gemm256<2><<<32*4, 512, 131072, stream>>>(regA, w1fT, nullptr, hbf,
                                            b1f, nullptr, 1024, 1024, 2048, 4);
  gemm256<3><<<32*8, 512, 131072, stream>>>(hbf, w2fT, out, nullptr,
                                            b2f, y2, 2048, 2048, 1024, 8);
}